// Round 4
// baseline (1861.031 us; speedup 1.0000x reference)
//
#include <hip/hip_runtime.h>
#include <hip/hip_bf16.h>

#define BB 4
#define CC 64
#define HH 96
#define WW 384
#define HW (HH*WW)          // 36864
#define CHW (CC*HW)         // 2359296
#define BH (BB*HH)          // 384
#define EPSV 1e-6f
#define QSCALE 0.125f       // C^-0.5, folded into Q_l

typedef __hip_bfloat16 bf16;
typedef short s8vec __attribute__((ext_vector_type(8)));   // 8 bf16 = one MFMA frag
typedef float f4vec __attribute__((ext_vector_type(4)));   // MFMA accum

__device__ __forceinline__ float b2f(bf16 v){ return __bfloat162float(v); }
__device__ __forceinline__ bf16 f2b(float v){ return __float2bfloat16(v); }
__device__ __forceinline__ unsigned short f2bu(float f){
    bf16 h = __float2bfloat16(f);
    return __builtin_bit_cast(unsigned short, h);
}

// ---------------- workspace layout (per-batch chunk) ----------------
// buf0: A [HH][WW][WW] bf16  -> overwritten in-place by P = M_r2l
// buf1: LT = M_l2r^T  bf16   (LT[u][v] = M_l2r[v][u])
// buf2: PT = P^T      bf16
//       * before k_trans, buf2 doubles as Ql/Qr/Vl/Vr (4*QELEMS <= ACHUNK);
//         k5m (V consumer) is ordered BEFORE k_trans so nothing is clobbered live.
// then f32 stats: rmax, irsum, cmax, icsum, mask_r2l, mask_l2r (each BH*WW)
// then 4 doubles.  TOTAL footprint identical to the verified baseline session.
#define ACHUNK ((size_t)HH*WW*WW)    // 14,155,776 elems
#define SST ((size_t)BH*WW)          // 147456
#define QELEMS ((size_t)HW*64)       // 2,359,296

// ---------------- K0: zero loss accumulators ----------------
__global__ void k0_zero(double* dsum){
    if (threadIdx.x < 4) dsum[threadIdx.x] = 0.0;
}

// ---------------- K_qv: LN + proj1 -> Q (bf16), proj2 -> V (bf16) -- unchanged ----------------
__global__ __launch_bounds__(256) void k_qv(
    const float* __restrict__ xl, const float* __restrict__ xr,
    const float* __restrict__ nlw, const float* __restrict__ nlb,
    const float* __restrict__ nrw, const float* __restrict__ nrb,
    const float* __restrict__ P1l, const float* __restrict__ b1l,
    const float* __restrict__ P1r, const float* __restrict__ b1r,
    const float* __restrict__ P2l, const float* __restrict__ b2l,
    const float* __restrict__ P2r, const float* __restrict__ b2r,
    bf16* __restrict__ Ql, bf16* __restrict__ Qr,
    bf16* __restrict__ Vl, bf16* __restrict__ Vr, int b)
{
    __shared__ float xs[64*64];                  // [c][w]
    __shared__ float p1s[64*65], p2s[64*65];     // [o][c]
    __shared__ float nws[64], nbs[64], b1s[64], b2s[64];
    __shared__ float mus[64], ris[64];
    int t = threadIdx.x;
    int wt = blockIdx.x, l = blockIdx.y;
    int w0 = wt*64;

    for (int side=0; side<2; side++){
        const float* x  = side ? xr  : xl;
        const float* nw = side ? nrw : nlw;
        const float* nb = side ? nrb : nlb;
        const float* P1 = side ? P1r : P1l;
        const float* B1 = side ? b1r : b1l;
        const float* P2 = side ? P2r : P2l;
        const float* B2 = side ? b2r : b2l;
        bf16* Q = side ? Qr : Ql;
        bf16* V = side ? Vr : Vl;
        float qsc = side ? 1.f : QSCALE;

        if (t < 64){ nws[t]=nw[t]; nbs[t]=nb[t]; b1s[t]=B1[t]; b2s[t]=B2[t]; }
        for (int k=0;k<16;k++){
            int i=t+256*k; int o=i>>6, c=i&63;
            p1s[o*65+c]=P1[i]; p2s[o*65+c]=P2[i];
        }
        const float* xb = x + (size_t)b*CHW + (size_t)l*WW + w0;
        for (int k=0;k<16;k++){
            int c=(t>>6)+4*k, w=t&63;
            xs[c*64+w] = xb[(size_t)c*HW + w];
        }
        __syncthreads();
        if (t < 64){
            float s=0.f, ss=0.f;
            for (int c=0;c<64;c++){ float v=xs[c*64+t]; s+=v; ss+=v*v; }
            float mu=s*(1.f/64.f), var=ss*(1.f/64.f)-mu*mu;
            mus[t]=mu; ris[t]=rsqrtf(var+EPSV);
        }
        __syncthreads();

        // V projection (raw x): thread -> c-quad (t>>4)*4, v-quad (t&15)*4
        {
            int vq=t&15, ov=t>>4;
            float acc[4][4]={};
            for (int c=0;c<64;c++){
                float xv[4];
                for (int j=0;j<4;j++) xv[j]=xs[c*64+vq*4+j];
                for (int i=0;i<4;i++){
                    float w2=p2s[(ov*4+i)*65+c];
                    for (int j=0;j<4;j++) acc[i][j]+=w2*xv[j];
                }
            }
            for (int i=0;i<4;i++){
                int c=ov*4+i;
                ushort4 pk;
                pk.x=f2bu(acc[i][0]+b2s[c]); pk.y=f2bu(acc[i][1]+b2s[c]);
                pk.z=f2bu(acc[i][2]+b2s[c]); pk.w=f2bu(acc[i][3]+b2s[c]);
                *reinterpret_cast<ushort4*>(&V[(size_t)c*HW + (size_t)l*WW + w0 + vq*4]) = pk;
            }
        }
        // Q projection (LN'd x): thread -> c-quad (t&15)*4, w-quad (t>>4)*4
        {
            int cq=t&15, wq=t>>4;
            float muj[4], rij[4];
            for (int j=0;j<4;j++){ muj[j]=mus[wq*4+j]; rij[j]=ris[wq*4+j]; }
            float acc[4][4]={};
            for (int c=0;c<64;c++){
                float nwc=nws[c], nbc=nbs[c];
                float xn[4];
                for (int j=0;j<4;j++) xn[j]=(xs[c*64+wq*4+j]-muj[j])*rij[j]*nwc+nbc;
                for (int i=0;i<4;i++){
                    float w1=p1s[(cq*4+i)*65+c];
                    for (int j=0;j<4;j++) acc[i][j]+=w1*xn[j];
                }
            }
            for (int j=0;j<4;j++){
                int w=w0+wq*4+j;
                ushort4 pk;
                pk.x=f2bu(qsc*(acc[0][j]+b1s[cq*4+0]));
                pk.y=f2bu(qsc*(acc[1][j]+b1s[cq*4+1]));
                pk.z=f2bu(qsc*(acc[2][j]+b1s[cq*4+2]));
                pk.w=f2bu(qsc*(acc[3][j]+b1s[cq*4+3]));
                *reinterpret_cast<ushort4*>(&Q[((size_t)l*WW + w)*64 + cq*4]) = pk;
            }
        }
        __syncthreads();   // LDS reuse by next side
    }
}

// ---------------- K_attn: A = Q_l^T Q_r via MFMA -- unchanged ----------------
__global__ __launch_bounds__(256) void k_attn(
    const bf16* __restrict__ Ql, const bf16* __restrict__ Qr,
    bf16* __restrict__ Abuf)
{
    __shared__ bf16 As[128*72];   // [w-row][c], stride 72 (144B: 2-way bank alias = free)
    __shared__ bf16 Bs[128*72];   // [v-row][c]
    int t=threadIdx.x;
    int mt=blockIdx.x, nt=blockIdx.y, l=blockIdx.z;
    const bf16* Qa = Ql + ((size_t)l*WW + mt*128)*64;
    const bf16* Qb = Qr + ((size_t)l*WW + nt*128)*64;
    for (int i=0;i<4;i++){
        int lin=t+256*i;            // 0..1023 over 128 rows x 8 chunks
        int r=lin>>3, c8=lin&7;
        *reinterpret_cast<uint4*>(&As[r*72+c8*8]) =
            *reinterpret_cast<const uint4*>(&Qa[(size_t)r*64 + c8*8]);
        *reinterpret_cast<uint4*>(&Bs[r*72+c8*8]) =
            *reinterpret_cast<const uint4*>(&Qb[(size_t)r*64 + c8*8]);
    }
    __syncthreads();
    int wv=t>>6, lane=t&63;
    int m0=(wv>>1)*64, n0=(wv&1)*64;
    int ln=lane&15, cq=lane>>4;
    f4vec acc[4][4];
    #pragma unroll
    for (int m=0;m<4;m++)
        #pragma unroll
        for (int n=0;n<4;n++) acc[m][n]=(f4vec){0.f,0.f,0.f,0.f};
    #pragma unroll
    for (int kk=0;kk<2;kk++){
        s8vec a[4], bb[4];
        #pragma unroll
        for (int m=0;m<4;m++) a[m]=*reinterpret_cast<const s8vec*>(&As[(m0+m*16+ln)*72 + kk*32 + cq*8]);
        #pragma unroll
        for (int n=0;n<4;n++) bb[n]=*reinterpret_cast<const s8vec*>(&Bs[(n0+n*16+ln)*72 + kk*32 + cq*8]);
        #pragma unroll
        for (int m=0;m<4;m++)
            #pragma unroll
            for (int n=0;n<4;n++)
                acc[m][n]=__builtin_amdgcn_mfma_f32_16x16x32_bf16(a[m],bb[n],acc[m][n],0,0,0);
    }
    bf16* Ab = Abuf + (size_t)l*WW*WW;
    // C/D layout: col = lane&15, row = (lane>>4)*4 + reg
    #pragma unroll
    for (int m=0;m<4;m++){
        #pragma unroll
        for (int r=0;r<4;r++){
            int w = mt*128 + m0 + m*16 + cq*4 + r;
            #pragma unroll
            for (int n=0;n<4;n++){
                int v = nt*128 + n0 + n*16 + ln;
                Ab[(size_t)w*WW + v] = f2b(acc[m][n][r]);
            }
        }
    }
}

// ---------------- K3: softmax stats (row + col) -- unchanged ----------------
__global__ __launch_bounds__(384) void k3_stats(
    const bf16* __restrict__ Abuf, float* __restrict__ rmax, float* __restrict__ irsum,
    float* __restrict__ cmax, float* __restrict__ icsum, int b)
{
    __shared__ float pm[6][64], ps[6][64];
    int t=threadIdx.x, l=blockIdx.x, seg=blockIdx.y;
    int bh=b*HH+l;
    const bf16* Ab = Abuf + (size_t)l*WW*WW;
    int lane=t&63, wid=t>>6;
    for (int w=seg*64+wid; w<seg*64+64; w+=6){
        const bf16* row=Ab+(size_t)w*WW;
        float m=-1e30f;
        for (int k=0;k<6;k++) m=fmaxf(m,b2f(row[lane+64*k]));
        for (int o=32;o;o>>=1) m=fmaxf(m,__shfl_xor(m,o,64));
        float s=0.f;
        for (int k=0;k<6;k++) s+=__expf(b2f(row[lane+64*k])-m);
        for (int o=32;o;o>>=1) s+=__shfl_xor(s,o,64);
        if (lane==0){ rmax[bh*WW+w]=m; irsum[bh*WW+w]=1.f/s; }
    }
    {
        int c=t&63, v=seg*64+c;
        float m=-1e30f;
        for (int w=wid*64; w<wid*64+64; w++) m=fmaxf(m,b2f(Ab[(size_t)w*WW+v]));
        float s=0.f;
        for (int w=wid*64; w<wid*64+64; w++) s+=__expf(b2f(Ab[(size_t)w*WW+v])-m);
        pm[wid][c]=m; ps[wid][c]=s;
    }
    __syncthreads();
    if (t<64){
        float M=-1e30f;
        for (int p=0;p<6;p++) M=fmaxf(M,pm[p][t]);
        float S=0.f;
        for (int p=0;p<6;p++) S+=ps[p][t]*__expf(pm[p][t]-M);
        cmax[bh*WW+seg*64+t]=M; icsum[bh*WW+seg*64+t]=1.f/S;
    }
}

// ---------------- K_mats: A -> P (in-place) + LT -- unchanged ----------------
__global__ __launch_bounds__(256) void k_mats(
    bf16* __restrict__ AP, bf16* __restrict__ LT,
    const float* __restrict__ rmax, const float* __restrict__ irsum,
    const float* __restrict__ cmax, const float* __restrict__ icsum, int b)
{
    int t=threadIdx.x, l=blockIdx.x, seg=blockIdx.y;
    int bh=b*HH+l;
    bf16* Ab  = AP + (size_t)l*WW*WW;
    bf16* LTb = LT + (size_t)l*WW*WW;
    const float* rm=rmax+(size_t)bh*WW; const float* ris=irsum+(size_t)bh*WW;
    const float* cm=cmax+(size_t)bh*WW; const float* cis=icsum+(size_t)bh*WW;
    int lane6=t&63;
    float cmv[6], civ[6];
    for (int s=0;s<6;s++){ cmv[s]=cm[s*64+lane6]; civ[s]=cis[s*64+lane6]; }
    for (int k=0;k<16;k++){
        int w = seg*64 + (t>>6) + 4*k;
        float rmw = rm[w], risw = ris[w];
        for (int s=0;s<6;s++){
            int v = s*64 + lane6;
            size_t idx = (size_t)w*WW + v;
            float a = b2f(Ab[idx]);
            Ab[idx]  = f2b(__expf(a - rmw)*risw);       // P[w][v] = M_r2l[w][v]
            LTb[idx] = f2b(__expf(a - cmv[s])*civ[s]);  // LT[w][v] = M_l2r[v][w]
        }
    }
}

// ---------------- K_trans: PT = P^T -- unchanged ----------------
__global__ __launch_bounds__(256) void k_trans(
    const bf16* __restrict__ Pm, bf16* __restrict__ PTm)
{
    __shared__ float tile[64][65];
    int t=threadIdx.x;
    int ti=blockIdx.x, tj=blockIdx.y, l=blockIdx.z;
    const bf16* Pb = Pm + (size_t)l*WW*WW;
    bf16* PTb = PTm + (size_t)l*WW*WW;
    for (int k=0;k<16;k++){
        int r=(t>>6)+4*k, c=t&63;
        tile[r][c] = b2f(Pb[(size_t)(ti*64+r)*WW + tj*64+c]);
    }
    __syncthreads();
    for (int k=0;k<16;k++){
        int r=(t>>6)+4*k, c=t&63;
        PTb[(size_t)(tj*64+r)*WW + ti*64+c] = f2b(tile[c][r]);
    }
}

// ---------------- K4: validity masks -- unchanged ----------------
__global__ __launch_bounds__(384) void k4_masks(
    const bf16* __restrict__ Pm, const bf16* __restrict__ LTm,
    float* __restrict__ mask_r2l, float* __restrict__ mask_l2r, int b)
{
    __shared__ float pa[6][64];
    int t=threadIdx.x, l=blockIdx.x, seg=blockIdx.y;
    int bh=b*HH+l;
    const bf16* Pb  = Pm  + (size_t)l*WW*WW;
    const bf16* LTb = LTm + (size_t)l*WW*WW;
    int lane=t&63, wid=t>>6;
    {
        int c=t&63, v=seg*64+c;
        float s=0.f;
        for (int w=wid*64; w<wid*64+64; w++) s+=b2f(Pb[(size_t)w*WW+v]);
        pa[wid][c]=s;
    }
    __syncthreads();
    if (t<64){
        float S=0.f;
        for (int p=0;p<6;p++) S+=pa[p][t];
        mask_r2l[bh*WW+seg*64+t]=(S>0.1f)?1.f:0.f;
    }
    for (int u=seg*64+wid; u<seg*64+64; u+=6){
        const bf16* row=LTb+(size_t)u*WW;
        float s=0.f;
        for (int k=0;k<6;k++) s+=b2f(row[lane+64*k]);
        for (int o=32;o;o>>=1) s+=__shfl_xor(s,o,64);
        if (lane==0) mask_l2r[bh*WW+u]=(s>0.1f)?1.f:0.f;
    }
}

// ---------------- K5m: out = x + coef * (M @ V^T) via MFMA -- unchanged ----------------
__global__ __launch_bounds__(256) void k5m(
    const bf16* __restrict__ Msrc, const bf16* __restrict__ VT,
    const float* __restrict__ xadd, const float* __restrict__ coef,
    float* __restrict__ outp, int b, int side)
{
    __shared__ bf16 As[64*72];   // VT tile [c][v]
    __shared__ bf16 Bs[64*72];   // M tile  [w][v]
    int t=threadIdx.x;
    int wt=blockIdx.x, l=blockIdx.y;
    int w0=wt*64;
    int wv=t>>6, lane=t&63;
    int cb=(wv>>1)*32, wb=(wv&1)*32;
    int ln=lane&15, cq=lane>>4;
    f4vec acc[2][2];
    #pragma unroll
    for (int m=0;m<2;m++)
        #pragma unroll
        for (int n=0;n<2;n++) acc[m][n]=(f4vec){0.f,0.f,0.f,0.f};
    const bf16* Mb = Msrc + (size_t)l*WW*WW;

    for (int vt=0;vt<6;vt++){
        int v0=vt*64;
        __syncthreads();
        for (int i=0;i<2;i++){
            int lin=t+256*i; int c=lin>>3, c8=lin&7;
            *reinterpret_cast<uint4*>(&As[c*72+c8*8]) =
                *reinterpret_cast<const uint4*>(&VT[(size_t)c*HW + (size_t)l*WW + v0 + c8*8]);
        }
        if (side==0){
            for (int i=0;i<2;i++){
                int lin=t+256*i; int r=lin>>3, c8=lin&7;
                *reinterpret_cast<uint4*>(&Bs[r*72+c8*8]) =
                    *reinterpret_cast<const uint4*>(&Mb[(size_t)(w0+r)*WW + v0 + c8*8]);
            }
        } else {
            // Bs[w][v] = LT[v0+v][w0+w]  (global reads coalesced along w)
            int wl=t&63, j0=t>>6;
            for (int jj=0;jj<16;jj++){
                int j=j0+4*jj;
                Bs[wl*72+j] = Mb[(size_t)(v0+j)*WW + w0 + wl];
            }
        }
        __syncthreads();
        #pragma unroll
        for (int kk=0;kk<2;kk++){
            s8vec a[2], bb[2];
            #pragma unroll
            for (int m=0;m<2;m++) a[m]=*reinterpret_cast<const s8vec*>(&As[(cb+m*16+ln)*72+kk*32+cq*8]);
            #pragma unroll
            for (int n=0;n<2;n++) bb[n]=*reinterpret_cast<const s8vec*>(&Bs[(wb+n*16+ln)*72+kk*32+cq*8]);
            #pragma unroll
            for (int m=0;m<2;m++)
                #pragma unroll
                for (int n=0;n<2;n++)
                    acc[m][n]=__builtin_amdgcn_mfma_f32_16x16x32_bf16(a[m],bb[n],acc[m][n],0,0,0);
        }
    }
    const float* xb = xadd + (size_t)b*CHW + (size_t)l*WW + w0;
    float*      ob = outp + (size_t)b*CHW + (size_t)l*WW + w0;
    #pragma unroll
    for (int m=0;m<2;m++){
        #pragma unroll
        for (int r=0;r<4;r++){
            int c = cb + m*16 + cq*4 + r;
            float cf = coef[c];
            #pragma unroll
            for (int n=0;n<2;n++){
                int w = wb + n*16 + ln;
                ob[(size_t)c*HW + w] = xb[(size_t)c*HW + w] + cf*acc[m][n][r];
            }
        }
    }
}

// ---------------- K6: cycle loss GEMMs via MFMA -- RESTRUCTURED ----------------
// grid (9 = 3wt x 3ut, HH, 2 which), block 256 (4 waves; each wave a 64x64 quadrant
// of the 128x128 output tile). Per K-step: both operands staged as 128x64 LDS tiles
// with XOR-swizzled 16B chunks (stride 128B) -> conflict-free ds_read_b128.
// 32 MFMAs per wave per barrier-pair (was 8); 12 barriers/block (was 72);
// LDS 32 KB -> ~5 blocks/CU (was 59 KB -> 2).
// which==0: D = P @ L   (As = P rows,            Bs = LT rows), mask_l2r on cols
// which==1: D = L @ P   (As = L via LT transpose, Bs = PT rows), mask_r2l on cols
__global__ __launch_bounds__(256) void k6_mfma(
    const bf16* __restrict__ Pm, const bf16* __restrict__ LTm, const bf16* __restrict__ PTm,
    const float* __restrict__ mask_r2l, const float* __restrict__ mask_l2r,
    double* __restrict__ dsum, int b)
{
    __shared__ bf16 As[128*64];   // [w][k] swizzled
    __shared__ bf16 Bs[128*64];   // [u][k] swizzled
    int t=threadIdx.x;
    int wt=blockIdx.x/3, ut=blockIdx.x-wt*3;
    int l=blockIdx.y, which=blockIdx.z;
    int w0=wt*128, u0=ut*128, bh=b*HH+l;
    const float* msk = which ? (mask_r2l+(size_t)bh*WW) : (mask_l2r+(size_t)bh*WW);
    const bf16* Ap = Pm  + (size_t)l*WW*WW;          // which==0 A source (row-major)
    const bf16* Lt = LTm + (size_t)l*WW*WW;          // which==1 A source (transposed stage)
    const bf16* Bsrc = (which==0 ? LTm : PTm) + (size_t)l*WW*WW;

    int wv=t>>6, lane=t&63;
    int qr=wv>>1, qc=wv&1;
    int ln=lane&15, cq=lane>>4;

    f4vec acc[4][4];
    #pragma unroll
    for (int m=0;m<4;m++)
        #pragma unroll
        for (int n=0;n<4;n++) acc[m][n]=(f4vec){0.f,0.f,0.f,0.f};

    for (int kt=0; kt<6; kt++){
        __syncthreads();
        // ---- stage Bs[u][k] = Bsrc[u0+u][kt*64+k], swizzled 16B chunks ----
        #pragma unroll
        for (int i=0;i<4;i++){
            int lin=t+256*i; int u=lin>>3, c8=lin&7;
            uint4 d = *reinterpret_cast<const uint4*>(&Bsrc[(size_t)(u0+u)*WW + kt*64 + c8*8]);
            *reinterpret_cast<uint4*>((char*)Bs + u*128 + (((c8 ^ (u&7)))<<4)) = d;
        }
        // ---- stage As ----
        if (which==0){
            #pragma unroll
            for (int i=0;i<4;i++){
                int lin=t+256*i; int w=lin>>3, c8=lin&7;
                uint4 d = *reinterpret_cast<const uint4*>(&Ap[(size_t)(w0+w)*WW + kt*64 + c8*8]);
                *reinterpret_cast<uint4*>((char*)As + w*128 + (((c8 ^ (w&7)))<<4)) = d;
            }
        } else {
            // As[w][vl] = L[w0+w][kt*64+vl] = LT[kt*64+vl][w0+w]
            // read LT rows (w-contiguous uint4), scatter 8 b16 writes each
            #pragma unroll
            for (int i=0;i<4;i++){
                int lin=t+256*i; int vl=lin>>4, wc=lin&15;
                uint4 d = *reinterpret_cast<const uint4*>(&Lt[(size_t)(kt*64+vl)*WW + w0 + wc*8]);
                const unsigned short* pv = reinterpret_cast<const unsigned short*>(&d);
                #pragma unroll
                for (int j=0;j<8;j++){
                    int w = wc*8+j;
                    *reinterpret_cast<unsigned short*>(
                        (char*)As + w*128 + (((vl>>3) ^ (w&7))<<4) + ((vl&7)<<1)) = pv[j];
                }
            }
        }
        __syncthreads();
        // ---- MFMA: 32 per wave ----
        #pragma unroll
        for (int kk=0;kk<2;kk++){
            s8vec a[4], bb[4];
            #pragma unroll
            for (int m=0;m<4;m++){
                int r = qr*64 + m*16 + ln;
                a[m] = *reinterpret_cast<const s8vec*>(
                    (const char*)As + r*128 + ((((kk*4+cq) ^ (r&7)))<<4));
            }
            #pragma unroll
            for (int n=0;n<4;n++){
                int u = qc*64 + n*16 + ln;
                bb[n] = *reinterpret_cast<const s8vec*>(
                    (const char*)Bs + u*128 + ((((kk*4+cq) ^ (u&7)))<<4));
            }
            #pragma unroll
            for (int m=0;m<4;m++)
                #pragma unroll
                for (int n=0;n<4;n++)
                    acc[m][n]=__builtin_amdgcn_mfma_f32_16x16x32_bf16(a[m],bb[n],acc[m][n],0,0,0);
        }
    }

    // ---- masked |D - I| reduction.  C/D layout: col = lane&15, row = (lane>>4)*4+reg ----
    float local = 0.f;
    #pragma unroll
    for (int n=0;n<4;n++){
        int ua = u0 + qc*64 + n*16 + ln;
        float mv = msk[ua];
        #pragma unroll
        for (int m=0;m<4;m++){
            int wbase = w0 + qr*64 + m*16 + cq*4;
            #pragma unroll
            for (int r=0;r<4;r++)
                local += mv * fabsf(acc[m][n][r] - ((ua==wbase+r)?1.f:0.f));
        }
    }
    for (int o=32;o;o>>=1) local += __shfl_xor(local,o,64);
    if (lane==0) atomicAdd(&dsum[0], (double)local);
}

// ---------------- K7: photometric loss + LR passthrough -- unchanged ----------------
__global__ __launch_bounds__(384) void k7_photo(
    const bf16* __restrict__ Pm, const bf16* __restrict__ LTm,
    const float* __restrict__ mask_r2l, const float* __restrict__ mask_l2r,
    const float* __restrict__ LRl, const float* __restrict__ LRr,
    float* __restrict__ out2, float* __restrict__ out3, double* __restrict__ dsum, int b)
{
    __shared__ float lrl[3*WW], lrr[3*WW];
    int t=threadIdx.x, l=blockIdx.x, seg=blockIdx.y;
    int bh=b*HH+l;
    for (int c=0;c<3;c++){
        size_t idx=((size_t)(b*3+c)*HH+l)*WW+t;
        float vl=LRl[idx], vr=LRr[idx];
        lrl[c*WW+t]=vl; lrr[c*WW+t]=vr;
        if (seg==0){ out2[idx]=vl; out3[idx]=vr; }
    }
    __syncthreads();
    const bf16* Pb  = Pm  + (size_t)l*WW*WW;
    const bf16* LTb = LTm + (size_t)l*WW*WW;
    int lane=t&63, wid=t>>6;
    float local=0.f;
    for (int w=seg*64+wid; w<seg*64+64; w+=6){
        const bf16* prow = Pb  + (size_t)w*WW;
        const bf16* lrow = LTb + (size_t)w*WW;
        float a0=0.f,a1=0.f,a2=0.f, d0=0.f,d1=0.f,d2=0.f;
        for (int k=0;k<6;k++){
            int v=lane+64*k;
            float mp=b2f(prow[v]), ml=b2f(lrow[v]);
            a0+=mp*lrr[v]; a1+=mp*lrr[WW+v]; a2+=mp*lrr[2*WW+v];
            d0+=ml*lrl[v]; d1+=ml*lrl[WW+v]; d2+=ml*lrl[2*WW+v];
        }
        for (int o=32;o;o>>=1){
            a0+=__shfl_xor(a0,o,64); a1+=__shfl_xor(a1,o,64); a2+=__shfl_xor(a2,o,64);
            d0+=__shfl_xor(d0,o,64); d1+=__shfl_xor(d1,o,64); d2+=__shfl_xor(d2,o,64);
        }
        if (lane==0){
            float mkL=mask_l2r[bh*WW+w], mkR=mask_r2l[bh*WW+w];
            local += mkL*(fabsf(lrl[w]-a0)+fabsf(lrl[WW+w]-a1)+fabsf(lrl[2*WW+w]-a2));
            local += mkR*(fabsf(lrr[w]-d0)+fabsf(lrr[WW+w]-d1)+fabsf(lrr[2*WW+w]-d2));
        }
    }
    if (lane==0) atomicAdd(&dsum[1],(double)local);
}

// ---------------- K8: smoothness losses -- unchanged ----------------
__global__ __launch_bounds__(384) void k8_smooth(
    const bf16* __restrict__ Pm, const bf16* __restrict__ LTm,
    double* __restrict__ dsum, int b)
{
    (void)b;
    int t=threadIdx.x, l=blockIdx.x, seg=blockIdx.y;
    const bf16* Pb  = Pm  + (size_t)l*WW*WW;
    const bf16* LTb = LTm + (size_t)l*WW*WW;
    int lane=t&63, wid=t>>6;
    bool hasnext = (l < HH-1);
    float lw=0.f, lh=0.f;
    for (int w=seg*64+wid; w<seg*64+64; w+=6){
        const bf16* p0  = Pb  + (size_t)w*WW;
        const bf16* lt0 = LTb + (size_t)w*WW;
        if (w < WW-1){
            const bf16* p1  = p0 + WW;
            const bf16* lt1 = lt0 + WW;
            for (int k=0;k<6;k++){
                int v=lane+64*k;
                if (v < WW-1){
                    lw += fabsf(b2f(p0[v]) - b2f(p1[v+1]));
                    lw += fabsf(b2f(lt0[v]) - b2f(lt1[v+1]));
                }
            }
        }
        if (hasnext){
            const bf16* pn  = p0  + (size_t)WW*WW;
            const bf16* ltn = lt0 + (size_t)WW*WW;
            for (int k=0;k<6;k++){
                int v=lane+64*k;
                lh += fabsf(b2f(p0[v]) - b2f(pn[v]));
                lh += fabsf(b2f(lt0[v]) - b2f(ltn[v]));
            }
        }
    }
    for (int o=32;o;o>>=1){ lw+=__shfl_xor(lw,o,64); lh+=__shfl_xor(lh,o,64); }
    if (lane==0){
        atomicAdd(&dsum[3],(double)lw);
        atomicAdd(&dsum[2],(double)lh);
    }
}

// ---------------- K9: final loss -- unchanged ----------------
__global__ void k9_final(const double* __restrict__ dsum, const float* __restrict__ lossin,
                         float* __restrict__ out4)
{
    if (threadIdx.x==0){
        double cyc  = dsum[0]/(double)((size_t)BB*HH*WW*WW);
        double photo= dsum[1]/(double)((size_t)BB*3*HH*WW);
        double lhv  = dsum[2]/(double)((size_t)BB*(HH-1)*WW*WW);
        double lwv  = dsum[3]/(double)((size_t)BB*HH*(WW-1)*(WW-1));
        double res  = (double)lossin[0] + 0.0025*(photo + 0.1*(lwv+lhv) + cyc);
        out4[0]=(float)res;
    }
}

extern "C" void kernel_launch(void* const* d_in, const int* in_sizes, int n_in,
                              void* d_out, int out_size, void* d_ws, size_t ws_size,
                              hipStream_t stream)
{
    (void)in_sizes; (void)n_in; (void)out_size; (void)ws_size;
    const float* x_l  = (const float*)d_in[0];
    const float* x_r  = (const float*)d_in[1];
    const float* LRl  = (const float*)d_in[2];
    const float* LRr  = (const float*)d_in[3];
    const float* lossi= (const float*)d_in[4];
    const float* nlw  = (const float*)d_in[5];
    const float* nlb  = (const float*)d_in[6];
    const float* nrw  = (const float*)d_in[7];
    const float* nrb  = (const float*)d_in[8];
    const float* lp1w = (const float*)d_in[9];
    const float* lp1b = (const float*)d_in[10];
    const float* rp1w = (const float*)d_in[11];
    const float* rp1b = (const float*)d_in[12];
    const float* lp2w = (const float*)d_in[13];
    const float* lp2b = (const float*)d_in[14];
    const float* rp2w = (const float*)d_in[15];
    const float* rp2b = (const float*)d_in[16];
    const float* beta = (const float*)d_in[17];
    const float* gamma= (const float*)d_in[18];

    bf16* Abuf = (bf16*)d_ws;             // A -> P in-place
    bf16* LTb  = Abuf + ACHUNK;
    bf16* PTb  = Abuf + 2*ACHUNK;
    float* wsf = (float*)((char*)d_ws + 3*ACHUNK*2);
    float* rmax=wsf, *irsum=wsf+SST, *cmax=wsf+2*SST, *icsum=wsf+3*SST;
    float* mask_r2l=wsf+4*SST, *mask_l2r=wsf+5*SST;
    double* dsum=(double*)(wsf+6*SST);
    // Q and V all alias the PT chunk (4*QELEMS <= ACHUNK); dead before k_trans runs.
    bf16* Qlb = PTb;
    bf16* Qrb = PTb + QELEMS;
    bf16* Vlb = PTb + 2*QELEMS;
    bf16* Vrb = PTb + 3*QELEMS;

    float* out  = (float*)d_out;
    float* out0 = out;
    float* out1 = out + (size_t)BB*CHW;
    float* out2 = out + 2*(size_t)BB*CHW;
    float* out3 = out2 + (size_t)BB*3*HW;
    float* out4 = out3 + (size_t)BB*3*HW;

    k0_zero<<<1,64,0,stream>>>(dsum);
    for (int b=0;b<BB;b++){
        k_qv<<<dim3(6,HH),256,0,stream>>>(x_l,x_r,nlw,nlb,nrw,nrb,
                                          lp1w,lp1b,rp1w,rp1b,lp2w,lp2b,rp2w,rp2b,
                                          Qlb,Qrb,Vlb,Vrb,b);
        k_attn<<<dim3(3,3,HH),256,0,stream>>>(Qlb,Qrb,Abuf);
        k3_stats<<<dim3(HH,6),384,0,stream>>>(Abuf,rmax,irsum,cmax,icsum,b);
        k_mats<<<dim3(HH,6),256,0,stream>>>(Abuf,LTb,rmax,irsum,cmax,icsum,b);
        k4_masks<<<dim3(HH,6),384,0,stream>>>(Abuf,LTb,mask_r2l,mask_l2r,b);
        k5m<<<dim3(6,HH),256,0,stream>>>(Abuf,Vrb,x_l,beta, out0,b,0);   // V consumed here,
        k5m<<<dim3(6,HH),256,0,stream>>>(LTb, Vlb,x_r,gamma,out1,b,1);   // BEFORE k_trans
        k_trans<<<dim3(6,6,HH),256,0,stream>>>(Abuf,PTb);
        k6_mfma<<<dim3(9,HH,2),256,0,stream>>>(Abuf,LTb,PTb,mask_r2l,mask_l2r,dsum,b);
        k7_photo<<<dim3(HH,6),384,0,stream>>>(Abuf,LTb,mask_r2l,mask_l2r,LRl,LRr,out2,out3,dsum,b);
        k8_smooth<<<dim3(HH,6),384,0,stream>>>(Abuf,LTb,dsum,b);
    }
    k9_final<<<1,64,0,stream>>>(dsum,lossi,out4);
}

// Round 5
// 1781.302 us; speedup vs baseline: 1.0448x; 1.0448x over previous
//
#include <hip/hip_runtime.h>
#include <hip/hip_bf16.h>

#define BB 4
#define CC 64
#define HH 96
#define WW 384
#define HW (HH*WW)          // 36864
#define CHW (CC*HW)         // 2359296
#define BH (BB*HH)          // 384
#define EPSV 1e-6f
#define QSCALE 0.125f       // C^-0.5, folded into Q_l

typedef __hip_bfloat16 bf16;
typedef short s8vec __attribute__((ext_vector_type(8)));   // 8 bf16 = one MFMA frag
typedef float f4vec __attribute__((ext_vector_type(4)));   // MFMA accum

__device__ __forceinline__ float b2f(bf16 v){ return __bfloat162float(v); }
__device__ __forceinline__ bf16 f2b(float v){ return __float2bfloat16(v); }
__device__ __forceinline__ unsigned short f2bu(float f){
    bf16 h = __float2bfloat16(f);
    return __builtin_bit_cast(unsigned short, h);
}

// ---------------- workspace layout (per-batch chunk) ----------------
#define ACHUNK ((size_t)HH*WW*WW)    // 14,155,776 elems
#define SST ((size_t)BH*WW)          // 147456
#define QELEMS ((size_t)HW*64)       // 2,359,296

// ---------------- K0: zero loss accumulators ----------------
__global__ void k0_zero(double* dsum){
    if (threadIdx.x < 4) dsum[threadIdx.x] = 0.0;
}

// ---------------- K_qv: LN + proj1 -> Q (bf16), proj2 -> V (bf16) -- unchanged ----------------
__global__ __launch_bounds__(256) void k_qv(
    const float* __restrict__ xl, const float* __restrict__ xr,
    const float* __restrict__ nlw, const float* __restrict__ nlb,
    const float* __restrict__ nrw, const float* __restrict__ nrb,
    const float* __restrict__ P1l, const float* __restrict__ b1l,
    const float* __restrict__ P1r, const float* __restrict__ b1r,
    const float* __restrict__ P2l, const float* __restrict__ b2l,
    const float* __restrict__ P2r, const float* __restrict__ b2r,
    bf16* __restrict__ Ql, bf16* __restrict__ Qr,
    bf16* __restrict__ Vl, bf16* __restrict__ Vr, int b)
{
    __shared__ float xs[64*64];                  // [c][w]
    __shared__ float p1s[64*65], p2s[64*65];     // [o][c]
    __shared__ float nws[64], nbs[64], b1s[64], b2s[64];
    __shared__ float mus[64], ris[64];
    int t = threadIdx.x;
    int wt = blockIdx.x, l = blockIdx.y;
    int w0 = wt*64;

    for (int side=0; side<2; side++){
        const float* x  = side ? xr  : xl;
        const float* nw = side ? nrw : nlw;
        const float* nb = side ? nrb : nlb;
        const float* P1 = side ? P1r : P1l;
        const float* B1 = side ? b1r : b1l;
        const float* P2 = side ? P2r : P2l;
        const float* B2 = side ? b2r : b2l;
        bf16* Q = side ? Qr : Ql;
        bf16* V = side ? Vr : Vl;
        float qsc = side ? 1.f : QSCALE;

        if (t < 64){ nws[t]=nw[t]; nbs[t]=nb[t]; b1s[t]=B1[t]; b2s[t]=B2[t]; }
        for (int k=0;k<16;k++){
            int i=t+256*k; int o=i>>6, c=i&63;
            p1s[o*65+c]=P1[i]; p2s[o*65+c]=P2[i];
        }
        const float* xb = x + (size_t)b*CHW + (size_t)l*WW + w0;
        for (int k=0;k<16;k++){
            int c=(t>>6)+4*k, w=t&63;
            xs[c*64+w] = xb[(size_t)c*HW + w];
        }
        __syncthreads();
        if (t < 64){
            float s=0.f, ss=0.f;
            for (int c=0;c<64;c++){ float v=xs[c*64+t]; s+=v; ss+=v*v; }
            float mu=s*(1.f/64.f), var=ss*(1.f/64.f)-mu*mu;
            mus[t]=mu; ris[t]=rsqrtf(var+EPSV);
        }
        __syncthreads();

        {
            int vq=t&15, ov=t>>4;
            float acc[4][4]={};
            for (int c=0;c<64;c++){
                float xv[4];
                for (int j=0;j<4;j++) xv[j]=xs[c*64+vq*4+j];
                for (int i=0;i<4;i++){
                    float w2=p2s[(ov*4+i)*65+c];
                    for (int j=0;j<4;j++) acc[i][j]+=w2*xv[j];
                }
            }
            for (int i=0;i<4;i++){
                int c=ov*4+i;
                ushort4 pk;
                pk.x=f2bu(acc[i][0]+b2s[c]); pk.y=f2bu(acc[i][1]+b2s[c]);
                pk.z=f2bu(acc[i][2]+b2s[c]); pk.w=f2bu(acc[i][3]+b2s[c]);
                *reinterpret_cast<ushort4*>(&V[(size_t)c*HW + (size_t)l*WW + w0 + vq*4]) = pk;
            }
        }
        {
            int cq=t&15, wq=t>>4;
            float muj[4], rij[4];
            for (int j=0;j<4;j++){ muj[j]=mus[wq*4+j]; rij[j]=ris[wq*4+j]; }
            float acc[4][4]={};
            for (int c=0;c<64;c++){
                float nwc=nws[c], nbc=nbs[c];
                float xn[4];
                for (int j=0;j<4;j++) xn[j]=(xs[c*64+wq*4+j]-muj[j])*rij[j]*nwc+nbc;
                for (int i=0;i<4;i++){
                    float w1=p1s[(cq*4+i)*65+c];
                    for (int j=0;j<4;j++) acc[i][j]+=w1*xn[j];
                }
            }
            for (int j=0;j<4;j++){
                int w=w0+wq*4+j;
                ushort4 pk;
                pk.x=f2bu(qsc*(acc[0][j]+b1s[cq*4+0]));
                pk.y=f2bu(qsc*(acc[1][j]+b1s[cq*4+1]));
                pk.z=f2bu(qsc*(acc[2][j]+b1s[cq*4+2]));
                pk.w=f2bu(qsc*(acc[3][j]+b1s[cq*4+3]));
                *reinterpret_cast<ushort4*>(&Q[((size_t)l*WW + w)*64 + cq*4]) = pk;
            }
        }
        __syncthreads();   // LDS reuse by next side
    }
}

// ---------------- K_attn: A = Q_l^T Q_r via MFMA -- unchanged ----------------
__global__ __launch_bounds__(256) void k_attn(
    const bf16* __restrict__ Ql, const bf16* __restrict__ Qr,
    bf16* __restrict__ Abuf)
{
    __shared__ bf16 As[128*72];   // [w-row][c], stride 72 (144B: 2-way bank alias = free)
    __shared__ bf16 Bs[128*72];   // [v-row][c]
    int t=threadIdx.x;
    int mt=blockIdx.x, nt=blockIdx.y, l=blockIdx.z;
    const bf16* Qa = Ql + ((size_t)l*WW + mt*128)*64;
    const bf16* Qb = Qr + ((size_t)l*WW + nt*128)*64;
    for (int i=0;i<4;i++){
        int lin=t+256*i;            // 0..1023 over 128 rows x 8 chunks
        int r=lin>>3, c8=lin&7;
        *reinterpret_cast<uint4*>(&As[r*72+c8*8]) =
            *reinterpret_cast<const uint4*>(&Qa[(size_t)r*64 + c8*8]);
        *reinterpret_cast<uint4*>(&Bs[r*72+c8*8]) =
            *reinterpret_cast<const uint4*>(&Qb[(size_t)r*64 + c8*8]);
    }
    __syncthreads();
    int wv=t>>6, lane=t&63;
    int m0=(wv>>1)*64, n0=(wv&1)*64;
    int ln=lane&15, cq=lane>>4;
    f4vec acc[4][4];
    #pragma unroll
    for (int m=0;m<4;m++)
        #pragma unroll
        for (int n=0;n<4;n++) acc[m][n]=(f4vec){0.f,0.f,0.f,0.f};
    #pragma unroll
    for (int kk=0;kk<2;kk++){
        s8vec a[4], bb[4];
        #pragma unroll
        for (int m=0;m<4;m++) a[m]=*reinterpret_cast<const s8vec*>(&As[(m0+m*16+ln)*72 + kk*32 + cq*8]);
        #pragma unroll
        for (int n=0;n<4;n++) bb[n]=*reinterpret_cast<const s8vec*>(&Bs[(n0+n*16+ln)*72 + kk*32 + cq*8]);
        #pragma unroll
        for (int m=0;m<4;m++)
            #pragma unroll
            for (int n=0;n<4;n++)
                acc[m][n]=__builtin_amdgcn_mfma_f32_16x16x32_bf16(a[m],bb[n],acc[m][n],0,0,0);
    }
    bf16* Ab = Abuf + (size_t)l*WW*WW;
    // C/D layout: col = lane&15, row = (lane>>4)*4 + reg
    #pragma unroll
    for (int m=0;m<4;m++){
        #pragma unroll
        for (int r=0;r<4;r++){
            int w = mt*128 + m0 + m*16 + cq*4 + r;
            #pragma unroll
            for (int n=0;n<4;n++){
                int v = nt*128 + n0 + n*16 + ln;
                Ab[(size_t)w*WW + v] = f2b(acc[m][n][r]);
            }
        }
    }
}

// ---------------- K3: softmax stats (row + col) -- unchanged ----------------
__global__ __launch_bounds__(384) void k3_stats(
    const bf16* __restrict__ Abuf, float* __restrict__ rmax, float* __restrict__ irsum,
    float* __restrict__ cmax, float* __restrict__ icsum, int b)
{
    __shared__ float pm[6][64], ps[6][64];
    int t=threadIdx.x, l=blockIdx.x, seg=blockIdx.y;
    int bh=b*HH+l;
    const bf16* Ab = Abuf + (size_t)l*WW*WW;
    int lane=t&63, wid=t>>6;
    for (int w=seg*64+wid; w<seg*64+64; w+=6){
        const bf16* row=Ab+(size_t)w*WW;
        float m=-1e30f;
        for (int k=0;k<6;k++) m=fmaxf(m,b2f(row[lane+64*k]));
        for (int o=32;o;o>>=1) m=fmaxf(m,__shfl_xor(m,o,64));
        float s=0.f;
        for (int k=0;k<6;k++) s+=__expf(b2f(row[lane+64*k])-m);
        for (int o=32;o;o>>=1) s+=__shfl_xor(s,o,64);
        if (lane==0){ rmax[bh*WW+w]=m; irsum[bh*WW+w]=1.f/s; }
    }
    {
        int c=t&63, v=seg*64+c;
        float m=-1e30f;
        for (int w=wid*64; w<wid*64+64; w++) m=fmaxf(m,b2f(Ab[(size_t)w*WW+v]));
        float s=0.f;
        for (int w=wid*64; w<wid*64+64; w++) s+=__expf(b2f(Ab[(size_t)w*WW+v])-m);
        pm[wid][c]=m; ps[wid][c]=s;
    }
    __syncthreads();
    if (t<64){
        float M=-1e30f;
        for (int p=0;p<6;p++) M=fmaxf(M,pm[p][t]);
        float S=0.f;
        for (int p=0;p<6;p++) S+=ps[p][t]*__expf(pm[p][t]-M);
        cmax[bh*WW+seg*64+t]=M; icsum[bh*WW+seg*64+t]=1.f/S;
    }
}

// ---------------- K_mats: A -> P (in-place) + LT -- unchanged ----------------
__global__ __launch_bounds__(256) void k_mats(
    bf16* __restrict__ AP, bf16* __restrict__ LT,
    const float* __restrict__ rmax, const float* __restrict__ irsum,
    const float* __restrict__ cmax, const float* __restrict__ icsum, int b)
{
    int t=threadIdx.x, l=blockIdx.x, seg=blockIdx.y;
    int bh=b*HH+l;
    bf16* Ab  = AP + (size_t)l*WW*WW;
    bf16* LTb = LT + (size_t)l*WW*WW;
    const float* rm=rmax+(size_t)bh*WW; const float* ris=irsum+(size_t)bh*WW;
    const float* cm=cmax+(size_t)bh*WW; const float* cis=icsum+(size_t)bh*WW;
    int lane6=t&63;
    float cmv[6], civ[6];
    for (int s=0;s<6;s++){ cmv[s]=cm[s*64+lane6]; civ[s]=cis[s*64+lane6]; }
    for (int k=0;k<16;k++){
        int w = seg*64 + (t>>6) + 4*k;
        float rmw = rm[w], risw = ris[w];
        for (int s=0;s<6;s++){
            int v = s*64 + lane6;
            size_t idx = (size_t)w*WW + v;
            float a = b2f(Ab[idx]);
            Ab[idx]  = f2b(__expf(a - rmw)*risw);       // P[w][v] = M_r2l[w][v]
            LTb[idx] = f2b(__expf(a - cmv[s])*civ[s]);  // LT[w][v] = M_l2r[v][w]
        }
    }
}

// ---------------- K_trans: PT = P^T -- unchanged ----------------
__global__ __launch_bounds__(256) void k_trans(
    const bf16* __restrict__ Pm, bf16* __restrict__ PTm)
{
    __shared__ float tile[64][65];
    int t=threadIdx.x;
    int ti=blockIdx.x, tj=blockIdx.y, l=blockIdx.z;
    const bf16* Pb = Pm + (size_t)l*WW*WW;
    bf16* PTb = PTm + (size_t)l*WW*WW;
    for (int k=0;k<16;k++){
        int r=(t>>6)+4*k, c=t&63;
        tile[r][c] = b2f(Pb[(size_t)(ti*64+r)*WW + tj*64+c]);
    }
    __syncthreads();
    for (int k=0;k<16;k++){
        int r=(t>>6)+4*k, c=t&63;
        PTb[(size_t)(tj*64+r)*WW + ti*64+c] = f2b(tile[c][r]);
    }
}

// ---------------- K4: validity masks -- unchanged ----------------
__global__ __launch_bounds__(384) void k4_masks(
    const bf16* __restrict__ Pm, const bf16* __restrict__ LTm,
    float* __restrict__ mask_r2l, float* __restrict__ mask_l2r, int b)
{
    __shared__ float pa[6][64];
    int t=threadIdx.x, l=blockIdx.x, seg=blockIdx.y;
    int bh=b*HH+l;
    const bf16* Pb  = Pm  + (size_t)l*WW*WW;
    const bf16* LTb = LTm + (size_t)l*WW*WW;
    int lane=t&63, wid=t>>6;
    {
        int c=t&63, v=seg*64+c;
        float s=0.f;
        for (int w=wid*64; w<wid*64+64; w++) s+=b2f(Pb[(size_t)w*WW+v]);
        pa[wid][c]=s;
    }
    __syncthreads();
    if (t<64){
        float S=0.f;
        for (int p=0;p<6;p++) S+=pa[p][t];
        mask_r2l[bh*WW+seg*64+t]=(S>0.1f)?1.f:0.f;
    }
    for (int u=seg*64+wid; u<seg*64+64; u+=6){
        const bf16* row=LTb+(size_t)u*WW;
        float s=0.f;
        for (int k=0;k<6;k++) s+=b2f(row[lane+64*k]);
        for (int o=32;o;o>>=1) s+=__shfl_xor(s,o,64);
        if (lane==0) mask_l2r[bh*WW+u]=(s>0.1f)?1.f:0.f;
    }
}

// ---------------- K5m: out = x + coef * (M @ V^T) via MFMA -- unchanged ----------------
__global__ __launch_bounds__(256) void k5m(
    const bf16* __restrict__ Msrc, const bf16* __restrict__ VT,
    const float* __restrict__ xadd, const float* __restrict__ coef,
    float* __restrict__ outp, int b, int side)
{
    __shared__ bf16 As[64*72];   // VT tile [c][v]
    __shared__ bf16 Bs[64*72];   // M tile  [w][v]
    int t=threadIdx.x;
    int wt=blockIdx.x, l=blockIdx.y;
    int w0=wt*64;
    int wv=t>>6, lane=t&63;
    int cb=(wv>>1)*32, wb=(wv&1)*32;
    int ln=lane&15, cq=lane>>4;
    f4vec acc[2][2];
    #pragma unroll
    for (int m=0;m<2;m++)
        #pragma unroll
        for (int n=0;n<2;n++) acc[m][n]=(f4vec){0.f,0.f,0.f,0.f};
    const bf16* Mb = Msrc + (size_t)l*WW*WW;

    for (int vt=0;vt<6;vt++){
        int v0=vt*64;
        __syncthreads();
        for (int i=0;i<2;i++){
            int lin=t+256*i; int c=lin>>3, c8=lin&7;
            *reinterpret_cast<uint4*>(&As[c*72+c8*8]) =
                *reinterpret_cast<const uint4*>(&VT[(size_t)c*HW + (size_t)l*WW + v0 + c8*8]);
        }
        if (side==0){
            for (int i=0;i<2;i++){
                int lin=t+256*i; int r=lin>>3, c8=lin&7;
                *reinterpret_cast<uint4*>(&Bs[r*72+c8*8]) =
                    *reinterpret_cast<const uint4*>(&Mb[(size_t)(w0+r)*WW + v0 + c8*8]);
            }
        } else {
            int wl=t&63, j0=t>>6;
            for (int jj=0;jj<16;jj++){
                int j=j0+4*jj;
                Bs[wl*72+j] = Mb[(size_t)(v0+j)*WW + w0 + wl];
            }
        }
        __syncthreads();
        #pragma unroll
        for (int kk=0;kk<2;kk++){
            s8vec a[2], bb[2];
            #pragma unroll
            for (int m=0;m<2;m++) a[m]=*reinterpret_cast<const s8vec*>(&As[(cb+m*16+ln)*72+kk*32+cq*8]);
            #pragma unroll
            for (int n=0;n<2;n++) bb[n]=*reinterpret_cast<const s8vec*>(&Bs[(wb+n*16+ln)*72+kk*32+cq*8]);
            #pragma unroll
            for (int m=0;m<2;m++)
                #pragma unroll
                for (int n=0;n<2;n++)
                    acc[m][n]=__builtin_amdgcn_mfma_f32_16x16x32_bf16(a[m],bb[n],acc[m][n],0,0,0);
        }
    }
    const float* xb = xadd + (size_t)b*CHW + (size_t)l*WW + w0;
    float*      ob = outp + (size_t)b*CHW + (size_t)l*WW + w0;
    #pragma unroll
    for (int m=0;m<2;m++){
        #pragma unroll
        for (int r=0;r<4;r++){
            int c = cb + m*16 + cq*4 + r;
            float cf = coef[c];
            #pragma unroll
            for (int n=0;n<2;n++){
                int w = wb + n*16 + ln;
                ob[(size_t)c*HW + w] = xb[(size_t)c*HW + w] + cf*acc[m][n][r];
            }
        }
    }
}

// ---------------- K6: cycle loss GEMMs via MFMA -- XCD l-affinity swizzle ----------------
// 1D grid 1728 = 8 xcd * 12 lgrp * 18 tiles. HW round-robins consecutive blockIdx.x
// across the 8 XCDs, so decoding xcd = wg&7 gives every XCD a contiguous set of l's:
// all 18 blocks (3wt x 3ut x 2which) of one l land on ONE XCD -> its private L2 keeps
// that l's P/LT/PT (885 KB) resident; HBM fetch drops ~2x (was 166 MB vs 85 MB unique).
// which==1 A-stage: write order rotated by vl so per-instruction lanes hit 4 distinct
// (w&7) values -> <=4-way bank conflict (was full-wave: w&7 uniform per instruction).
// Epilogue: 4 wave-partials reduced in LDS -> ONE atomicAdd per block.
__global__ __launch_bounds__(256) void k6_mfma(
    const bf16* __restrict__ Pm, const bf16* __restrict__ LTm, const bf16* __restrict__ PTm,
    const float* __restrict__ mask_r2l, const float* __restrict__ mask_l2r,
    double* __restrict__ dsum, int b)
{
    __shared__ bf16 As[128*64];   // [w][k] swizzled
    __shared__ bf16 Bs[128*64];   // [u][k] swizzled
    __shared__ float red[4];
    int t=threadIdx.x;
    int wg=blockIdx.x;
    int xcd = wg & 7, j = wg >> 3;          // 0..215
    int lgrp = j/18, tile = j - lgrp*18;    // lgrp 0..11, tile 0..17
    int l = xcd + 8*lgrp;                   // all 18 tiles of l on one XCD
    int which = tile/9; int xt = tile - which*9;
    int wt = xt/3, ut = xt - wt*3;
    int w0=wt*128, u0=ut*128, bh=b*HH+l;
    const float* msk = which ? (mask_r2l+(size_t)bh*WW) : (mask_l2r+(size_t)bh*WW);
    const bf16* Ap = Pm  + (size_t)l*WW*WW;
    const bf16* Lt = LTm + (size_t)l*WW*WW;
    const bf16* Bsrc = (which==0 ? LTm : PTm) + (size_t)l*WW*WW;

    int wv=t>>6, lane=t&63;
    int qr=wv>>1, qc=wv&1;
    int ln=lane&15, cq=lane>>4;

    f4vec acc[4][4];
    #pragma unroll
    for (int m=0;m<4;m++)
        #pragma unroll
        for (int n=0;n<4;n++) acc[m][n]=(f4vec){0.f,0.f,0.f,0.f};

    for (int kt=0; kt<6; kt++){
        __syncthreads();
        // ---- stage Bs[u][k] = Bsrc[u0+u][kt*64+k], swizzled 16B chunks ----
        #pragma unroll
        for (int i=0;i<4;i++){
            int lin=t+256*i; int u=lin>>3, c8=lin&7;
            uint4 d = *reinterpret_cast<const uint4*>(&Bsrc[(size_t)(u0+u)*WW + kt*64 + c8*8]);
            *reinterpret_cast<uint4*>((char*)Bs + u*128 + (((c8 ^ (u&7)))<<4)) = d;
        }
        // ---- stage As ----
        if (which==0){
            #pragma unroll
            for (int i=0;i<4;i++){
                int lin=t+256*i; int w=lin>>3, c8=lin&7;
                uint4 d = *reinterpret_cast<const uint4*>(&Ap[(size_t)(w0+w)*WW + kt*64 + c8*8]);
                *reinterpret_cast<uint4*>((char*)As + w*128 + (((c8 ^ (w&7)))<<4)) = d;
            }
        } else {
            // As[w][vl] = L[w0+w][kt*64+vl] = LT[kt*64+vl][w0+w]
            // rotate write order by vl so lanes of one instruction hit different w&7
            #pragma unroll
            for (int i=0;i<4;i++){
                int lin=t+256*i; int vl=lin>>4, wc=lin&15;
                uint4 d = *reinterpret_cast<const uint4*>(&Lt[(size_t)(kt*64+vl)*WW + w0 + wc*8]);
                const unsigned short* pv = reinterpret_cast<const unsigned short*>(&d);
                #pragma unroll
                for (int jj=0;jj<8;jj++){
                    int e = (jj + vl) & 7;
                    int w = wc*8 + e;
                    *reinterpret_cast<unsigned short*>(
                        (char*)As + w*128 + (((vl>>3) ^ (w&7))<<4) + ((vl&7)<<1)) = pv[e];
                }
            }
        }
        __syncthreads();
        // ---- MFMA: 32 per wave ----
        #pragma unroll
        for (int kk=0;kk<2;kk++){
            s8vec a[4], bb[4];
            #pragma unroll
            for (int m=0;m<4;m++){
                int r = qr*64 + m*16 + ln;
                a[m] = *reinterpret_cast<const s8vec*>(
                    (const char*)As + r*128 + ((((kk*4+cq) ^ (r&7)))<<4));
            }
            #pragma unroll
            for (int n=0;n<4;n++){
                int u = qc*64 + n*16 + ln;
                bb[n] = *reinterpret_cast<const s8vec*>(
                    (const char*)Bs + u*128 + ((((kk*4+cq) ^ (u&7)))<<4));
            }
            #pragma unroll
            for (int m=0;m<4;m++)
                #pragma unroll
                for (int n=0;n<4;n++)
                    acc[m][n]=__builtin_amdgcn_mfma_f32_16x16x32_bf16(a[m],bb[n],acc[m][n],0,0,0);
        }
    }

    // ---- masked |D - I| reduction.  C/D layout: col = lane&15, row = (lane>>4)*4+reg ----
    float local = 0.f;
    #pragma unroll
    for (int n=0;n<4;n++){
        int ua = u0 + qc*64 + n*16 + ln;
        float mv = msk[ua];
        #pragma unroll
        for (int m=0;m<4;m++){
            int wbase = w0 + qr*64 + m*16 + cq*4;
            #pragma unroll
            for (int r=0;r<4;r++)
                local += mv * fabsf(acc[m][n][r] - ((ua==wbase+r)?1.f:0.f));
        }
    }
    for (int o=32;o;o>>=1) local += __shfl_xor(local,o,64);
    if (lane==0) red[wv]=local;
    __syncthreads();
    if (t==0) atomicAdd(&dsum[0], (double)(red[0]+red[1]+red[2]+red[3]));
}

// ---------------- K7: photometric loss + LR passthrough -- unchanged ----------------
__global__ __launch_bounds__(384) void k7_photo(
    const bf16* __restrict__ Pm, const bf16* __restrict__ LTm,
    const float* __restrict__ mask_r2l, const float* __restrict__ mask_l2r,
    const float* __restrict__ LRl, const float* __restrict__ LRr,
    float* __restrict__ out2, float* __restrict__ out3, double* __restrict__ dsum, int b)
{
    __shared__ float lrl[3*WW], lrr[3*WW];
    int t=threadIdx.x, l=blockIdx.x, seg=blockIdx.y;
    int bh=b*HH+l;
    for (int c=0;c<3;c++){
        size_t idx=((size_t)(b*3+c)*HH+l)*WW+t;
        float vl=LRl[idx], vr=LRr[idx];
        lrl[c*WW+t]=vl; lrr[c*WW+t]=vr;
        if (seg==0){ out2[idx]=vl; out3[idx]=vr; }
    }
    __syncthreads();
    const bf16* Pb  = Pm  + (size_t)l*WW*WW;
    const bf16* LTb = LTm + (size_t)l*WW*WW;
    int lane=t&63, wid=t>>6;
    float local=0.f;
    for (int w=seg*64+wid; w<seg*64+64; w+=6){
        const bf16* prow = Pb  + (size_t)w*WW;
        const bf16* lrow = LTb + (size_t)w*WW;
        float a0=0.f,a1=0.f,a2=0.f, d0=0.f,d1=0.f,d2=0.f;
        for (int k=0;k<6;k++){
            int v=lane+64*k;
            float mp=b2f(prow[v]), ml=b2f(lrow[v]);
            a0+=mp*lrr[v]; a1+=mp*lrr[WW+v]; a2+=mp*lrr[2*WW+v];
            d0+=ml*lrl[v]; d1+=ml*lrl[WW+v]; d2+=ml*lrl[2*WW+v];
        }
        for (int o=32;o;o>>=1){
            a0+=__shfl_xor(a0,o,64); a1+=__shfl_xor(a1,o,64); a2+=__shfl_xor(a2,o,64);
            d0+=__shfl_xor(d0,o,64); d1+=__shfl_xor(d1,o,64); d2+=__shfl_xor(d2,o,64);
        }
        if (lane==0){
            float mkL=mask_l2r[bh*WW+w], mkR=mask_r2l[bh*WW+w];
            local += mkL*(fabsf(lrl[w]-a0)+fabsf(lrl[WW+w]-a1)+fabsf(lrl[2*WW+w]-a2));
            local += mkR*(fabsf(lrr[w]-d0)+fabsf(lrr[WW+w]-d1)+fabsf(lrr[2*WW+w]-d2));
        }
    }
    if (lane==0) atomicAdd(&dsum[1],(double)local);
}

// ---------------- K8: smoothness losses -- unchanged ----------------
__global__ __launch_bounds__(384) void k8_smooth(
    const bf16* __restrict__ Pm, const bf16* __restrict__ LTm,
    double* __restrict__ dsum, int b)
{
    (void)b;
    int t=threadIdx.x, l=blockIdx.x, seg=blockIdx.y;
    const bf16* Pb  = Pm  + (size_t)l*WW*WW;
    const bf16* LTb = LTm + (size_t)l*WW*WW;
    int lane=t&63, wid=t>>6;
    bool hasnext = (l < HH-1);
    float lw=0.f, lh=0.f;
    for (int w=seg*64+wid; w<seg*64+64; w+=6){
        const bf16* p0  = Pb  + (size_t)w*WW;
        const bf16* lt0 = LTb + (size_t)w*WW;
        if (w < WW-1){
            const bf16* p1  = p0 + WW;
            const bf16* lt1 = lt0 + WW;
            for (int k=0;k<6;k++){
                int v=lane+64*k;
                if (v < WW-1){
                    lw += fabsf(b2f(p0[v]) - b2f(p1[v+1]));
                    lw += fabsf(b2f(lt0[v]) - b2f(lt1[v+1]));
                }
            }
        }
        if (hasnext){
            const bf16* pn  = p0  + (size_t)WW*WW;
            const bf16* ltn = lt0 + (size_t)WW*WW;
            for (int k=0;k<6;k++){
                int v=lane+64*k;
                lh += fabsf(b2f(p0[v]) - b2f(pn[v]));
                lh += fabsf(b2f(lt0[v]) - b2f(ltn[v]));
            }
        }
    }
    for (int o=32;o;o>>=1){ lw+=__shfl_xor(lw,o,64); lh+=__shfl_xor(lh,o,64); }
    if (lane==0){
        atomicAdd(&dsum[3],(double)lw);
        atomicAdd(&dsum[2],(double)lh);
    }
}

// ---------------- K9: final loss -- unchanged ----------------
__global__ void k9_final(const double* __restrict__ dsum, const float* __restrict__ lossin,
                         float* __restrict__ out4)
{
    if (threadIdx.x==0){
        double cyc  = dsum[0]/(double)((size_t)BB*HH*WW*WW);
        double photo= dsum[1]/(double)((size_t)BB*3*HH*WW);
        double lhv  = dsum[2]/(double)((size_t)BB*(HH-1)*WW*WW);
        double lwv  = dsum[3]/(double)((size_t)BB*HH*(WW-1)*(WW-1));
        double res  = (double)lossin[0] + 0.0025*(photo + 0.1*(lwv+lhv) + cyc);
        out4[0]=(float)res;
    }
}

extern "C" void kernel_launch(void* const* d_in, const int* in_sizes, int n_in,
                              void* d_out, int out_size, void* d_ws, size_t ws_size,
                              hipStream_t stream)
{
    (void)in_sizes; (void)n_in; (void)out_size; (void)ws_size;
    const float* x_l  = (const float*)d_in[0];
    const float* x_r  = (const float*)d_in[1];
    const float* LRl  = (const float*)d_in[2];
    const float* LRr  = (const float*)d_in[3];
    const float* lossi= (const float*)d_in[4];
    const float* nlw  = (const float*)d_in[5];
    const float* nlb  = (const float*)d_in[6];
    const float* nrw  = (const float*)d_in[7];
    const float* nrb  = (const float*)d_in[8];
    const float* lp1w = (const float*)d_in[9];
    const float* lp1b = (const float*)d_in[10];
    const float* rp1w = (const float*)d_in[11];
    const float* rp1b = (const float*)d_in[12];
    const float* lp2w = (const float*)d_in[13];
    const float* lp2b = (const float*)d_in[14];
    const float* rp2w = (const float*)d_in[15];
    const float* rp2b = (const float*)d_in[16];
    const float* beta = (const float*)d_in[17];
    const float* gamma= (const float*)d_in[18];

    bf16* Abuf = (bf16*)d_ws;             // A -> P in-place
    bf16* LTb  = Abuf + ACHUNK;
    bf16* PTb  = Abuf + 2*ACHUNK;
    float* wsf = (float*)((char*)d_ws + 3*ACHUNK*2);
    float* rmax=wsf, *irsum=wsf+SST, *cmax=wsf+2*SST, *icsum=wsf+3*SST;
    float* mask_r2l=wsf+4*SST, *mask_l2r=wsf+5*SST;
    double* dsum=(double*)(wsf+6*SST);
    // Q and V all alias the PT chunk (4*QELEMS <= ACHUNK); dead before k_trans runs.
    bf16* Qlb = PTb;
    bf16* Qrb = PTb + QELEMS;
    bf16* Vlb = PTb + 2*QELEMS;
    bf16* Vrb = PTb + 3*QELEMS;

    float* out  = (float*)d_out;
    float* out0 = out;
    float* out1 = out + (size_t)BB*CHW;
    float* out2 = out + 2*(size_t)BB*CHW;
    float* out3 = out2 + (size_t)BB*3*HW;
    float* out4 = out3 + (size_t)BB*3*HW;

    k0_zero<<<1,64,0,stream>>>(dsum);
    for (int b=0;b<BB;b++){
        k_qv<<<dim3(6,HH),256,0,stream>>>(x_l,x_r,nlw,nlb,nrw,nrb,
                                          lp1w,lp1b,rp1w,rp1b,lp2w,lp2b,rp2w,rp2b,
                                          Qlb,Qrb,Vlb,Vrb,b);
        k_attn<<<dim3(3,3,HH),256,0,stream>>>(Qlb,Qrb,Abuf);
        k3_stats<<<dim3(HH,6),384,0,stream>>>(Abuf,rmax,irsum,cmax,icsum,b);
        k_mats<<<dim3(HH,6),256,0,stream>>>(Abuf,LTb,rmax,irsum,cmax,icsum,b);
        k4_masks<<<dim3(HH,6),384,0,stream>>>(Abuf,LTb,mask_r2l,mask_l2r,b);
        k5m<<<dim3(6,HH),256,0,stream>>>(Abuf,Vrb,x_l,beta, out0,b,0);   // V consumed here,
        k5m<<<dim3(6,HH),256,0,stream>>>(LTb, Vlb,x_r,gamma,out1,b,1);   // BEFORE k_trans
        k_trans<<<dim3(6,6,HH),256,0,stream>>>(Abuf,PTb);
        k6_mfma<<<1728,256,0,stream>>>(Abuf,LTb,PTb,mask_r2l,mask_l2r,dsum,b);
        k7_photo<<<dim3(HH,6),384,0,stream>>>(Abuf,LTb,mask_r2l,mask_l2r,LRl,LRr,out2,out3,dsum,b);
        k8_smooth<<<dim3(HH,6),384,0,stream>>>(Abuf,LTb,dsum,b);
    }
    k9_final<<<1,64,0,stream>>>(dsum,lossi,out4);
}

// Round 6
// 1685.665 us; speedup vs baseline: 1.1040x; 1.0567x over previous
//
#include <hip/hip_runtime.h>
#include <hip/hip_bf16.h>

#define BB 4
#define CC 64
#define HH 96
#define WW 384
#define HW (HH*WW)          // 36864
#define CHW (CC*HW)         // 2359296
#define BH (BB*HH)          // 384
#define EPSV 1e-6f
#define QSCALE 0.125f       // C^-0.5, folded into Q_l

typedef __hip_bfloat16 bf16;
typedef short s8vec __attribute__((ext_vector_type(8)));   // 8 bf16 = one MFMA frag
typedef float f4vec __attribute__((ext_vector_type(4)));   // MFMA accum

__device__ __forceinline__ float b2f(bf16 v){ return __bfloat162float(v); }
__device__ __forceinline__ bf16 f2b(float v){ return __float2bfloat16(v); }
__device__ __forceinline__ unsigned short f2bu(float f){
    bf16 h = __float2bfloat16(f);
    return __builtin_bit_cast(unsigned short, h);
}

// ---------------- workspace layout (per-batch chunk) ----------------
#define ACHUNK ((size_t)HH*WW*WW)    // 14,155,776 elems
#define SST ((size_t)BH*WW)          // 147456
#define QELEMS ((size_t)HW*64)       // 2,359,296

// LDS chunk swizzle for k6: row-dependent XOR that varies in the LOW 3 bits of row,
// so both linear-row staging (c8 spreads) AND the w=wc*8+jj scatter (g varies with wc)
// are conflict-free, and MFMA 16-lane reads (r varies with ln) spread over 8 chunks.
#define SWZ(row) ((((row) + ((row)>>3)) & 7))

// ---------------- K0: zero loss accumulators ----------------
__global__ void k0_zero(double* dsum){
    if (threadIdx.x < 4) dsum[threadIdx.x] = 0.0;
}

// ---------------- K_qv: LN + proj1 -> Q (bf16), proj2 -> V (bf16) -- unchanged ----------------
__global__ __launch_bounds__(256) void k_qv(
    const float* __restrict__ xl, const float* __restrict__ xr,
    const float* __restrict__ nlw, const float* __restrict__ nlb,
    const float* __restrict__ nrw, const float* __restrict__ nrb,
    const float* __restrict__ P1l, const float* __restrict__ b1l,
    const float* __restrict__ P1r, const float* __restrict__ b1r,
    const float* __restrict__ P2l, const float* __restrict__ b2l,
    const float* __restrict__ P2r, const float* __restrict__ b2r,
    bf16* __restrict__ Ql, bf16* __restrict__ Qr,
    bf16* __restrict__ Vl, bf16* __restrict__ Vr, int b)
{
    __shared__ float xs[64*64];                  // [c][w]
    __shared__ float p1s[64*65], p2s[64*65];     // [o][c]
    __shared__ float nws[64], nbs[64], b1s[64], b2s[64];
    __shared__ float mus[64], ris[64];
    int t = threadIdx.x;
    int wt = blockIdx.x, l = blockIdx.y;
    int w0 = wt*64;

    for (int side=0; side<2; side++){
        const float* x  = side ? xr  : xl;
        const float* nw = side ? nrw : nlw;
        const float* nb = side ? nrb : nlb;
        const float* P1 = side ? P1r : P1l;
        const float* B1 = side ? b1r : b1l;
        const float* P2 = side ? P2r : P2l;
        const float* B2 = side ? b2r : b2l;
        bf16* Q = side ? Qr : Ql;
        bf16* V = side ? Vr : Vl;
        float qsc = side ? 1.f : QSCALE;

        if (t < 64){ nws[t]=nw[t]; nbs[t]=nb[t]; b1s[t]=B1[t]; b2s[t]=B2[t]; }
        for (int k=0;k<16;k++){
            int i=t+256*k; int o=i>>6, c=i&63;
            p1s[o*65+c]=P1[i]; p2s[o*65+c]=P2[i];
        }
        const float* xb = x + (size_t)b*CHW + (size_t)l*WW + w0;
        for (int k=0;k<16;k++){
            int c=(t>>6)+4*k, w=t&63;
            xs[c*64+w] = xb[(size_t)c*HW + w];
        }
        __syncthreads();
        if (t < 64){
            float s=0.f, ss=0.f;
            for (int c=0;c<64;c++){ float v=xs[c*64+t]; s+=v; ss+=v*v; }
            float mu=s*(1.f/64.f), var=ss*(1.f/64.f)-mu*mu;
            mus[t]=mu; ris[t]=rsqrtf(var+EPSV);
        }
        __syncthreads();

        {
            int vq=t&15, ov=t>>4;
            float acc[4][4]={};
            for (int c=0;c<64;c++){
                float xv[4];
                for (int j=0;j<4;j++) xv[j]=xs[c*64+vq*4+j];
                for (int i=0;i<4;i++){
                    float w2=p2s[(ov*4+i)*65+c];
                    for (int j=0;j<4;j++) acc[i][j]+=w2*xv[j];
                }
            }
            for (int i=0;i<4;i++){
                int c=ov*4+i;
                ushort4 pk;
                pk.x=f2bu(acc[i][0]+b2s[c]); pk.y=f2bu(acc[i][1]+b2s[c]);
                pk.z=f2bu(acc[i][2]+b2s[c]); pk.w=f2bu(acc[i][3]+b2s[c]);
                *reinterpret_cast<ushort4*>(&V[(size_t)c*HW + (size_t)l*WW + w0 + vq*4]) = pk;
            }
        }
        {
            int cq=t&15, wq=t>>4;
            float muj[4], rij[4];
            for (int j=0;j<4;j++){ muj[j]=mus[wq*4+j]; rij[j]=ris[wq*4+j]; }
            float acc[4][4]={};
            for (int c=0;c<64;c++){
                float nwc=nws[c], nbc=nbs[c];
                float xn[4];
                for (int j=0;j<4;j++) xn[j]=(xs[c*64+wq*4+j]-muj[j])*rij[j]*nwc+nbc;
                for (int i=0;i<4;i++){
                    float w1=p1s[(cq*4+i)*65+c];
                    for (int j=0;j<4;j++) acc[i][j]+=w1*xn[j];
                }
            }
            for (int j=0;j<4;j++){
                int w=w0+wq*4+j;
                ushort4 pk;
                pk.x=f2bu(qsc*(acc[0][j]+b1s[cq*4+0]));
                pk.y=f2bu(qsc*(acc[1][j]+b1s[cq*4+1]));
                pk.z=f2bu(qsc*(acc[2][j]+b1s[cq*4+2]));
                pk.w=f2bu(qsc*(acc[3][j]+b1s[cq*4+3]));
                *reinterpret_cast<ushort4*>(&Q[((size_t)l*WW + w)*64 + cq*4]) = pk;
            }
        }
        __syncthreads();   // LDS reuse by next side
    }
}

// ---------------- K_attn: A = Q_l^T Q_r via MFMA -- unchanged ----------------
__global__ __launch_bounds__(256) void k_attn(
    const bf16* __restrict__ Ql, const bf16* __restrict__ Qr,
    bf16* __restrict__ Abuf)
{
    __shared__ bf16 As[128*72];   // [w-row][c], stride 72 (144B: 2-way bank alias = free)
    __shared__ bf16 Bs[128*72];   // [v-row][c]
    int t=threadIdx.x;
    int mt=blockIdx.x, nt=blockIdx.y, l=blockIdx.z;
    const bf16* Qa = Ql + ((size_t)l*WW + mt*128)*64;
    const bf16* Qb = Qr + ((size_t)l*WW + nt*128)*64;
    for (int i=0;i<4;i++){
        int lin=t+256*i;            // 0..1023 over 128 rows x 8 chunks
        int r=lin>>3, c8=lin&7;
        *reinterpret_cast<uint4*>(&As[r*72+c8*8]) =
            *reinterpret_cast<const uint4*>(&Qa[(size_t)r*64 + c8*8]);
        *reinterpret_cast<uint4*>(&Bs[r*72+c8*8]) =
            *reinterpret_cast<const uint4*>(&Qb[(size_t)r*64 + c8*8]);
    }
    __syncthreads();
    int wv=t>>6, lane=t&63;
    int m0=(wv>>1)*64, n0=(wv&1)*64;
    int ln=lane&15, cq=lane>>4;
    f4vec acc[4][4];
    #pragma unroll
    for (int m=0;m<4;m++)
        #pragma unroll
        for (int n=0;n<4;n++) acc[m][n]=(f4vec){0.f,0.f,0.f,0.f};
    #pragma unroll
    for (int kk=0;kk<2;kk++){
        s8vec a[4], bb[4];
        #pragma unroll
        for (int m=0;m<4;m++) a[m]=*reinterpret_cast<const s8vec*>(&As[(m0+m*16+ln)*72 + kk*32 + cq*8]);
        #pragma unroll
        for (int n=0;n<4;n++) bb[n]=*reinterpret_cast<const s8vec*>(&Bs[(n0+n*16+ln)*72 + kk*32 + cq*8]);
        #pragma unroll
        for (int m=0;m<4;m++)
            #pragma unroll
            for (int n=0;n<4;n++)
                acc[m][n]=__builtin_amdgcn_mfma_f32_16x16x32_bf16(a[m],bb[n],acc[m][n],0,0,0);
    }
    bf16* Ab = Abuf + (size_t)l*WW*WW;
    // C/D layout: col = lane&15, row = (lane>>4)*4 + reg
    #pragma unroll
    for (int m=0;m<4;m++){
        #pragma unroll
        for (int r=0;r<4;r++){
            int w = mt*128 + m0 + m*16 + cq*4 + r;
            #pragma unroll
            for (int n=0;n<4;n++){
                int v = nt*128 + n0 + n*16 + ln;
                Ab[(size_t)w*WW + v] = f2b(acc[m][n][r]);
            }
        }
    }
}

// ---------------- K3: softmax stats (row + col) -- unchanged ----------------
__global__ __launch_bounds__(384) void k3_stats(
    const bf16* __restrict__ Abuf, float* __restrict__ rmax, float* __restrict__ irsum,
    float* __restrict__ cmax, float* __restrict__ icsum, int b)
{
    __shared__ float pm[6][64], ps[6][64];
    int t=threadIdx.x, l=blockIdx.x, seg=blockIdx.y;
    int bh=b*HH+l;
    const bf16* Ab = Abuf + (size_t)l*WW*WW;
    int lane=t&63, wid=t>>6;
    for (int w=seg*64+wid; w<seg*64+64; w+=6){
        const bf16* row=Ab+(size_t)w*WW;
        float m=-1e30f;
        for (int k=0;k<6;k++) m=fmaxf(m,b2f(row[lane+64*k]));
        for (int o=32;o;o>>=1) m=fmaxf(m,__shfl_xor(m,o,64));
        float s=0.f;
        for (int k=0;k<6;k++) s+=__expf(b2f(row[lane+64*k])-m);
        for (int o=32;o;o>>=1) s+=__shfl_xor(s,o,64);
        if (lane==0){ rmax[bh*WW+w]=m; irsum[bh*WW+w]=1.f/s; }
    }
    {
        int c=t&63, v=seg*64+c;
        float m=-1e30f;
        for (int w=wid*64; w<wid*64+64; w++) m=fmaxf(m,b2f(Ab[(size_t)w*WW+v]));
        float s=0.f;
        for (int w=wid*64; w<wid*64+64; w++) s+=__expf(b2f(Ab[(size_t)w*WW+v])-m);
        pm[wid][c]=m; ps[wid][c]=s;
    }
    __syncthreads();
    if (t<64){
        float M=-1e30f;
        for (int p=0;p<6;p++) M=fmaxf(M,pm[p][t]);
        float S=0.f;
        for (int p=0;p<6;p++) S+=ps[p][t]*__expf(pm[p][t]-M);
        cmax[bh*WW+seg*64+t]=M; icsum[bh*WW+seg*64+t]=1.f/S;
    }
}

// ---------------- K_mats: A -> P (in-place) + LT -- unchanged ----------------
__global__ __launch_bounds__(256) void k_mats(
    bf16* __restrict__ AP, bf16* __restrict__ LT,
    const float* __restrict__ rmax, const float* __restrict__ irsum,
    const float* __restrict__ cmax, const float* __restrict__ icsum, int b)
{
    int t=threadIdx.x, l=blockIdx.x, seg=blockIdx.y;
    int bh=b*HH+l;
    bf16* Ab  = AP + (size_t)l*WW*WW;
    bf16* LTb = LT + (size_t)l*WW*WW;
    const float* rm=rmax+(size_t)bh*WW; const float* ris=irsum+(size_t)bh*WW;
    const float* cm=cmax+(size_t)bh*WW; const float* cis=icsum+(size_t)bh*WW;
    int lane6=t&63;
    float cmv[6], civ[6];
    for (int s=0;s<6;s++){ cmv[s]=cm[s*64+lane6]; civ[s]=cis[s*64+lane6]; }
    for (int k=0;k<16;k++){
        int w = seg*64 + (t>>6) + 4*k;
        float rmw = rm[w], risw = ris[w];
        for (int s=0;s<6;s++){
            int v = s*64 + lane6;
            size_t idx = (size_t)w*WW + v;
            float a = b2f(Ab[idx]);
            Ab[idx]  = f2b(__expf(a - rmw)*risw);       // P[w][v] = M_r2l[w][v]
            LTb[idx] = f2b(__expf(a - cmv[s])*civ[s]);  // LT[w][v] = M_l2r[v][w]
        }
    }
}

// ---------------- K_trans: PT = P^T -- unchanged ----------------
__global__ __launch_bounds__(256) void k_trans(
    const bf16* __restrict__ Pm, bf16* __restrict__ PTm)
{
    __shared__ float tile[64][65];
    int t=threadIdx.x;
    int ti=blockIdx.x, tj=blockIdx.y, l=blockIdx.z;
    const bf16* Pb = Pm + (size_t)l*WW*WW;
    bf16* PTb = PTm + (size_t)l*WW*WW;
    for (int k=0;k<16;k++){
        int r=(t>>6)+4*k, c=t&63;
        tile[r][c] = b2f(Pb[(size_t)(ti*64+r)*WW + tj*64+c]);
    }
    __syncthreads();
    for (int k=0;k<16;k++){
        int r=(t>>6)+4*k, c=t&63;
        PTb[(size_t)(tj*64+r)*WW + ti*64+c] = f2b(tile[c][r]);
    }
}

// ---------------- K4: validity masks -- unchanged ----------------
__global__ __launch_bounds__(384) void k4_masks(
    const bf16* __restrict__ Pm, const bf16* __restrict__ LTm,
    float* __restrict__ mask_r2l, float* __restrict__ mask_l2r, int b)
{
    __shared__ float pa[6][64];
    int t=threadIdx.x, l=blockIdx.x, seg=blockIdx.y;
    int bh=b*HH+l;
    const bf16* Pb  = Pm  + (size_t)l*WW*WW;
    const bf16* LTb = LTm + (size_t)l*WW*WW;
    int lane=t&63, wid=t>>6;
    {
        int c=t&63, v=seg*64+c;
        float s=0.f;
        for (int w=wid*64; w<wid*64+64; w++) s+=b2f(Pb[(size_t)w*WW+v]);
        pa[wid][c]=s;
    }
    __syncthreads();
    if (t<64){
        float S=0.f;
        for (int p=0;p<6;p++) S+=pa[p][t];
        mask_r2l[bh*WW+seg*64+t]=(S>0.1f)?1.f:0.f;
    }
    for (int u=seg*64+wid; u<seg*64+64; u+=6){
        const bf16* row=LTb+(size_t)u*WW;
        float s=0.f;
        for (int k=0;k<6;k++) s+=b2f(row[lane+64*k]);
        for (int o=32;o;o>>=1) s+=__shfl_xor(s,o,64);
        if (lane==0) mask_l2r[bh*WW+u]=(s>0.1f)?1.f:0.f;
    }
}

// ---------------- K5m: out = x + coef * (M @ V^T) via MFMA -- unchanged ----------------
__global__ __launch_bounds__(256) void k5m(
    const bf16* __restrict__ Msrc, const bf16* __restrict__ VT,
    const float* __restrict__ xadd, const float* __restrict__ coef,
    float* __restrict__ outp, int b, int side)
{
    __shared__ bf16 As[64*72];   // VT tile [c][v]
    __shared__ bf16 Bs[64*72];   // M tile  [w][v]
    int t=threadIdx.x;
    int wt=blockIdx.x, l=blockIdx.y;
    int w0=wt*64;
    int wv=t>>6, lane=t&63;
    int cb=(wv>>1)*32, wb=(wv&1)*32;
    int ln=lane&15, cq=lane>>4;
    f4vec acc[2][2];
    #pragma unroll
    for (int m=0;m<2;m++)
        #pragma unroll
        for (int n=0;n<2;n++) acc[m][n]=(f4vec){0.f,0.f,0.f,0.f};
    const bf16* Mb = Msrc + (size_t)l*WW*WW;

    for (int vt=0;vt<6;vt++){
        int v0=vt*64;
        __syncthreads();
        for (int i=0;i<2;i++){
            int lin=t+256*i; int c=lin>>3, c8=lin&7;
            *reinterpret_cast<uint4*>(&As[c*72+c8*8]) =
                *reinterpret_cast<const uint4*>(&VT[(size_t)c*HW + (size_t)l*WW + v0 + c8*8]);
        }
        if (side==0){
            for (int i=0;i<2;i++){
                int lin=t+256*i; int r=lin>>3, c8=lin&7;
                *reinterpret_cast<uint4*>(&Bs[r*72+c8*8]) =
                    *reinterpret_cast<const uint4*>(&Mb[(size_t)(w0+r)*WW + v0 + c8*8]);
            }
        } else {
            int wl=t&63, j0=t>>6;
            for (int jj=0;jj<16;jj++){
                int j=j0+4*jj;
                Bs[wl*72+j] = Mb[(size_t)(v0+j)*WW + w0 + wl];
            }
        }
        __syncthreads();
        #pragma unroll
        for (int kk=0;kk<2;kk++){
            s8vec a[2], bb[2];
            #pragma unroll
            for (int m=0;m<2;m++) a[m]=*reinterpret_cast<const s8vec*>(&As[(cb+m*16+ln)*72+kk*32+cq*8]);
            #pragma unroll
            for (int n=0;n<2;n++) bb[n]=*reinterpret_cast<const s8vec*>(&Bs[(wb+n*16+ln)*72+kk*32+cq*8]);
            #pragma unroll
            for (int m=0;m<2;m++)
                #pragma unroll
                for (int n=0;n<2;n++)
                    acc[m][n]=__builtin_amdgcn_mfma_f32_16x16x32_bf16(a[m],bb[n],acc[m][n],0,0,0);
        }
    }
    const float* xb = xadd + (size_t)b*CHW + (size_t)l*WW + w0;
    float*      ob = outp + (size_t)b*CHW + (size_t)l*WW + w0;
    #pragma unroll
    for (int m=0;m<2;m++){
        #pragma unroll
        for (int r=0;r<4;r++){
            int c = cb + m*16 + cq*4 + r;
            float cf = coef[c];
            #pragma unroll
            for (int n=0;n<2;n++){
                int w = wb + n*16 + ln;
                ob[(size_t)c*HW + w] = xb[(size_t)c*HW + w] + cf*acc[m][n][r];
            }
        }
    }
}

// ---------------- K6: cycle loss GEMMs -- 2-phase double-buffered pipeline ----------------
// Grid 1728 (XCD l-affinity decode unchanged from R5: FETCH 42MB, keep it).
// Per kt: {issue next-tile global loads -> regs} || {ds_read cur buf + 32 MFMA/wave}
// then ds_write next buf, ONE barrier. L2 latency hides under the MFMA burst.
// Swizzle SWZ(row) varies in row's low bits -> which==1 b32 scatter (e=jj compile-time,
// w=wc*8+jj) spreads 32 banks x 2-way (free); MFMA reads stay spread.
__global__ __launch_bounds__(256) void k6_mfma(
    const bf16* __restrict__ Pm, const bf16* __restrict__ LTm, const bf16* __restrict__ PTm,
    const float* __restrict__ mask_r2l, const float* __restrict__ mask_l2r,
    double* __restrict__ dsum, int b)
{
    __shared__ bf16 As[2][128*64];   // [buf][w][k] swizzled
    __shared__ bf16 Bs[2][128*64];   // [buf][u][k] swizzled
    int t=threadIdx.x;
    int wg=blockIdx.x;
    int xcd = wg & 7, j = wg >> 3;
    int lgrp = j/18, tile = j - lgrp*18;
    int l = xcd + 8*lgrp;                   // all 18 tiles of l on one XCD
    int which = tile/9; int xt = tile - which*9;
    int wt = xt/3, ut = xt - wt*3;
    int w0=wt*128, u0=ut*128, bh=b*HH+l;
    const float* msk = which ? (mask_r2l+(size_t)bh*WW) : (mask_l2r+(size_t)bh*WW);
    const bf16* Ap = Pm  + (size_t)l*WW*WW;
    const bf16* Lt = LTm + (size_t)l*WW*WW;
    const bf16* Bsrc = (which==0 ? LTm : PTm) + (size_t)l*WW*WW;

    int wv=t>>6, lane=t&63;
    int qr=wv>>1, qc=wv&1;
    int ln=lane&15, cq=lane>>4;

    uint4 rb[4], ra[4];     // staging regs (B; A which==0)
    uint4 r0[2], r1[2];     // staging regs (A which==1: v-pair rows)

    auto stage_read = [&](int kt){
        #pragma unroll
        for (int i=0;i<4;i++){
            int lin=t+256*i; int u=lin>>3, c8=lin&7;
            rb[i] = *reinterpret_cast<const uint4*>(&Bsrc[(size_t)(u0+u)*WW + kt*64 + c8*8]);
        }
        if (which==0){
            #pragma unroll
            for (int i=0;i<4;i++){
                int lin=t+256*i; int w=lin>>3, c8=lin&7;
                ra[i] = *reinterpret_cast<const uint4*>(&Ap[(size_t)(w0+w)*WW + kt*64 + c8*8]);
            }
        } else {
            #pragma unroll
            for (int i=0;i<2;i++){
                int p=(t>>4)+16*i, wc=t&15;
                const bf16* base = &Lt[(size_t)(kt*64 + 2*p)*WW + w0 + wc*8];
                r0[i] = *reinterpret_cast<const uint4*>(base);
                r1[i] = *reinterpret_cast<const uint4*>(base + WW);
            }
        }
    };
    auto stage_write = [&](int bufi){
        bf16* bsw = Bs[bufi]; bf16* asw = As[bufi];
        #pragma unroll
        for (int i=0;i<4;i++){
            int lin=t+256*i; int u=lin>>3, c8=lin&7;
            *reinterpret_cast<uint4*>((char*)bsw + u*128 + ((c8 ^ SWZ(u))<<4)) = rb[i];
        }
        if (which==0){
            #pragma unroll
            for (int i=0;i<4;i++){
                int lin=t+256*i; int w=lin>>3, c8=lin&7;
                *reinterpret_cast<uint4*>((char*)asw + w*128 + ((c8 ^ SWZ(w))<<4)) = ra[i];
            }
        } else {
            // As[w][2p],[2p+1] = L[w0+w][kt*64+2p..] = LT[..][w0+w]; b32 pair writes.
            #pragma unroll
            for (int i=0;i<2;i++){
                int p=(t>>4)+16*i, wc=t&15;
                const unsigned short* q0 = reinterpret_cast<const unsigned short*>(&r0[i]);
                const unsigned short* q1 = reinterpret_cast<const unsigned short*>(&r1[i]);
                int cb2 = p>>2, off = (p&3)*4;
                #pragma unroll
                for (int jj=0;jj<8;jj++){
                    int w = wc*8 + jj;
                    unsigned val = (unsigned)q0[jj] | ((unsigned)q1[jj]<<16);
                    *reinterpret_cast<unsigned*>((char*)asw + w*128 + ((cb2 ^ SWZ(w))<<4) + off) = val;
                }
            }
        }
    };

    f4vec acc[4][4];
    #pragma unroll
    for (int m=0;m<4;m++)
        #pragma unroll
        for (int n=0;n<4;n++) acc[m][n]=(f4vec){0.f,0.f,0.f,0.f};

    // prologue
    stage_read(0);
    stage_write(0);
    __syncthreads();
    int cur=0;
    for (int kt=0; kt<6; kt++){
        if (kt<5) stage_read(kt+1);              // loads in flight during MFMA
        const bf16* as = As[cur]; const bf16* bs = Bs[cur];
        #pragma unroll
        for (int kk=0;kk<2;kk++){
            s8vec a[4], bb[4];
            #pragma unroll
            for (int m=0;m<4;m++){
                int r = qr*64 + m*16 + ln;
                a[m] = *reinterpret_cast<const s8vec*>(
                    (const char*)as + r*128 + (((kk*4+cq) ^ SWZ(r))<<4));
            }
            #pragma unroll
            for (int n=0;n<4;n++){
                int u = qc*64 + n*16 + ln;
                bb[n] = *reinterpret_cast<const s8vec*>(
                    (const char*)bs + u*128 + (((kk*4+cq) ^ SWZ(u))<<4));
            }
            #pragma unroll
            for (int m=0;m<4;m++)
                #pragma unroll
                for (int n=0;n<4;n++)
                    acc[m][n]=__builtin_amdgcn_mfma_f32_16x16x32_bf16(a[m],bb[n],acc[m][n],0,0,0);
        }
        if (kt<5) stage_write(cur^1);
        __syncthreads();
        cur ^= 1;
    }

    // ---- masked |D - I| reduction.  C/D layout: col = lane&15, row = (lane>>4)*4+reg ----
    float local = 0.f;
    #pragma unroll
    for (int n=0;n<4;n++){
        int ua = u0 + qc*64 + n*16 + ln;
        float mv = msk[ua];
        #pragma unroll
        for (int m=0;m<4;m++){
            int wbase = w0 + qr*64 + m*16 + cq*4;
            #pragma unroll
            for (int r=0;r<4;r++)
                local += mv * fabsf(acc[m][n][r] - ((ua==wbase+r)?1.f:0.f));
        }
    }
    for (int o=32;o;o>>=1) local += __shfl_xor(local,o,64);
    float* red = (float*)As;   // As dead after loop's final barrier
    if (lane==0) red[wv]=local;
    __syncthreads();
    if (t==0) atomicAdd(&dsum[0], (double)(red[0]+red[1]+red[2]+red[3]));
}

// ---------------- K78: photometric + smoothness losses fused (same inputs, one pass) ----------------
__global__ __launch_bounds__(384) void k78_photo_smooth(
    const bf16* __restrict__ Pm, const bf16* __restrict__ LTm,
    const float* __restrict__ mask_r2l, const float* __restrict__ mask_l2r,
    const float* __restrict__ LRl, const float* __restrict__ LRr,
    float* __restrict__ out2, float* __restrict__ out3, double* __restrict__ dsum, int b)
{
    __shared__ float lrl[3*WW], lrr[3*WW];
    int t=threadIdx.x, l=blockIdx.x, seg=blockIdx.y;
    int bh=b*HH+l;
    for (int c=0;c<3;c++){
        size_t idx=((size_t)(b*3+c)*HH+l)*WW+t;
        float vl=LRl[idx], vr=LRr[idx];
        lrl[c*WW+t]=vl; lrr[c*WW+t]=vr;
        if (seg==0){ out2[idx]=vl; out3[idx]=vr; }
    }
    __syncthreads();
    const bf16* Pb  = Pm  + (size_t)l*WW*WW;
    const bf16* LTb = LTm + (size_t)l*WW*WW;
    int lane=t&63, wid=t>>6;
    // ---- photometric ----
    float local=0.f;
    for (int w=seg*64+wid; w<seg*64+64; w+=6){
        const bf16* prow = Pb  + (size_t)w*WW;
        const bf16* lrow = LTb + (size_t)w*WW;
        float a0=0.f,a1=0.f,a2=0.f, d0=0.f,d1=0.f,d2=0.f;
        for (int k=0;k<6;k++){
            int v=lane+64*k;
            float mp=b2f(prow[v]), ml=b2f(lrow[v]);
            a0+=mp*lrr[v]; a1+=mp*lrr[WW+v]; a2+=mp*lrr[2*WW+v];
            d0+=ml*lrl[v]; d1+=ml*lrl[WW+v]; d2+=ml*lrl[2*WW+v];
        }
        for (int o=32;o;o>>=1){
            a0+=__shfl_xor(a0,o,64); a1+=__shfl_xor(a1,o,64); a2+=__shfl_xor(a2,o,64);
            d0+=__shfl_xor(d0,o,64); d1+=__shfl_xor(d1,o,64); d2+=__shfl_xor(d2,o,64);
        }
        if (lane==0){
            float mkL=mask_l2r[bh*WW+w], mkR=mask_r2l[bh*WW+w];
            local += mkL*(fabsf(lrl[w]-a0)+fabsf(lrl[WW+w]-a1)+fabsf(lrl[2*WW+w]-a2));
            local += mkR*(fabsf(lrr[w]-d0)+fabsf(lrr[WW+w]-d1)+fabsf(lrr[2*WW+w]-d2));
        }
    }
    // ---- smoothness ----
    bool hasnext = (l < HH-1);
    float lw=0.f, lh=0.f;
    for (int w=seg*64+wid; w<seg*64+64; w+=6){
        const bf16* p0  = Pb  + (size_t)w*WW;
        const bf16* lt0 = LTb + (size_t)w*WW;
        if (w < WW-1){
            const bf16* p1  = p0 + WW;
            const bf16* lt1 = lt0 + WW;
            for (int k=0;k<6;k++){
                int v=lane+64*k;
                if (v < WW-1){
                    lw += fabsf(b2f(p0[v]) - b2f(p1[v+1]));
                    lw += fabsf(b2f(lt0[v]) - b2f(lt1[v+1]));
                }
            }
        }
        if (hasnext){
            const bf16* pn  = p0  + (size_t)WW*WW;
            const bf16* ltn = lt0 + (size_t)WW*WW;
            for (int k=0;k<6;k++){
                int v=lane+64*k;
                lh += fabsf(b2f(p0[v]) - b2f(pn[v]));
                lh += fabsf(b2f(lt0[v]) - b2f(ltn[v]));
            }
        }
    }
    for (int o=32;o;o>>=1){ lw+=__shfl_xor(lw,o,64); lh+=__shfl_xor(lh,o,64); }
    if (lane==0){
        atomicAdd(&dsum[1],(double)local);
        atomicAdd(&dsum[3],(double)lw);
        atomicAdd(&dsum[2],(double)lh);
    }
}

// ---------------- K9: final loss -- unchanged ----------------
__global__ void k9_final(const double* __restrict__ dsum, const float* __restrict__ lossin,
                         float* __restrict__ out4)
{
    if (threadIdx.x==0){
        double cyc  = dsum[0]/(double)((size_t)BB*HH*WW*WW);
        double photo= dsum[1]/(double)((size_t)BB*3*HH*WW);
        double lhv  = dsum[2]/(double)((size_t)BB*(HH-1)*WW*WW);
        double lwv  = dsum[3]/(double)((size_t)BB*HH*(WW-1)*(WW-1));
        double res  = (double)lossin[0] + 0.0025*(photo + 0.1*(lwv+lhv) + cyc);
        out4[0]=(float)res;
    }
}

extern "C" void kernel_launch(void* const* d_in, const int* in_sizes, int n_in,
                              void* d_out, int out_size, void* d_ws, size_t ws_size,
                              hipStream_t stream)
{
    (void)in_sizes; (void)n_in; (void)out_size; (void)ws_size;
    const float* x_l  = (const float*)d_in[0];
    const float* x_r  = (const float*)d_in[1];
    const float* LRl  = (const float*)d_in[2];
    const float* LRr  = (const float*)d_in[3];
    const float* lossi= (const float*)d_in[4];
    const float* nlw  = (const float*)d_in[5];
    const float* nlb  = (const float*)d_in[6];
    const float* nrw  = (const float*)d_in[7];
    const float* nrb  = (const float*)d_in[8];
    const float* lp1w = (const float*)d_in[9];
    const float* lp1b = (const float*)d_in[10];
    const float* rp1w = (const float*)d_in[11];
    const float* rp1b = (const float*)d_in[12];
    const float* lp2w = (const float*)d_in[13];
    const float* lp2b = (const float*)d_in[14];
    const float* rp2w = (const float*)d_in[15];
    const float* rp2b = (const float*)d_in[16];
    const float* beta = (const float*)d_in[17];
    const float* gamma= (const float*)d_in[18];

    bf16* Abuf = (bf16*)d_ws;             // A -> P in-place
    bf16* LTb  = Abuf + ACHUNK;
    bf16* PTb  = Abuf + 2*ACHUNK;
    float* wsf = (float*)((char*)d_ws + 3*ACHUNK*2);
    float* rmax=wsf, *irsum=wsf+SST, *cmax=wsf+2*SST, *icsum=wsf+3*SST;
    float* mask_r2l=wsf+4*SST, *mask_l2r=wsf+5*SST;
    double* dsum=(double*)(wsf+6*SST);
    // Q and V all alias the PT chunk (4*QELEMS <= ACHUNK); dead before k_trans runs.
    bf16* Qlb = PTb;
    bf16* Qrb = PTb + QELEMS;
    bf16* Vlb = PTb + 2*QELEMS;
    bf16* Vrb = PTb + 3*QELEMS;

    float* out  = (float*)d_out;
    float* out0 = out;
    float* out1 = out + (size_t)BB*CHW;
    float* out2 = out + 2*(size_t)BB*CHW;
    float* out3 = out2 + (size_t)BB*3*HW;
    float* out4 = out3 + (size_t)BB*3*HW;

    k0_zero<<<1,64,0,stream>>>(dsum);
    for (int b=0;b<BB;b++){
        k_qv<<<dim3(6,HH),256,0,stream>>>(x_l,x_r,nlw,nlb,nrw,nrb,
                                          lp1w,lp1b,rp1w,rp1b,lp2w,lp2b,rp2w,rp2b,
                                          Qlb,Qrb,Vlb,Vrb,b);
        k_attn<<<dim3(3,3,HH),256,0,stream>>>(Qlb,Qrb,Abuf);
        k3_stats<<<dim3(HH,6),384,0,stream>>>(Abuf,rmax,irsum,cmax,icsum,b);
        k_mats<<<dim3(HH,6),256,0,stream>>>(Abuf,LTb,rmax,irsum,cmax,icsum,b);
        k4_masks<<<dim3(HH,6),384,0,stream>>>(Abuf,LTb,mask_r2l,mask_l2r,b);
        k5m<<<dim3(6,HH),256,0,stream>>>(Abuf,Vrb,x_l,beta, out0,b,0);   // V consumed here,
        k5m<<<dim3(6,HH),256,0,stream>>>(LTb, Vlb,x_r,gamma,out1,b,1);   // BEFORE k_trans
        k_trans<<<dim3(6,6,HH),256,0,stream>>>(Abuf,PTb);
        k6_mfma<<<1728,256,0,stream>>>(Abuf,LTb,PTb,mask_r2l,mask_l2r,dsum,b);
        k78_photo_smooth<<<dim3(HH,6),384,0,stream>>>(Abuf,LTb,mask_r2l,mask_l2r,LRl,LRr,out2,out3,dsum,b);
    }
    k9_final<<<1,64,0,stream>>>(dsum,lossi,out4);
}

// Round 8
// 1271.978 us; speedup vs baseline: 1.4631x; 1.3252x over previous
//
#include <hip/hip_runtime.h>
#include <hip/hip_bf16.h>

#define BB 4
#define CC 64
#define HH 96
#define WW 384
#define HW (HH*WW)          // 36864
#define CHW (CC*HW)         // 2359296
#define BH (BB*HH)          // 384
#define EPSV 1e-6f
#define QSCALE 0.125f       // C^-0.5, folded into Q_l

typedef __hip_bfloat16 bf16;
typedef short s8vec __attribute__((ext_vector_type(8)));   // 8 bf16 = one MFMA frag
typedef float f4vec __attribute__((ext_vector_type(4)));   // MFMA accum

__device__ __forceinline__ float b2f(bf16 v){ return __bfloat162float(v); }
__device__ __forceinline__ bf16 f2b(float v){ return __float2bfloat16(v); }
__device__ __forceinline__ unsigned short f2bu(float f){
    bf16 h = __float2bfloat16(f);
    return __builtin_bit_cast(unsigned short, h);
}
__device__ __forceinline__ float bfu2f(unsigned short u){
    unsigned v = ((unsigned)u)<<16;
    return __builtin_bit_cast(float, v);
}

// ---------------- workspace layout (per-batch chunk) ----------------
#define ACHUNK ((size_t)HH*WW*WW)    // 14,155,776 elems
#define SST ((size_t)BH*WW)          // 147456
#define QELEMS ((size_t)HW*64)       // 2,359,296

// LDS chunk swizzle for k6 (unchanged from passing R6)
#define SWZ(row) ((((row) + ((row)>>3)) & 7))

// ---------------- K0: zero loss accumulators ----------------
__global__ void k0_zero(double* dsum){
    if (threadIdx.x < 4) dsum[threadIdx.x] = 0.0;
}

// ---------------- K_qv -- unchanged ----------------
__global__ __launch_bounds__(256) void k_qv(
    const float* __restrict__ xl, const float* __restrict__ xr,
    const float* __restrict__ nlw, const float* __restrict__ nlb,
    const float* __restrict__ nrw, const float* __restrict__ nrb,
    const float* __restrict__ P1l, const float* __restrict__ b1l,
    const float* __restrict__ P1r, const float* __restrict__ b1r,
    const float* __restrict__ P2l, const float* __restrict__ b2l,
    const float* __restrict__ P2r, const float* __restrict__ b2r,
    bf16* __restrict__ Ql, bf16* __restrict__ Qr,
    bf16* __restrict__ Vl, bf16* __restrict__ Vr, int b)
{
    __shared__ float xs[64*64];                  // [c][w]
    __shared__ float p1s[64*65], p2s[64*65];     // [o][c]
    __shared__ float nws[64], nbs[64], b1s[64], b2s[64];
    __shared__ float mus[64], ris[64];
    int t = threadIdx.x;
    int wt = blockIdx.x, l = blockIdx.y;
    int w0 = wt*64;

    for (int side=0; side<2; side++){
        const float* x  = side ? xr  : xl;
        const float* nw = side ? nrw : nlw;
        const float* nb = side ? nrb : nlb;
        const float* P1 = side ? P1r : P1l;
        const float* B1 = side ? b1r : b1l;
        const float* P2 = side ? P2r : P2l;
        const float* B2 = side ? b2r : b2l;
        bf16* Q = side ? Qr : Ql;
        bf16* V = side ? Vr : Vl;
        float qsc = side ? 1.f : QSCALE;

        if (t < 64){ nws[t]=nw[t]; nbs[t]=nb[t]; b1s[t]=B1[t]; b2s[t]=B2[t]; }
        for (int k=0;k<16;k++){
            int i=t+256*k; int o=i>>6, c=i&63;
            p1s[o*65+c]=P1[i]; p2s[o*65+c]=P2[i];
        }
        const float* xb = x + (size_t)b*CHW + (size_t)l*WW + w0;
        for (int k=0;k<16;k++){
            int c=(t>>6)+4*k, w=t&63;
            xs[c*64+w] = xb[(size_t)c*HW + w];
        }
        __syncthreads();
        if (t < 64){
            float s=0.f, ss=0.f;
            for (int c=0;c<64;c++){ float v=xs[c*64+t]; s+=v; ss+=v*v; }
            float mu=s*(1.f/64.f), var=ss*(1.f/64.f)-mu*mu;
            mus[t]=mu; ris[t]=rsqrtf(var+EPSV);
        }
        __syncthreads();

        {
            int vq=t&15, ov=t>>4;
            float acc[4][4]={};
            for (int c=0;c<64;c++){
                float xv[4];
                for (int j=0;j<4;j++) xv[j]=xs[c*64+vq*4+j];
                for (int i=0;i<4;i++){
                    float w2=p2s[(ov*4+i)*65+c];
                    for (int j=0;j<4;j++) acc[i][j]+=w2*xv[j];
                }
            }
            for (int i=0;i<4;i++){
                int c=ov*4+i;
                ushort4 pk;
                pk.x=f2bu(acc[i][0]+b2s[c]); pk.y=f2bu(acc[i][1]+b2s[c]);
                pk.z=f2bu(acc[i][2]+b2s[c]); pk.w=f2bu(acc[i][3]+b2s[c]);
                *reinterpret_cast<ushort4*>(&V[(size_t)c*HW + (size_t)l*WW + w0 + vq*4]) = pk;
            }
        }
        {
            int cq=t&15, wq=t>>4;
            float muj[4], rij[4];
            for (int j=0;j<4;j++){ muj[j]=mus[wq*4+j]; rij[j]=ris[wq*4+j]; }
            float acc[4][4]={};
            for (int c=0;c<64;c++){
                float nwc=nws[c], nbc=nbs[c];
                float xn[4];
                for (int j=0;j<4;j++) xn[j]=(xs[c*64+wq*4+j]-muj[j])*rij[j]*nwc+nbc;
                for (int i=0;i<4;i++){
                    float w1=p1s[(cq*4+i)*65+c];
                    for (int j=0;j<4;j++) acc[i][j]+=w1*xn[j];
                }
            }
            for (int j=0;j<4;j++){
                int w=w0+wq*4+j;
                ushort4 pk;
                pk.x=f2bu(qsc*(acc[0][j]+b1s[cq*4+0]));
                pk.y=f2bu(qsc*(acc[1][j]+b1s[cq*4+1]));
                pk.z=f2bu(qsc*(acc[2][j]+b1s[cq*4+2]));
                pk.w=f2bu(qsc*(acc[3][j]+b1s[cq*4+3]));
                *reinterpret_cast<ushort4*>(&Q[((size_t)l*WW + w)*64 + cq*4]) = pk;
            }
        }
        __syncthreads();   // LDS reuse by next side
    }
}

// ---------------- K_attn -- unchanged ----------------
__global__ __launch_bounds__(256) void k_attn(
    const bf16* __restrict__ Ql, const bf16* __restrict__ Qr,
    bf16* __restrict__ Abuf)
{
    __shared__ bf16 As[128*72];
    __shared__ bf16 Bs[128*72];
    int t=threadIdx.x;
    int mt=blockIdx.x, nt=blockIdx.y, l=blockIdx.z;
    const bf16* Qa = Ql + ((size_t)l*WW + mt*128)*64;
    const bf16* Qb = Qr + ((size_t)l*WW + nt*128)*64;
    for (int i=0;i<4;i++){
        int lin=t+256*i;
        int r=lin>>3, c8=lin&7;
        *reinterpret_cast<uint4*>(&As[r*72+c8*8]) =
            *reinterpret_cast<const uint4*>(&Qa[(size_t)r*64 + c8*8]);
        *reinterpret_cast<uint4*>(&Bs[r*72+c8*8]) =
            *reinterpret_cast<const uint4*>(&Qb[(size_t)r*64 + c8*8]);
    }
    __syncthreads();
    int wv=t>>6, lane=t&63;
    int m0=(wv>>1)*64, n0=(wv&1)*64;
    int ln=lane&15, cq=lane>>4;
    f4vec acc[4][4];
    #pragma unroll
    for (int m=0;m<4;m++)
        #pragma unroll
        for (int n=0;n<4;n++) acc[m][n]=(f4vec){0.f,0.f,0.f,0.f};
    #pragma unroll
    for (int kk=0;kk<2;kk++){
        s8vec a[4], bb[4];
        #pragma unroll
        for (int m=0;m<4;m++) a[m]=*reinterpret_cast<const s8vec*>(&As[(m0+m*16+ln)*72 + kk*32 + cq*8]);
        #pragma unroll
        for (int n=0;n<4;n++) bb[n]=*reinterpret_cast<const s8vec*>(&Bs[(n0+n*16+ln)*72 + kk*32 + cq*8]);
        #pragma unroll
        for (int m=0;m<4;m++)
            #pragma unroll
            for (int n=0;n<4;n++)
                acc[m][n]=__builtin_amdgcn_mfma_f32_16x16x32_bf16(a[m],bb[n],acc[m][n],0,0,0);
    }
    bf16* Ab = Abuf + (size_t)l*WW*WW;
    #pragma unroll
    for (int m=0;m<4;m++){
        #pragma unroll
        for (int r=0;r<4;r++){
            int w = mt*128 + m0 + m*16 + cq*4 + r;
            #pragma unroll
            for (int n=0;n<4;n++){
                int v = nt*128 + n0 + n*16 + ln;
                Ab[(size_t)w*WW + v] = f2b(acc[m][n][r]);
            }
        }
    }
}

// ---------------- K3: softmax stats -- unchanged ----------------
__global__ __launch_bounds__(384) void k3_stats(
    const bf16* __restrict__ Abuf, float* __restrict__ rmax, float* __restrict__ irsum,
    float* __restrict__ cmax, float* __restrict__ icsum, int b)
{
    __shared__ float pm[6][64], ps[6][64];
    int t=threadIdx.x, l=blockIdx.x, seg=blockIdx.y;
    int bh=b*HH+l;
    const bf16* Ab = Abuf + (size_t)l*WW*WW;
    int lane=t&63, wid=t>>6;
    for (int w=seg*64+wid; w<seg*64+64; w+=6){
        const bf16* row=Ab+(size_t)w*WW;
        float m=-1e30f;
        for (int k=0;k<6;k++) m=fmaxf(m,b2f(row[lane+64*k]));
        for (int o=32;o;o>>=1) m=fmaxf(m,__shfl_xor(m,o,64));
        float s=0.f;
        for (int k=0;k<6;k++) s+=__expf(b2f(row[lane+64*k])-m);
        for (int o=32;o;o>>=1) s+=__shfl_xor(s,o,64);
        if (lane==0){ rmax[bh*WW+w]=m; irsum[bh*WW+w]=1.f/s; }
    }
    {
        int c=t&63, v=seg*64+c;
        float m=-1e30f;
        for (int w=wid*64; w<wid*64+64; w++) m=fmaxf(m,b2f(Ab[(size_t)w*WW+v]));
        float s=0.f;
        for (int w=wid*64; w<wid*64+64; w++) s+=__expf(b2f(Ab[(size_t)w*WW+v])-m);
        pm[wid][c]=m; ps[wid][c]=s;
    }
    __syncthreads();
    if (t<64){
        float M=-1e30f;
        for (int p=0;p<6;p++) M=fmaxf(M,pm[p][t]);
        float S=0.f;
        for (int p=0;p<6;p++) S+=ps[p][t]*__expf(pm[p][t]-M);
        cmax[bh*WW+seg*64+t]=M; icsum[bh*WW+seg*64+t]=1.f/S;
    }
}

// ---------------- K_mats -- unchanged ----------------
__global__ __launch_bounds__(256) void k_mats(
    bf16* __restrict__ AP, bf16* __restrict__ LT,
    const float* __restrict__ rmax, const float* __restrict__ irsum,
    const float* __restrict__ cmax, const float* __restrict__ icsum, int b)
{
    int t=threadIdx.x, l=blockIdx.x, seg=blockIdx.y;
    int bh=b*HH+l;
    bf16* Ab  = AP + (size_t)l*WW*WW;
    bf16* LTb = LT + (size_t)l*WW*WW;
    const float* rm=rmax+(size_t)bh*WW; const float* ris=irsum+(size_t)bh*WW;
    const float* cm=cmax+(size_t)bh*WW; const float* cis=icsum+(size_t)bh*WW;
    int lane6=t&63;
    float cmv[6], civ[6];
    for (int s=0;s<6;s++){ cmv[s]=cm[s*64+lane6]; civ[s]=cis[s*64+lane6]; }
    for (int k=0;k<16;k++){
        int w = seg*64 + (t>>6) + 4*k;
        float rmw = rm[w], risw = ris[w];
        for (int s=0;s<6;s++){
            int v = s*64 + lane6;
            size_t idx = (size_t)w*WW + v;
            float a = b2f(Ab[idx]);
            Ab[idx]  = f2b(__expf(a - rmw)*risw);       // P[w][v] = M_r2l[w][v]
            LTb[idx] = f2b(__expf(a - cmv[s])*civ[s]);  // LT[w][v] = M_l2r[v][w]
        }
    }
}

// ---------------- K_trans -- unchanged ----------------
__global__ __launch_bounds__(256) void k_trans(
    const bf16* __restrict__ Pm, bf16* __restrict__ PTm)
{
    __shared__ float tile[64][65];
    int t=threadIdx.x;
    int ti=blockIdx.x, tj=blockIdx.y, l=blockIdx.z;
    const bf16* Pb = Pm + (size_t)l*WW*WW;
    bf16* PTb = PTm + (size_t)l*WW*WW;
    for (int k=0;k<16;k++){
        int r=(t>>6)+4*k, c=t&63;
        tile[r][c] = b2f(Pb[(size_t)(ti*64+r)*WW + tj*64+c]);
    }
    __syncthreads();
    for (int k=0;k<16;k++){
        int r=(t>>6)+4*k, c=t&63;
        PTb[(size_t)(tj*64+r)*WW + ti*64+c] = f2b(tile[c][r]);
    }
}

// ---------------- K4: validity masks -- unchanged ----------------
__global__ __launch_bounds__(384) void k4_masks(
    const bf16* __restrict__ Pm, const bf16* __restrict__ LTm,
    float* __restrict__ mask_r2l, float* __restrict__ mask_l2r, int b)
{
    __shared__ float pa[6][64];
    int t=threadIdx.x, l=blockIdx.x, seg=blockIdx.y;
    int bh=b*HH+l;
    const bf16* Pb  = Pm  + (size_t)l*WW*WW;
    const bf16* LTb = LTm + (size_t)l*WW*WW;
    int lane=t&63, wid=t>>6;
    {
        int c=t&63, v=seg*64+c;
        float s=0.f;
        for (int w=wid*64; w<wid*64+64; w++) s+=b2f(Pb[(size_t)w*WW+v]);
        pa[wid][c]=s;
    }
    __syncthreads();
    if (t<64){
        float S=0.f;
        for (int p=0;p<6;p++) S+=pa[p][t];
        mask_r2l[bh*WW+seg*64+t]=(S>0.1f)?1.f:0.f;
    }
    for (int u=seg*64+wid; u<seg*64+64; u+=6){
        const bf16* row=LTb+(size_t)u*WW;
        float s=0.f;
        for (int k=0;k<6;k++) s+=b2f(row[lane+64*k]);
        for (int o=32;o;o>>=1) s+=__shfl_xor(s,o,64);
        if (lane==0) mask_l2r[bh*WW+u]=(s>0.1f)?1.f:0.f;
    }
}

// ---------------- K5m -- unchanged ----------------
__global__ __launch_bounds__(256) void k5m(
    const bf16* __restrict__ Msrc, const bf16* __restrict__ VT,
    const float* __restrict__ xadd, const float* __restrict__ coef,
    float* __restrict__ outp, int b, int side)
{
    __shared__ bf16 As[64*72];   // VT tile [c][v]
    __shared__ bf16 Bs[64*72];   // M tile  [w][v]
    int t=threadIdx.x;
    int wt=blockIdx.x, l=blockIdx.y;
    int w0=wt*64;
    int wv=t>>6, lane=t&63;
    int cb=(wv>>1)*32, wb=(wv&1)*32;
    int ln=lane&15, cq=lane>>4;
    f4vec acc[2][2];
    #pragma unroll
    for (int m=0;m<2;m++)
        #pragma unroll
        for (int n=0;n<2;n++) acc[m][n]=(f4vec){0.f,0.f,0.f,0.f};
    const bf16* Mb = Msrc + (size_t)l*WW*WW;

    for (int vt=0;vt<6;vt++){
        int v0=vt*64;
        __syncthreads();
        for (int i=0;i<2;i++){
            int lin=t+256*i; int c=lin>>3, c8=lin&7;
            *reinterpret_cast<uint4*>(&As[c*72+c8*8]) =
                *reinterpret_cast<const uint4*>(&VT[(size_t)c*HW + (size_t)l*WW + v0 + c8*8]);
        }
        if (side==0){
            for (int i=0;i<2;i++){
                int lin=t+256*i; int r=lin>>3, c8=lin&7;
                *reinterpret_cast<uint4*>(&Bs[r*72+c8*8]) =
                    *reinterpret_cast<const uint4*>(&Mb[(size_t)(w0+r)*WW + v0 + c8*8]);
            }
        } else {
            int wl=t&63, j0=t>>6;
            for (int jj=0;jj<16;jj++){
                int j=j0+4*jj;
                Bs[wl*72+j] = Mb[(size_t)(v0+j)*WW + w0 + wl];
            }
        }
        __syncthreads();
        #pragma unroll
        for (int kk=0;kk<2;kk++){
            s8vec a[2], bb[2];
            #pragma unroll
            for (int m=0;m<2;m++) a[m]=*reinterpret_cast<const s8vec*>(&As[(cb+m*16+ln)*72+kk*32+cq*8]);
            #pragma unroll
            for (int n=0;n<2;n++) bb[n]=*reinterpret_cast<const s8vec*>(&Bs[(wb+n*16+ln)*72+kk*32+cq*8]);
            #pragma unroll
            for (int m=0;m<2;m++)
                #pragma unroll
                for (int n=0;n<2;n++)
                    acc[m][n]=__builtin_amdgcn_mfma_f32_16x16x32_bf16(a[m],bb[n],acc[m][n],0,0,0);
        }
    }
    const float* xb = xadd + (size_t)b*CHW + (size_t)l*WW + w0;
    float*      ob = outp + (size_t)b*CHW + (size_t)l*WW + w0;
    #pragma unroll
    for (int m=0;m<2;m++){
        #pragma unroll
        for (int r=0;r<4;r++){
            int c = cb + m*16 + cq*4 + r;
            float cf = coef[c];
            #pragma unroll
            for (int n=0;n<2;n++){
                int w = wb + n*16 + ln;
                ob[(size_t)c*HW + w] = xb[(size_t)c*HW + w] + cf*acc[m][n][r];
            }
        }
    }
}

// ---------------- K6 -- unchanged from R6 (2-phase dbuf + XCD affinity) ----------------
__global__ __launch_bounds__(256) void k6_mfma(
    const bf16* __restrict__ Pm, const bf16* __restrict__ LTm, const bf16* __restrict__ PTm,
    const float* __restrict__ mask_r2l, const float* __restrict__ mask_l2r,
    double* __restrict__ dsum, int b)
{
    __shared__ bf16 As[2][128*64];   // [buf][w][k] swizzled
    __shared__ bf16 Bs[2][128*64];   // [buf][u][k] swizzled
    int t=threadIdx.x;
    int wg=blockIdx.x;
    int xcd = wg & 7, j = wg >> 3;
    int lgrp = j/18, tile = j - lgrp*18;
    int l = xcd + 8*lgrp;
    int which = tile/9; int xt = tile - which*9;
    int wt = xt/3, ut = xt - wt*3;
    int w0=wt*128, u0=ut*128, bh=b*HH+l;
    const float* msk = which ? (mask_r2l+(size_t)bh*WW) : (mask_l2r+(size_t)bh*WW);
    const bf16* Ap = Pm  + (size_t)l*WW*WW;
    const bf16* Lt = LTm + (size_t)l*WW*WW;
    const bf16* Bsrc = (which==0 ? LTm : PTm) + (size_t)l*WW*WW;

    int wv=t>>6, lane=t&63;
    int qr=wv>>1, qc=wv&1;
    int ln=lane&15, cq=lane>>4;

    uint4 rb[4], ra[4];
    uint4 r0[2], r1[2];

    auto stage_read = [&](int kt){
        #pragma unroll
        for (int i=0;i<4;i++){
            int lin=t+256*i; int u=lin>>3, c8=lin&7;
            rb[i] = *reinterpret_cast<const uint4*>(&Bsrc[(size_t)(u0+u)*WW + kt*64 + c8*8]);
        }
        if (which==0){
            #pragma unroll
            for (int i=0;i<4;i++){
                int lin=t+256*i; int w=lin>>3, c8=lin&7;
                ra[i] = *reinterpret_cast<const uint4*>(&Ap[(size_t)(w0+w)*WW + kt*64 + c8*8]);
            }
        } else {
            #pragma unroll
            for (int i=0;i<2;i++){
                int p=(t>>4)+16*i, wc=t&15;
                const bf16* base = &Lt[(size_t)(kt*64 + 2*p)*WW + w0 + wc*8];
                r0[i] = *reinterpret_cast<const uint4*>(base);
                r1[i] = *reinterpret_cast<const uint4*>(base + WW);
            }
        }
    };
    auto stage_write = [&](int bufi){
        bf16* bsw = Bs[bufi]; bf16* asw = As[bufi];
        #pragma unroll
        for (int i=0;i<4;i++){
            int lin=t+256*i; int u=lin>>3, c8=lin&7;
            *reinterpret_cast<uint4*>((char*)bsw + u*128 + ((c8 ^ SWZ(u))<<4)) = rb[i];
        }
        if (which==0){
            #pragma unroll
            for (int i=0;i<4;i++){
                int lin=t+256*i; int w=lin>>3, c8=lin&7;
                *reinterpret_cast<uint4*>((char*)asw + w*128 + ((c8 ^ SWZ(w))<<4)) = ra[i];
            }
        } else {
            #pragma unroll
            for (int i=0;i<2;i++){
                int p=(t>>4)+16*i, wc=t&15;
                const unsigned short* q0 = reinterpret_cast<const unsigned short*>(&r0[i]);
                const unsigned short* q1 = reinterpret_cast<const unsigned short*>(&r1[i]);
                int cb2 = p>>2, off = (p&3)*4;
                #pragma unroll
                for (int jj=0;jj<8;jj++){
                    int w = wc*8 + jj;
                    unsigned val = (unsigned)q0[jj] | ((unsigned)q1[jj]<<16);
                    *reinterpret_cast<unsigned*>((char*)asw + w*128 + ((cb2 ^ SWZ(w))<<4) + off) = val;
                }
            }
        }
    };

    f4vec acc[4][4];
    #pragma unroll
    for (int m=0;m<4;m++)
        #pragma unroll
        for (int n=0;n<4;n++) acc[m][n]=(f4vec){0.f,0.f,0.f,0.f};

    stage_read(0);
    stage_write(0);
    __syncthreads();
    int cur=0;
    for (int kt=0; kt<6; kt++){
        if (kt<5) stage_read(kt+1);
        const bf16* as = As[cur]; const bf16* bs = Bs[cur];
        #pragma unroll
        for (int kk=0;kk<2;kk++){
            s8vec a[4], bb[4];
            #pragma unroll
            for (int m=0;m<4;m++){
                int r = qr*64 + m*16 + ln;
                a[m] = *reinterpret_cast<const s8vec*>(
                    (const char*)as + r*128 + (((kk*4+cq) ^ SWZ(r))<<4));
            }
            #pragma unroll
            for (int n=0;n<4;n++){
                int u = qc*64 + n*16 + ln;
                bb[n] = *reinterpret_cast<const s8vec*>(
                    (const char*)bs + u*128 + (((kk*4+cq) ^ SWZ(u))<<4));
            }
            #pragma unroll
            for (int m=0;m<4;m++)
                #pragma unroll
                for (int n=0;n<4;n++)
                    acc[m][n]=__builtin_amdgcn_mfma_f32_16x16x32_bf16(a[m],bb[n],acc[m][n],0,0,0);
        }
        if (kt<5) stage_write(cur^1);
        __syncthreads();
        cur ^= 1;
    }

    float local = 0.f;
    #pragma unroll
    for (int n=0;n<4;n++){
        int ua = u0 + qc*64 + n*16 + ln;
        float mv = msk[ua];
        #pragma unroll
        for (int m=0;m<4;m++){
            int wbase = w0 + qr*64 + m*16 + cq*4;
            #pragma unroll
            for (int r=0;r<4;r++)
                local += mv * fabsf(acc[m][n][r] - ((ua==wbase+r)?1.f:0.f));
        }
    }
    for (int o=32;o;o>>=1) local += __shfl_xor(local,o,64);
    float* red = (float*)As;
    if (lane==0) red[wv]=local;
    __syncthreads();
    if (t==0) atomicAdd(&dsum[0], (double)(red[0]+red[1]+red[2]+red[3]));
}

// ---------------- K78: photo + smooth, VECTORIZED (16B/lane, 6 streams) ----------------
// 1D grid 576 = 8 xcd * 12 lgrp * 6 seg. XCD x owns l in [12x,12x+12) ascending, so
// the l+1 reads hit the same XCD L2. Block 256 = 4 waves; each wave processes 4 rows
// per iter (16 lanes/row); lane ln holds chunks 8*(ln+16i), i=0..2 (48x8=384).
// Per row, 6 uint4 streams: P[w], LT[w], P[w+1], LT[w+1], P(l+1)[w], LT(l+1)[w].
// Photo dots use bf16-packed LR chunks in LDS (16 contiguous 16B reads/group: no
// conflicts, broadcast across the 4 row-groups). v+1 shift: in-register for e<7,
// 2 shfls for the chunk-boundary element.
__global__ __launch_bounds__(256) void k78_photo_smooth(
    const bf16* __restrict__ Pm, const bf16* __restrict__ LTm,
    const float* __restrict__ mask_r2l, const float* __restrict__ mask_l2r,
    const float* __restrict__ LRl, const float* __restrict__ LRr,
    float* __restrict__ out2, float* __restrict__ out3, double* __restrict__ dsum, int b)
{
    __shared__ unsigned short lrR[3*WW], lrL[3*WW];   // bf16-packed LR rows
    __shared__ float redP[4], redW[4], redH[4];
    int t=threadIdx.x;
    int wg=blockIdx.x;
    int xcd = wg & 7, j = wg >> 3;          // j 0..71
    int lgrp = j/6, seg = j - lgrp*6;       // lgrp 0..11, seg 0..5
    int l = xcd*12 + lgrp;
    int bh = b*HH + l;

    // stage LR (f32 -> bf16 chunks) + passthrough outputs (seg==0 blocks)
    for (int c=0;c<3;c++){
        size_t base = ((size_t)(b*3+c)*HH + l)*WW;
        if (t < 96){
            float4 vl = *reinterpret_cast<const float4*>(&LRl[base + t*4]);
            float4 vr = *reinterpret_cast<const float4*>(&LRr[base + t*4]);
            ushort4 pl, pr;
            pl.x=f2bu(vl.x); pl.y=f2bu(vl.y); pl.z=f2bu(vl.z); pl.w=f2bu(vl.w);
            pr.x=f2bu(vr.x); pr.y=f2bu(vr.y); pr.z=f2bu(vr.z); pr.w=f2bu(vr.w);
            *reinterpret_cast<ushort4*>(&lrL[c*WW + t*4]) = pl;
            *reinterpret_cast<ushort4*>(&lrR[c*WW + t*4]) = pr;
            if (seg==0){
                *reinterpret_cast<float4*>(&out2[base + t*4]) = vl;
                *reinterpret_cast<float4*>(&out3[base + t*4]) = vr;
            }
        }
    }
    __syncthreads();

    int wid=t>>6, lane=t&63;
    int r4=lane>>4, ln=lane&15;
    const bf16* Pb  = Pm  + (size_t)l*WW*WW;
    const bf16* LTb = LTm + (size_t)l*WW*WW;
    bool dnok = (l < HH-1);
    const bf16* Pdn = Pb  + (dnok ? (size_t)WW*WW : 0);
    const bf16* Ldn = LTb + (dnok ? (size_t)WW*WW : 0);
    float fdn = dnok ? 1.f : 0.f;
    int src_same = (lane & 48) | ((ln+1)&15);
    int src_zero = (lane & 48);

    float phL=0.f, lwv=0.f, lhv=0.f;

    for (int it=0; it<4; it++){
        int w = seg*64 + wid*16 + it*4 + r4;
        int wn = (w<WW-1) ? w+1 : w;
        float fwn = (w<WW-1) ? 1.f : 0.f;
        const bf16* pr  = Pb  + (size_t)w*WW;
        const bf16* lr_ = LTb + (size_t)w*WW;
        const bf16* prn = Pb  + (size_t)wn*WW;
        const bf16* lrn = LTb + (size_t)wn*WW;
        const bf16* prd = Pdn + (size_t)w*WW;
        const bf16* lrd = Ldn + (size_t)w*WW;

        uint4 up[3], ul[3], upn[3], uln[3], upd[3], uld[3];
        #pragma unroll
        for (int i=0;i<3;i++){
            int off = 8*(ln + 16*i);
            up[i]  = *reinterpret_cast<const uint4*>(pr  + off);
            ul[i]  = *reinterpret_cast<const uint4*>(lr_ + off);
            upn[i] = *reinterpret_cast<const uint4*>(prn + off);
            uln[i] = *reinterpret_cast<const uint4*>(lrn + off);
            upd[i] = *reinterpret_cast<const uint4*>(prd + off);
            uld[i] = *reinterpret_cast<const uint4*>(lrd + off);
        }
        // first elems of w+1 chunks, for the e=7 shift crossing
        float pn0[3], ln0[3];
        #pragma unroll
        for (int i=0;i<3;i++){
            pn0[i] = bfu2f((unsigned short)(upn[i].x & 0xffffu));
            ln0[i] = bfu2f((unsigned short)(uln[i].x & 0xffffu));
        }

        float a0=0.f,a1=0.f,a2=0.f, d0=0.f,d1=0.f,d2=0.f;
        #pragma unroll
        for (int i=0;i<3;i++){
            const unsigned short* pu = reinterpret_cast<const unsigned short*>(&up[i]);
            const unsigned short* lu = reinterpret_cast<const unsigned short*>(&ul[i]);
            const unsigned short* pnu= reinterpret_cast<const unsigned short*>(&upn[i]);
            const unsigned short* lnu= reinterpret_cast<const unsigned short*>(&uln[i]);
            const unsigned short* pdu= reinterpret_cast<const unsigned short*>(&upd[i]);
            const unsigned short* ldu= reinterpret_cast<const unsigned short*>(&uld[i]);
            int v8 = 8*(ln+16*i);
            uint4 R0 = *reinterpret_cast<const uint4*>(&lrR[0*WW + v8]);
            uint4 R1 = *reinterpret_cast<const uint4*>(&lrR[1*WW + v8]);
            uint4 R2 = *reinterpret_cast<const uint4*>(&lrR[2*WW + v8]);
            uint4 L0 = *reinterpret_cast<const uint4*>(&lrL[0*WW + v8]);
            uint4 L1 = *reinterpret_cast<const uint4*>(&lrL[1*WW + v8]);
            uint4 L2 = *reinterpret_cast<const uint4*>(&lrL[2*WW + v8]);
            const unsigned short* r0c = reinterpret_cast<const unsigned short*>(&R0);
            const unsigned short* r1c = reinterpret_cast<const unsigned short*>(&R1);
            const unsigned short* r2c = reinterpret_cast<const unsigned short*>(&R2);
            const unsigned short* l0c = reinterpret_cast<const unsigned short*>(&L0);
            const unsigned short* l1c = reinterpret_cast<const unsigned short*>(&L1);
            const unsigned short* l2c = reinterpret_cast<const unsigned short*>(&L2);

            // shfl the boundary elements (wave-uniform participation)
            float pn_same = __shfl(pn0[i], src_same, 64);
            float ln_same = __shfl(ln0[i], src_same, 64);
            float pn_next = __shfl(pn0[i<2 ? i+1 : 0], src_zero, 64);
            float ln_next = __shfl(ln0[i<2 ? i+1 : 0], src_zero, 64);
            float pn_last = (ln==15) ? pn_next : pn_same;
            float ln_last = (ln==15) ? ln_next : ln_same;

            float pc[8], lc[8];
            #pragma unroll
            for (int e=0;e<8;e++){ pc[e]=bfu2f(pu[e]); lc[e]=bfu2f(lu[e]); }
            #pragma unroll
            for (int e=0;e<8;e++){
                a0 += pc[e]*bfu2f(r0c[e]); a1 += pc[e]*bfu2f(r1c[e]); a2 += pc[e]*bfu2f(r2c[e]);
                d0 += lc[e]*bfu2f(l0c[e]); d1 += lc[e]*bfu2f(l1c[e]); d2 += lc[e]*bfu2f(l2c[e]);
            }
            #pragma unroll
            for (int e=0;e<8;e++){
                lhv += fdn*(fabsf(pc[e]-bfu2f(pdu[e])) + fabsf(lc[e]-bfu2f(ldu[e])));
            }
            #pragma unroll
            for (int e=0;e<7;e++){
                lwv += fwn*(fabsf(pc[e]-bfu2f(pnu[e+1])) + fabsf(lc[e]-bfu2f(lnu[e+1])));
            }
            {
                float m = (v8+7 < WW-1) ? fwn : 0.f;   // masks chunk 47 (v=383)
                lwv += m*(fabsf(pc[7]-pn_last) + fabsf(lc[7]-ln_last));
            }
        }
        // 16-lane group reduce (photo dots)
        #pragma unroll
        for (int o=8;o;o>>=1){
            a0+=__shfl_xor(a0,o,64); a1+=__shfl_xor(a1,o,64); a2+=__shfl_xor(a2,o,64);
            d0+=__shfl_xor(d0,o,64); d1+=__shfl_xor(d1,o,64); d2+=__shfl_xor(d2,o,64);
        }
        if (ln==0){
            float mkL = mask_l2r[(size_t)bh*WW+w], mkR = mask_r2l[(size_t)bh*WW+w];
            size_t lrb = ((size_t)(b*3)*HH + l)*WW + w;
            size_t chs = (size_t)HH*WW;
            float l0v=LRl[lrb], l1v=LRl[lrb+chs], l2v=LRl[lrb+2*chs];
            float r0v=LRr[lrb], r1v=LRr[lrb+chs], r2v=LRr[lrb+2*chs];
            phL += mkL*(fabsf(l0v-a0)+fabsf(l1v-a1)+fabsf(l2v-a2));
            phL += mkR*(fabsf(r0v-d0)+fabsf(r1v-d1)+fabsf(r2v-d2));
        }
    }
    for (int o=32;o;o>>=1){
        phL+=__shfl_xor(phL,o,64); lwv+=__shfl_xor(lwv,o,64); lhv+=__shfl_xor(lhv,o,64);
    }
    if (lane==0){ redP[wid]=phL; redW[wid]=lwv; redH[wid]=lhv; }
    __syncthreads();
    if (t==0){
        atomicAdd(&dsum[1], (double)(redP[0]+redP[1]+redP[2]+redP[3]));
        atomicAdd(&dsum[3], (double)(redW[0]+redW[1]+redW[2]+redW[3]));
        atomicAdd(&dsum[2], (double)(redH[0]+redH[1]+redH[2]+redH[3]));
    }
}

// ---------------- K9: final loss -- unchanged ----------------
__global__ void k9_final(const double* __restrict__ dsum, const float* __restrict__ lossin,
                         float* __restrict__ out4)
{
    if (threadIdx.x==0){
        double cyc  = dsum[0]/(double)((size_t)BB*HH*WW*WW);
        double photo= dsum[1]/(double)((size_t)BB*3*HH*WW);
        double lhv  = dsum[2]/(double)((size_t)BB*(HH-1)*WW*WW);
        double lwv  = dsum[3]/(double)((size_t)BB*HH*(WW-1)*(WW-1));
        double res  = (double)lossin[0] + 0.0025*(photo + 0.1*(lwv+lhv) + cyc);
        out4[0]=(float)res;
    }
}

extern "C" void kernel_launch(void* const* d_in, const int* in_sizes, int n_in,
                              void* d_out, int out_size, void* d_ws, size_t ws_size,
                              hipStream_t stream)
{
    (void)in_sizes; (void)n_in; (void)out_size; (void)ws_size;
    const float* x_l  = (const float*)d_in[0];
    const float* x_r  = (const float*)d_in[1];
    const float* LRl  = (const float*)d_in[2];
    const float* LRr  = (const float*)d_in[3];
    const float* lossi= (const float*)d_in[4];
    const float* nlw  = (const float*)d_in[5];
    const float* nlb  = (const float*)d_in[6];
    const float* nrw  = (const float*)d_in[7];
    const float* nrb  = (const float*)d_in[8];
    const float* lp1w = (const float*)d_in[9];
    const float* lp1b = (const float*)d_in[10];
    const float* rp1w = (const float*)d_in[11];
    const float* rp1b = (const float*)d_in[12];
    const float* lp2w = (const float*)d_in[13];
    const float* lp2b = (const float*)d_in[14];
    const float* rp2w = (const float*)d_in[15];
    const float* rp2b = (const float*)d_in[16];
    const float* beta = (const float*)d_in[17];
    const float* gamma= (const float*)d_in[18];

    bf16* Abuf = (bf16*)d_ws;             // A -> P in-place
    bf16* LTb  = Abuf + ACHUNK;
    bf16* PTb  = Abuf + 2*ACHUNK;
    float* wsf = (float*)((char*)d_ws + 3*ACHUNK*2);
    float* rmax=wsf, *irsum=wsf+SST, *cmax=wsf+2*SST, *icsum=wsf+3*SST;
    float* mask_r2l=wsf+4*SST, *mask_l2r=wsf+5*SST;
    double* dsum=(double*)(wsf+6*SST);
    // Q and V all alias the PT chunk (4*QELEMS <= ACHUNK); dead before k_trans runs.
    bf16* Qlb = PTb;
    bf16* Qrb = PTb + QELEMS;
    bf16* Vlb = PTb + 2*QELEMS;
    bf16* Vrb = PTb + 3*QELEMS;

    float* out  = (float*)d_out;
    float* out0 = out;
    float* out1 = out + (size_t)BB*CHW;
    float* out2 = out + 2*(size_t)BB*CHW;
    float* out3 = out2 + (size_t)BB*3*HW;
    float* out4 = out3 + (size_t)BB*3*HW;

    k0_zero<<<1,64,0,stream>>>(dsum);
    for (int b=0;b<BB;b++){
        k_qv<<<dim3(6,HH),256,0,stream>>>(x_l,x_r,nlw,nlb,nrw,nrb,
                                          lp1w,lp1b,rp1w,rp1b,lp2w,lp2b,rp2w,rp2b,
                                          Qlb,Qrb,Vlb,Vrb,b);
        k_attn<<<dim3(3,3,HH),256,0,stream>>>(Qlb,Qrb,Abuf);
        k3_stats<<<dim3(HH,6),384,0,stream>>>(Abuf,rmax,irsum,cmax,icsum,b);
        k_mats<<<dim3(HH,6),256,0,stream>>>(Abuf,LTb,rmax,irsum,cmax,icsum,b);
        k4_masks<<<dim3(HH,6),384,0,stream>>>(Abuf,LTb,mask_r2l,mask_l2r,b);
        k5m<<<dim3(6,HH),256,0,stream>>>(Abuf,Vrb,x_l,beta, out0,b,0);   // V consumed here,
        k5m<<<dim3(6,HH),256,0,stream>>>(LTb, Vlb,x_r,gamma,out1,b,1);   // BEFORE k_trans
        k_trans<<<dim3(6,6,HH),256,0,stream>>>(Abuf,PTb);
        k6_mfma<<<1728,256,0,stream>>>(Abuf,LTb,PTb,mask_r2l,mask_l2r,dsum,b);
        k78_photo_smooth<<<576,256,0,stream>>>(Abuf,LTb,mask_r2l,mask_l2r,LRl,LRr,out2,out3,dsum,b);
    }
    k9_final<<<1,64,0,stream>>>(dsum,lossi,out4);
}

// Round 9
// 1144.478 us; speedup vs baseline: 1.6261x; 1.1114x over previous
//
#include <hip/hip_runtime.h>
#include <hip/hip_bf16.h>

#define BB 4
#define CC 64
#define HH 96
#define WW 384
#define HW (HH*WW)          // 36864
#define CHW (CC*HW)         // 2359296
#define BH (BB*HH)          // 384
#define EPSV 1e-6f
#define QSCALE 0.125f       // C^-0.5, folded into Q_l

typedef __hip_bfloat16 bf16;
typedef short s8vec __attribute__((ext_vector_type(8)));   // 8 bf16 = one MFMA frag
typedef float f4vec __attribute__((ext_vector_type(4)));   // MFMA accum

__device__ __forceinline__ float b2f(bf16 v){ return __bfloat162float(v); }
__device__ __forceinline__ bf16 f2b(float v){ return __float2bfloat16(v); }
__device__ __forceinline__ unsigned short f2bu(float f){
    bf16 h = __float2bfloat16(f);
    return __builtin_bit_cast(unsigned short, h);
}
__device__ __forceinline__ float bfu2f(unsigned short u){
    unsigned v = ((unsigned)u)<<16;
    return __builtin_bit_cast(float, v);
}

// ---------------- workspace layout (per-batch chunk) ----------------
#define ACHUNK ((size_t)HH*WW*WW)    // 14,155,776 elems
#define SST ((size_t)BH*WW)          // 147456
#define QELEMS ((size_t)HW*64)       // 2,359,296

// LDS chunk swizzle for k6 (unchanged from passing R6)
#define SWZ(row) ((((row) + ((row)>>3)) & 7))

// ---------------- K0: zero loss accumulators ----------------
__global__ void k0_zero(double* dsum){
    if (threadIdx.x < 4) dsum[threadIdx.x] = 0.0;
}

// ---------------- K_qv -- unchanged ----------------
__global__ __launch_bounds__(256) void k_qv(
    const float* __restrict__ xl, const float* __restrict__ xr,
    const float* __restrict__ nlw, const float* __restrict__ nlb,
    const float* __restrict__ nrw, const float* __restrict__ nrb,
    const float* __restrict__ P1l, const float* __restrict__ b1l,
    const float* __restrict__ P1r, const float* __restrict__ b1r,
    const float* __restrict__ P2l, const float* __restrict__ b2l,
    const float* __restrict__ P2r, const float* __restrict__ b2r,
    bf16* __restrict__ Ql, bf16* __restrict__ Qr,
    bf16* __restrict__ Vl, bf16* __restrict__ Vr, int b)
{
    __shared__ float xs[64*64];                  // [c][w]
    __shared__ float p1s[64*65], p2s[64*65];     // [o][c]
    __shared__ float nws[64], nbs[64], b1s[64], b2s[64];
    __shared__ float mus[64], ris[64];
    int t = threadIdx.x;
    int wt = blockIdx.x, l = blockIdx.y;
    int w0 = wt*64;

    for (int side=0; side<2; side++){
        const float* x  = side ? xr  : xl;
        const float* nw = side ? nrw : nlw;
        const float* nb = side ? nrb : nlb;
        const float* P1 = side ? P1r : P1l;
        const float* B1 = side ? b1r : b1l;
        const float* P2 = side ? P2r : P2l;
        const float* B2 = side ? b2r : b2l;
        bf16* Q = side ? Qr : Ql;
        bf16* V = side ? Vr : Vl;
        float qsc = side ? 1.f : QSCALE;

        if (t < 64){ nws[t]=nw[t]; nbs[t]=nb[t]; b1s[t]=B1[t]; b2s[t]=B2[t]; }
        for (int k=0;k<16;k++){
            int i=t+256*k; int o=i>>6, c=i&63;
            p1s[o*65+c]=P1[i]; p2s[o*65+c]=P2[i];
        }
        const float* xb = x + (size_t)b*CHW + (size_t)l*WW + w0;
        for (int k=0;k<16;k++){
            int c=(t>>6)+4*k, w=t&63;
            xs[c*64+w] = xb[(size_t)c*HW + w];
        }
        __syncthreads();
        if (t < 64){
            float s=0.f, ss=0.f;
            for (int c=0;c<64;c++){ float v=xs[c*64+t]; s+=v; ss+=v*v; }
            float mu=s*(1.f/64.f), var=ss*(1.f/64.f)-mu*mu;
            mus[t]=mu; ris[t]=rsqrtf(var+EPSV);
        }
        __syncthreads();

        {
            int vq=t&15, ov=t>>4;
            float acc[4][4]={};
            for (int c=0;c<64;c++){
                float xv[4];
                for (int j=0;j<4;j++) xv[j]=xs[c*64+vq*4+j];
                for (int i=0;i<4;i++){
                    float w2=p2s[(ov*4+i)*65+c];
                    for (int j=0;j<4;j++) acc[i][j]+=w2*xv[j];
                }
            }
            for (int i=0;i<4;i++){
                int c=ov*4+i;
                ushort4 pk;
                pk.x=f2bu(acc[i][0]+b2s[c]); pk.y=f2bu(acc[i][1]+b2s[c]);
                pk.z=f2bu(acc[i][2]+b2s[c]); pk.w=f2bu(acc[i][3]+b2s[c]);
                *reinterpret_cast<ushort4*>(&V[(size_t)c*HW + (size_t)l*WW + w0 + vq*4]) = pk;
            }
        }
        {
            int cq=t&15, wq=t>>4;
            float muj[4], rij[4];
            for (int j=0;j<4;j++){ muj[j]=mus[wq*4+j]; rij[j]=ris[wq*4+j]; }
            float acc[4][4]={};
            for (int c=0;c<64;c++){
                float nwc=nws[c], nbc=nbs[c];
                float xn[4];
                for (int j=0;j<4;j++) xn[j]=(xs[c*64+wq*4+j]-muj[j])*rij[j]*nwc+nbc;
                for (int i=0;i<4;i++){
                    float w1=p1s[(cq*4+i)*65+c];
                    for (int j=0;j<4;j++) acc[i][j]+=w1*xn[j];
                }
            }
            for (int j=0;j<4;j++){
                int w=w0+wq*4+j;
                ushort4 pk;
                pk.x=f2bu(qsc*(acc[0][j]+b1s[cq*4+0]));
                pk.y=f2bu(qsc*(acc[1][j]+b1s[cq*4+1]));
                pk.z=f2bu(qsc*(acc[2][j]+b1s[cq*4+2]));
                pk.w=f2bu(qsc*(acc[3][j]+b1s[cq*4+3]));
                *reinterpret_cast<ushort4*>(&Q[((size_t)l*WW + w)*64 + cq*4]) = pk;
            }
        }
        __syncthreads();   // LDS reuse by next side
    }
}

// ---------------- K_attn -- unchanged ----------------
__global__ __launch_bounds__(256) void k_attn(
    const bf16* __restrict__ Ql, const bf16* __restrict__ Qr,
    bf16* __restrict__ Abuf)
{
    __shared__ bf16 As[128*72];
    __shared__ bf16 Bs[128*72];
    int t=threadIdx.x;
    int mt=blockIdx.x, nt=blockIdx.y, l=blockIdx.z;
    const bf16* Qa = Ql + ((size_t)l*WW + mt*128)*64;
    const bf16* Qb = Qr + ((size_t)l*WW + nt*128)*64;
    for (int i=0;i<4;i++){
        int lin=t+256*i;
        int r=lin>>3, c8=lin&7;
        *reinterpret_cast<uint4*>(&As[r*72+c8*8]) =
            *reinterpret_cast<const uint4*>(&Qa[(size_t)r*64 + c8*8]);
        *reinterpret_cast<uint4*>(&Bs[r*72+c8*8]) =
            *reinterpret_cast<const uint4*>(&Qb[(size_t)r*64 + c8*8]);
    }
    __syncthreads();
    int wv=t>>6, lane=t&63;
    int m0=(wv>>1)*64, n0=(wv&1)*64;
    int ln=lane&15, cq=lane>>4;
    f4vec acc[4][4];
    #pragma unroll
    for (int m=0;m<4;m++)
        #pragma unroll
        for (int n=0;n<4;n++) acc[m][n]=(f4vec){0.f,0.f,0.f,0.f};
    #pragma unroll
    for (int kk=0;kk<2;kk++){
        s8vec a[4], bb[4];
        #pragma unroll
        for (int m=0;m<4;m++) a[m]=*reinterpret_cast<const s8vec*>(&As[(m0+m*16+ln)*72 + kk*32 + cq*8]);
        #pragma unroll
        for (int n=0;n<4;n++) bb[n]=*reinterpret_cast<const s8vec*>(&Bs[(n0+n*16+ln)*72 + kk*32 + cq*8]);
        #pragma unroll
        for (int m=0;m<4;m++)
            #pragma unroll
            for (int n=0;n<4;n++)
                acc[m][n]=__builtin_amdgcn_mfma_f32_16x16x32_bf16(a[m],bb[n],acc[m][n],0,0,0);
    }
    bf16* Ab = Abuf + (size_t)l*WW*WW;
    #pragma unroll
    for (int m=0;m<4;m++){
        #pragma unroll
        for (int r=0;r<4;r++){
            int w = mt*128 + m0 + m*16 + cq*4 + r;
            #pragma unroll
            for (int n=0;n<4;n++){
                int v = nt*128 + n0 + n*16 + ln;
                Ab[(size_t)w*WW + v] = f2b(acc[m][n][r]);
            }
        }
    }
}

// ---------------- K3a: softmax stats, vectorized single pass ----------------
// grid (HH, 6), block 256 (4 waves). 16-lane groups: lane ln holds chunks 8*(ln+16i),
// i=0..2 of one row; wave covers 4 rows/iter x 4 iters = 16 rows; block = 64 rows (seg).
// Row stats (rmax, irsum) final here. Col stats kept as online-(m,s) partials per
// (l,seg) -> pcm/pcs (stored in the dead Q region); k3b combines the 6 seg partials.
__global__ __launch_bounds__(256) void k3a(
    const bf16* __restrict__ Abuf, float* __restrict__ rmax, float* __restrict__ irsum,
    float* __restrict__ pcm, float* __restrict__ pcs, int b)
{
    __shared__ float cpm[4][384], cps[4][384];
    int t=threadIdx.x, l=blockIdx.x, seg=blockIdx.y;
    int bh=b*HH+l;
    const bf16* Ab = Abuf + (size_t)l*WW*WW;
    int wid=t>>6, lane=t&63, r4=lane>>4, ln=lane&15;
    float cm[24], cs[24];
    #pragma unroll
    for (int c=0;c<24;c++){ cm[c]=-1e30f; cs[c]=0.f; }

    for (int it=0; it<4; it++){
        int w = seg*64 + wid*16 + it*4 + r4;
        const bf16* row = Ab + (size_t)w*WW;
        float x[24];
        #pragma unroll
        for (int i=0;i<3;i++){
            uint4 u = *reinterpret_cast<const uint4*>(row + 8*(ln+16*i));
            const unsigned short* p = reinterpret_cast<const unsigned short*>(&u);
            #pragma unroll
            for (int e=0;e<8;e++) x[i*8+e] = bfu2f(p[e]);
        }
        // row max + sum (16-lane group reduce)
        float m = x[0];
        #pragma unroll
        for (int c=1;c<24;c++) m = fmaxf(m, x[c]);
        #pragma unroll
        for (int o=1;o<16;o<<=1) m = fmaxf(m, __shfl_xor(m, o, 64));
        float s = 0.f;
        #pragma unroll
        for (int c=0;c<24;c++) s += __expf(x[c]-m);
        #pragma unroll
        for (int o=1;o<16;o<<=1) s += __shfl_xor(s, o, 64);
        if (ln==0){ rmax[(size_t)bh*WW+w]=m; irsum[(size_t)bh*WW+w]=1.f/s; }
        // col online merge
        #pragma unroll
        for (int c=0;c<24;c++){
            float mn = fmaxf(cm[c], x[c]);
            cs[c] = cs[c]*__expf(cm[c]-mn) + __expf(x[c]-mn);
            cm[c] = mn;
        }
    }
    // reduce across the 4 r4 row-groups (same cols)
    #pragma unroll
    for (int o=16;o<64;o<<=1){
        #pragma unroll
        for (int c=0;c<24;c++){
            float om = __shfl_xor(cm[c], o, 64);
            float os = __shfl_xor(cs[c], o, 64);
            float mn = fmaxf(cm[c], om);
            cs[c] = cs[c]*__expf(cm[c]-mn) + os*__expf(om-mn);
            cm[c] = mn;
        }
    }
    if (r4==0){
        #pragma unroll
        for (int i=0;i<3;i++)
            #pragma unroll
            for (int e=0;e<8;e++){
                cpm[wid][8*(ln+16*i)+e]=cm[i*8+e];
                cps[wid][8*(ln+16*i)+e]=cs[i*8+e];
            }
    }
    __syncthreads();
    for (int c=t;c<384;c+=256){
        float M=cpm[0][c], S=cps[0][c];
        #pragma unroll
        for (int p2=1;p2<4;p2++){
            float om=cpm[p2][c], os=cps[p2][c];
            float mn=fmaxf(M,om);
            S = S*__expf(M-mn) + os*__expf(om-mn);
            M = mn;
        }
        pcm[((size_t)l*6+seg)*384+c]=M;
        pcs[((size_t)l*6+seg)*384+c]=S;
    }
}

// ---------------- K3b: combine col partials -> cmax/icsum; zero colsum accumulator ----------------
// grid HH, block 384
__global__ __launch_bounds__(384) void k3b(
    const float* __restrict__ pcm, const float* __restrict__ pcs,
    float* __restrict__ cmax, float* __restrict__ icsum,
    float* __restrict__ mr2l_acc, int b)
{
    int l=blockIdx.x, c=threadIdx.x, bh=b*HH+l;
    float M=-1e30f, S=0.f;
    for (int s=0;s<6;s++){
        float om=pcm[((size_t)l*6+s)*384+c], os=pcs[((size_t)l*6+s)*384+c];
        float mn=fmaxf(M,om);
        S = S*__expf(M-mn) + os*__expf(om-mn);
        M = mn;
    }
    cmax[(size_t)bh*WW+c]=M; icsum[(size_t)bh*WW+c]=1.f/S;
    mr2l_acc[(size_t)bh*WW+c]=0.f;
}

// ---------------- K_mats: A -> P (in-place) + LT, FUSED mask sums (k4 eliminated) ----------------
// mask_l2r holds rowsum(LT[w]) (consumers threshold >0.1 inline);
// mask_r2l holds colsum(P) via per-block LDS reduce + one atomicAdd per col (zeroed by k3b).
// Sums use the bf16-ROUNDED values -> bit-matches the old k4's post-rounding reads.
__global__ __launch_bounds__(256) void k_mats(
    bf16* __restrict__ AP, bf16* __restrict__ LT,
    const float* __restrict__ rmax, const float* __restrict__ irsum,
    const float* __restrict__ cmax, const float* __restrict__ icsum,
    float* __restrict__ mr2l_acc, float* __restrict__ ml2r_sum, int b)
{
    __shared__ float cssum[4][384];
    int t=threadIdx.x, l=blockIdx.x, seg=blockIdx.y;
    int bh=b*HH+l;
    bf16* Ab  = AP + (size_t)l*WW*WW;
    bf16* LTb = LT + (size_t)l*WW*WW;
    const float* rm=rmax+(size_t)bh*WW; const float* ris=irsum+(size_t)bh*WW;
    const float* cm=cmax+(size_t)bh*WW; const float* cis=icsum+(size_t)bh*WW;
    int wid=t>>6, lane6=t&63;
    float cmv[6], civ[6], colp[6];
    for (int s=0;s<6;s++){ cmv[s]=cm[s*64+lane6]; civ[s]=cis[s*64+lane6]; colp[s]=0.f; }
    for (int k=0;k<16;k++){
        int w = seg*64 + wid + 4*k;
        float rmw = rm[w], risw = ris[w];
        float rowp = 0.f;
        for (int s=0;s<6;s++){
            int v = s*64 + lane6;
            size_t idx = (size_t)w*WW + v;
            float a = b2f(Ab[idx]);
            bf16 pb = f2b(__expf(a - rmw)*risw);        // P[w][v] = M_r2l[w][v]
            bf16 lb = f2b(__expf(a - cmv[s])*civ[s]);   // LT[w][v] = M_l2r[v][w]
            Ab[idx]  = pb;
            LTb[idx] = lb;
            colp[s] += b2f(pb);
            rowp    += b2f(lb);
        }
        for (int o=32;o;o>>=1) rowp += __shfl_xor(rowp,o,64);
        if (lane6==0) ml2r_sum[(size_t)bh*WW+w] = rowp;   // w is wave-uniform
    }
    for (int s=0;s<6;s++) cssum[wid][s*64+lane6] = colp[s];
    __syncthreads();
    for (int c=t;c<384;c+=256)
        atomicAdd(&mr2l_acc[(size_t)bh*WW+c],
                  cssum[0][c]+cssum[1][c]+cssum[2][c]+cssum[3][c]);
}

// ---------------- K_trans: PT = P^T, vectorized global I/O ----------------
// grid (6,6,HH), block 256. f32 LDS tile (stride 65: both phases <=2-way, free).
__global__ __launch_bounds__(256) void k_trans(
    const bf16* __restrict__ Pm, bf16* __restrict__ PTm)
{
    __shared__ float tile[64][65];
    int t=threadIdx.x;
    int ti=blockIdx.x, tj=blockIdx.y, l=blockIdx.z;
    const bf16* Pb = Pm + (size_t)l*WW*WW;
    bf16* PTb = PTm + (size_t)l*WW*WW;
    #pragma unroll
    for (int i=0;i<2;i++){
        int lin=t+256*i; int r=lin>>3, c8=lin&7;
        uint4 u = *reinterpret_cast<const uint4*>(&Pb[(size_t)(ti*64+r)*WW + tj*64 + c8*8]);
        const unsigned short* p = reinterpret_cast<const unsigned short*>(&u);
        #pragma unroll
        for (int e=0;e<8;e++) tile[r][c8*8+e] = bfu2f(p[e]);
    }
    __syncthreads();
    #pragma unroll
    for (int i=0;i<2;i++){
        int lin=t+256*i; int vr=lin>>3, c8=lin&7;
        unsigned short o[8];
        #pragma unroll
        for (int e=0;e<8;e++) o[e] = f2bu(tile[c8*8+e][vr]);
        uint4 pk;
        pk.x = (unsigned)o[0] | ((unsigned)o[1]<<16);
        pk.y = (unsigned)o[2] | ((unsigned)o[3]<<16);
        pk.z = (unsigned)o[4] | ((unsigned)o[5]<<16);
        pk.w = (unsigned)o[6] | ((unsigned)o[7]<<16);
        *reinterpret_cast<uint4*>(&PTb[(size_t)(tj*64+vr)*WW + ti*64 + c8*8]) = pk;
    }
}

// ---------------- K5m -- unchanged ----------------
__global__ __launch_bounds__(256) void k5m(
    const bf16* __restrict__ Msrc, const bf16* __restrict__ VT,
    const float* __restrict__ xadd, const float* __restrict__ coef,
    float* __restrict__ outp, int b, int side)
{
    __shared__ bf16 As[64*72];   // VT tile [c][v]
    __shared__ bf16 Bs[64*72];   // M tile  [w][v]
    int t=threadIdx.x;
    int wt=blockIdx.x, l=blockIdx.y;
    int w0=wt*64;
    int wv=t>>6, lane=t&63;
    int cb=(wv>>1)*32, wb=(wv&1)*32;
    int ln=lane&15, cq=lane>>4;
    f4vec acc[2][2];
    #pragma unroll
    for (int m=0;m<2;m++)
        #pragma unroll
        for (int n=0;n<2;n++) acc[m][n]=(f4vec){0.f,0.f,0.f,0.f};
    const bf16* Mb = Msrc + (size_t)l*WW*WW;

    for (int vt=0;vt<6;vt++){
        int v0=vt*64;
        __syncthreads();
        for (int i=0;i<2;i++){
            int lin=t+256*i; int c=lin>>3, c8=lin&7;
            *reinterpret_cast<uint4*>(&As[c*72+c8*8]) =
                *reinterpret_cast<const uint4*>(&VT[(size_t)c*HW + (size_t)l*WW + v0 + c8*8]);
        }
        if (side==0){
            for (int i=0;i<2;i++){
                int lin=t+256*i; int r=lin>>3, c8=lin&7;
                *reinterpret_cast<uint4*>(&Bs[r*72+c8*8]) =
                    *reinterpret_cast<const uint4*>(&Mb[(size_t)(w0+r)*WW + v0 + c8*8]);
            }
        } else {
            int wl=t&63, j0=t>>6;
            for (int jj=0;jj<16;jj++){
                int j=j0+4*jj;
                Bs[wl*72+j] = Mb[(size_t)(v0+j)*WW + w0 + wl];
            }
        }
        __syncthreads();
        #pragma unroll
        for (int kk=0;kk<2;kk++){
            s8vec a[2], bb[2];
            #pragma unroll
            for (int m=0;m<2;m++) a[m]=*reinterpret_cast<const s8vec*>(&As[(cb+m*16+ln)*72+kk*32+cq*8]);
            #pragma unroll
            for (int n=0;n<2;n++) bb[n]=*reinterpret_cast<const s8vec*>(&Bs[(wb+n*16+ln)*72+kk*32+cq*8]);
            #pragma unroll
            for (int m=0;m<2;m++)
                #pragma unroll
                for (int n=0;n<2;n++)
                    acc[m][n]=__builtin_amdgcn_mfma_f32_16x16x32_bf16(a[m],bb[n],acc[m][n],0,0,0);
        }
    }
    const float* xb = xadd + (size_t)b*CHW + (size_t)l*WW + w0;
    float*      ob = outp + (size_t)b*CHW + (size_t)l*WW + w0;
    #pragma unroll
    for (int m=0;m<2;m++){
        #pragma unroll
        for (int r=0;r<4;r++){
            int c = cb + m*16 + cq*4 + r;
            float cf = coef[c];
            #pragma unroll
            for (int n=0;n<2;n++){
                int w = wb + n*16 + ln;
                ob[(size_t)c*HW + w] = xb[(size_t)c*HW + w] + cf*acc[m][n][r];
            }
        }
    }
}

// ---------------- K6 -- unchanged except mask threshold inline ----------------
__global__ __launch_bounds__(256) void k6_mfma(
    const bf16* __restrict__ Pm, const bf16* __restrict__ LTm, const bf16* __restrict__ PTm,
    const float* __restrict__ mask_r2l, const float* __restrict__ mask_l2r,
    double* __restrict__ dsum, int b)
{
    __shared__ bf16 As[2][128*64];   // [buf][w][k] swizzled
    __shared__ bf16 Bs[2][128*64];   // [buf][u][k] swizzled
    int t=threadIdx.x;
    int wg=blockIdx.x;
    int xcd = wg & 7, j = wg >> 3;
    int lgrp = j/18, tile = j - lgrp*18;
    int l = xcd + 8*lgrp;
    int which = tile/9; int xt = tile - which*9;
    int wt = xt/3, ut = xt - wt*3;
    int w0=wt*128, u0=ut*128, bh=b*HH+l;
    const float* msk = which ? (mask_r2l+(size_t)bh*WW) : (mask_l2r+(size_t)bh*WW);
    const bf16* Ap = Pm  + (size_t)l*WW*WW;
    const bf16* Lt = LTm + (size_t)l*WW*WW;
    const bf16* Bsrc = (which==0 ? LTm : PTm) + (size_t)l*WW*WW;

    int wv=t>>6, lane=t&63;
    int qr=wv>>1, qc=wv&1;
    int ln=lane&15, cq=lane>>4;

    uint4 rb[4], ra[4];
    uint4 r0[2], r1[2];

    auto stage_read = [&](int kt){
        #pragma unroll
        for (int i=0;i<4;i++){
            int lin=t+256*i; int u=lin>>3, c8=lin&7;
            rb[i] = *reinterpret_cast<const uint4*>(&Bsrc[(size_t)(u0+u)*WW + kt*64 + c8*8]);
        }
        if (which==0){
            #pragma unroll
            for (int i=0;i<4;i++){
                int lin=t+256*i; int w=lin>>3, c8=lin&7;
                ra[i] = *reinterpret_cast<const uint4*>(&Ap[(size_t)(w0+w)*WW + kt*64 + c8*8]);
            }
        } else {
            #pragma unroll
            for (int i=0;i<2;i++){
                int p=(t>>4)+16*i, wc=t&15;
                const bf16* base = &Lt[(size_t)(kt*64 + 2*p)*WW + w0 + wc*8];
                r0[i] = *reinterpret_cast<const uint4*>(base);
                r1[i] = *reinterpret_cast<const uint4*>(base + WW);
            }
        }
    };
    auto stage_write = [&](int bufi){
        bf16* bsw = Bs[bufi]; bf16* asw = As[bufi];
        #pragma unroll
        for (int i=0;i<4;i++){
            int lin=t+256*i; int u=lin>>3, c8=lin&7;
            *reinterpret_cast<uint4*>((char*)bsw + u*128 + ((c8 ^ SWZ(u))<<4)) = rb[i];
        }
        if (which==0){
            #pragma unroll
            for (int i=0;i<4;i++){
                int lin=t+256*i; int w=lin>>3, c8=lin&7;
                *reinterpret_cast<uint4*>((char*)asw + w*128 + ((c8 ^ SWZ(w))<<4)) = ra[i];
            }
        } else {
            #pragma unroll
            for (int i=0;i<2;i++){
                int p=(t>>4)+16*i, wc=t&15;
                const unsigned short* q0 = reinterpret_cast<const unsigned short*>(&r0[i]);
                const unsigned short* q1 = reinterpret_cast<const unsigned short*>(&r1[i]);
                int cb2 = p>>2, off = (p&3)*4;
                #pragma unroll
                for (int jj=0;jj<8;jj++){
                    int w = wc*8 + jj;
                    unsigned val = (unsigned)q0[jj] | ((unsigned)q1[jj]<<16);
                    *reinterpret_cast<unsigned*>((char*)asw + w*128 + ((cb2 ^ SWZ(w))<<4) + off) = val;
                }
            }
        }
    };

    f4vec acc[4][4];
    #pragma unroll
    for (int m=0;m<4;m++)
        #pragma unroll
        for (int n=0;n<4;n++) acc[m][n]=(f4vec){0.f,0.f,0.f,0.f};

    stage_read(0);
    stage_write(0);
    __syncthreads();
    int cur=0;
    for (int kt=0; kt<6; kt++){
        if (kt<5) stage_read(kt+1);
        const bf16* as = As[cur]; const bf16* bs = Bs[cur];
        #pragma unroll
        for (int kk=0;kk<2;kk++){
            s8vec a[4], bb[4];
            #pragma unroll
            for (int m=0;m<4;m++){
                int r = qr*64 + m*16 + ln;
                a[m] = *reinterpret_cast<const s8vec*>(
                    (const char*)as + r*128 + (((kk*4+cq) ^ SWZ(r))<<4));
            }
            #pragma unroll
            for (int n=0;n<4;n++){
                int u = qc*64 + n*16 + ln;
                bb[n] = *reinterpret_cast<const s8vec*>(
                    (const char*)bs + u*128 + (((kk*4+cq) ^ SWZ(u))<<4));
            }
            #pragma unroll
            for (int m=0;m<4;m++)
                #pragma unroll
                for (int n=0;n<4;n++)
                    acc[m][n]=__builtin_amdgcn_mfma_f32_16x16x32_bf16(a[m],bb[n],acc[m][n],0,0,0);
        }
        if (kt<5) stage_write(cur^1);
        __syncthreads();
        cur ^= 1;
    }

    float local = 0.f;
    #pragma unroll
    for (int n=0;n<4;n++){
        int ua = u0 + qc*64 + n*16 + ln;
        float mv = (msk[ua] > 0.1f) ? 1.f : 0.f;
        #pragma unroll
        for (int m=0;m<4;m++){
            int wbase = w0 + qr*64 + m*16 + cq*4;
            #pragma unroll
            for (int r=0;r<4;r++)
                local += mv * fabsf(acc[m][n][r] - ((ua==wbase+r)?1.f:0.f));
        }
    }
    for (int o=32;o;o>>=1) local += __shfl_xor(local,o,64);
    float* red = (float*)As;
    if (lane==0) red[wv]=local;
    __syncthreads();
    if (t==0) atomicAdd(&dsum[0], (double)(red[0]+red[1]+red[2]+red[3]));
}

// ---------------- K78 -- unchanged except mask threshold inline ----------------
__global__ __launch_bounds__(256) void k78_photo_smooth(
    const bf16* __restrict__ Pm, const bf16* __restrict__ LTm,
    const float* __restrict__ mask_r2l, const float* __restrict__ mask_l2r,
    const float* __restrict__ LRl, const float* __restrict__ LRr,
    float* __restrict__ out2, float* __restrict__ out3, double* __restrict__ dsum, int b)
{
    __shared__ unsigned short lrR[3*WW], lrL[3*WW];   // bf16-packed LR rows
    __shared__ float redP[4], redW[4], redH[4];
    int t=threadIdx.x;
    int wg=blockIdx.x;
    int xcd = wg & 7, j = wg >> 3;          // j 0..71
    int lgrp = j/6, seg = j - lgrp*6;       // lgrp 0..11, seg 0..5
    int l = xcd*12 + lgrp;
    int bh = b*HH + l;

    for (int c=0;c<3;c++){
        size_t base = ((size_t)(b*3+c)*HH + l)*WW;
        if (t < 96){
            float4 vl = *reinterpret_cast<const float4*>(&LRl[base + t*4]);
            float4 vr = *reinterpret_cast<const float4*>(&LRr[base + t*4]);
            ushort4 pl, pr;
            pl.x=f2bu(vl.x); pl.y=f2bu(vl.y); pl.z=f2bu(vl.z); pl.w=f2bu(vl.w);
            pr.x=f2bu(vr.x); pr.y=f2bu(vr.y); pr.z=f2bu(vr.z); pr.w=f2bu(vr.w);
            *reinterpret_cast<ushort4*>(&lrL[c*WW + t*4]) = pl;
            *reinterpret_cast<ushort4*>(&lrR[c*WW + t*4]) = pr;
            if (seg==0){
                *reinterpret_cast<float4*>(&out2[base + t*4]) = vl;
                *reinterpret_cast<float4*>(&out3[base + t*4]) = vr;
            }
        }
    }
    __syncthreads();

    int wid=t>>6, lane=t&63;
    int r4=lane>>4, ln=lane&15;
    const bf16* Pb  = Pm  + (size_t)l*WW*WW;
    const bf16* LTb = LTm + (size_t)l*WW*WW;
    bool dnok = (l < HH-1);
    const bf16* Pdn = Pb  + (dnok ? (size_t)WW*WW : 0);
    const bf16* Ldn = LTb + (dnok ? (size_t)WW*WW : 0);
    float fdn = dnok ? 1.f : 0.f;
    int src_same = (lane & 48) | ((ln+1)&15);
    int src_zero = (lane & 48);

    float phL=0.f, lwv=0.f, lhv=0.f;

    for (int it=0; it<4; it++){
        int w = seg*64 + wid*16 + it*4 + r4;
        int wn = (w<WW-1) ? w+1 : w;
        float fwn = (w<WW-1) ? 1.f : 0.f;
        const bf16* pr  = Pb  + (size_t)w*WW;
        const bf16* lr_ = LTb + (size_t)w*WW;
        const bf16* prn = Pb  + (size_t)wn*WW;
        const bf16* lrn = LTb + (size_t)wn*WW;
        const bf16* prd = Pdn + (size_t)w*WW;
        const bf16* lrd = Ldn + (size_t)w*WW;

        uint4 up[3], ul[3], upn[3], uln[3], upd[3], uld[3];
        #pragma unroll
        for (int i=0;i<3;i++){
            int off = 8*(ln + 16*i);
            up[i]  = *reinterpret_cast<const uint4*>(pr  + off);
            ul[i]  = *reinterpret_cast<const uint4*>(lr_ + off);
            upn[i] = *reinterpret_cast<const uint4*>(prn + off);
            uln[i] = *reinterpret_cast<const uint4*>(lrn + off);
            upd[i] = *reinterpret_cast<const uint4*>(prd + off);
            uld[i] = *reinterpret_cast<const uint4*>(lrd + off);
        }
        float pn0[3], ln0[3];
        #pragma unroll
        for (int i=0;i<3;i++){
            pn0[i] = bfu2f((unsigned short)(upn[i].x & 0xffffu));
            ln0[i] = bfu2f((unsigned short)(uln[i].x & 0xffffu));
        }

        float a0=0.f,a1=0.f,a2=0.f, d0=0.f,d1=0.f,d2=0.f;
        #pragma unroll
        for (int i=0;i<3;i++){
            const unsigned short* pu = reinterpret_cast<const unsigned short*>(&up[i]);
            const unsigned short* lu = reinterpret_cast<const unsigned short*>(&ul[i]);
            const unsigned short* pnu= reinterpret_cast<const unsigned short*>(&upn[i]);
            const unsigned short* lnu= reinterpret_cast<const unsigned short*>(&uln[i]);
            const unsigned short* pdu= reinterpret_cast<const unsigned short*>(&upd[i]);
            const unsigned short* ldu= reinterpret_cast<const unsigned short*>(&uld[i]);
            int v8 = 8*(ln+16*i);
            uint4 R0 = *reinterpret_cast<const uint4*>(&lrR[0*WW + v8]);
            uint4 R1 = *reinterpret_cast<const uint4*>(&lrR[1*WW + v8]);
            uint4 R2 = *reinterpret_cast<const uint4*>(&lrR[2*WW + v8]);
            uint4 L0 = *reinterpret_cast<const uint4*>(&lrL[0*WW + v8]);
            uint4 L1 = *reinterpret_cast<const uint4*>(&lrL[1*WW + v8]);
            uint4 L2 = *reinterpret_cast<const uint4*>(&lrL[2*WW + v8]);
            const unsigned short* r0c = reinterpret_cast<const unsigned short*>(&R0);
            const unsigned short* r1c = reinterpret_cast<const unsigned short*>(&R1);
            const unsigned short* r2c = reinterpret_cast<const unsigned short*>(&R2);
            const unsigned short* l0c = reinterpret_cast<const unsigned short*>(&L0);
            const unsigned short* l1c = reinterpret_cast<const unsigned short*>(&L1);
            const unsigned short* l2c = reinterpret_cast<const unsigned short*>(&L2);

            float pn_same = __shfl(pn0[i], src_same, 64);
            float ln_same = __shfl(ln0[i], src_same, 64);
            float pn_next = __shfl(pn0[i<2 ? i+1 : 0], src_zero, 64);
            float ln_next = __shfl(ln0[i<2 ? i+1 : 0], src_zero, 64);
            float pn_last = (ln==15) ? pn_next : pn_same;
            float ln_last = (ln==15) ? ln_next : ln_same;

            float pc[8], lc[8];
            #pragma unroll
            for (int e=0;e<8;e++){ pc[e]=bfu2f(pu[e]); lc[e]=bfu2f(lu[e]); }
            #pragma unroll
            for (int e=0;e<8;e++){
                a0 += pc[e]*bfu2f(r0c[e]); a1 += pc[e]*bfu2f(r1c[e]); a2 += pc[e]*bfu2f(r2c[e]);
                d0 += lc[e]*bfu2f(l0c[e]); d1 += lc[e]*bfu2f(l1c[e]); d2 += lc[e]*bfu2f(l2c[e]);
            }
            #pragma unroll
            for (int e=0;e<8;e++){
                lhv += fdn*(fabsf(pc[e]-bfu2f(pdu[e])) + fabsf(lc[e]-bfu2f(ldu[e])));
            }
            #pragma unroll
            for (int e=0;e<7;e++){
                lwv += fwn*(fabsf(pc[e]-bfu2f(pnu[e+1])) + fabsf(lc[e]-bfu2f(lnu[e+1])));
            }
            {
                float m = (v8+7 < WW-1) ? fwn : 0.f;
                lwv += m*(fabsf(pc[7]-pn_last) + fabsf(lc[7]-ln_last));
            }
        }
        #pragma unroll
        for (int o=8;o;o>>=1){
            a0+=__shfl_xor(a0,o,64); a1+=__shfl_xor(a1,o,64); a2+=__shfl_xor(a2,o,64);
            d0+=__shfl_xor(d0,o,64); d1+=__shfl_xor(d1,o,64); d2+=__shfl_xor(d2,o,64);
        }
        if (ln==0){
            float mkL = (mask_l2r[(size_t)bh*WW+w] > 0.1f) ? 1.f : 0.f;
            float mkR = (mask_r2l[(size_t)bh*WW+w] > 0.1f) ? 1.f : 0.f;
            size_t lrb = ((size_t)(b*3)*HH + l)*WW + w;
            size_t chs = (size_t)HH*WW;
            float l0v=LRl[lrb], l1v=LRl[lrb+chs], l2v=LRl[lrb+2*chs];
            float r0v=LRr[lrb], r1v=LRr[lrb+chs], r2v=LRr[lrb+2*chs];
            phL += mkL*(fabsf(l0v-a0)+fabsf(l1v-a1)+fabsf(l2v-a2));
            phL += mkR*(fabsf(r0v-d0)+fabsf(r1v-d1)+fabsf(r2v-d2));
        }
    }
    for (int o=32;o;o>>=1){
        phL+=__shfl_xor(phL,o,64); lwv+=__shfl_xor(lwv,o,64); lhv+=__shfl_xor(lhv,o,64);
    }
    if (lane==0){ redP[wid]=phL; redW[wid]=lwv; redH[wid]=lhv; }
    __syncthreads();
    if (t==0){
        atomicAdd(&dsum[1], (double)(redP[0]+redP[1]+redP[2]+redP[3]));
        atomicAdd(&dsum[3], (double)(redW[0]+redW[1]+redW[2]+redW[3]));
        atomicAdd(&dsum[2], (double)(redH[0]+redH[1]+redH[2]+redH[3]));
    }
}

// ---------------- K9: final loss -- unchanged ----------------
__global__ void k9_final(const double* __restrict__ dsum, const float* __restrict__ lossin,
                         float* __restrict__ out4)
{
    if (threadIdx.x==0){
        double cyc  = dsum[0]/(double)((size_t)BB*HH*WW*WW);
        double photo= dsum[1]/(double)((size_t)BB*3*HH*WW);
        double lhv  = dsum[2]/(double)((size_t)BB*(HH-1)*WW*WW);
        double lwv  = dsum[3]/(double)((size_t)BB*HH*(WW-1)*(WW-1));
        double res  = (double)lossin[0] + 0.0025*(photo + 0.1*(lwv+lhv) + cyc);
        out4[0]=(float)res;
    }
}

extern "C" void kernel_launch(void* const* d_in, const int* in_sizes, int n_in,
                              void* d_out, int out_size, void* d_ws, size_t ws_size,
                              hipStream_t stream)
{
    (void)in_sizes; (void)n_in; (void)out_size; (void)ws_size;
    const float* x_l  = (const float*)d_in[0];
    const float* x_r  = (const float*)d_in[1];
    const float* LRl  = (const float*)d_in[2];
    const float* LRr  = (const float*)d_in[3];
    const float* lossi= (const float*)d_in[4];
    const float* nlw  = (const float*)d_in[5];
    const float* nlb  = (const float*)d_in[6];
    const float* nrw  = (const float*)d_in[7];
    const float* nrb  = (const float*)d_in[8];
    const float* lp1w = (const float*)d_in[9];
    const float* lp1b = (const float*)d_in[10];
    const float* rp1w = (const float*)d_in[11];
    const float* rp1b = (const float*)d_in[12];
    const float* lp2w = (const float*)d_in[13];
    const float* lp2b = (const float*)d_in[14];
    const float* rp2w = (const float*)d_in[15];
    const float* rp2b = (const float*)d_in[16];
    const float* beta = (const float*)d_in[17];
    const float* gamma= (const float*)d_in[18];

    bf16* Abuf = (bf16*)d_ws;             // A -> P in-place
    bf16* LTb  = Abuf + ACHUNK;
    bf16* PTb  = Abuf + 2*ACHUNK;
    float* wsf = (float*)((char*)d_ws + 3*ACHUNK*2);
    float* rmax=wsf, *irsum=wsf+SST, *cmax=wsf+2*SST, *icsum=wsf+3*SST;
    float* mask_r2l=wsf+4*SST, *mask_l2r=wsf+5*SST;
    double* dsum=(double*)(wsf+6*SST);
    // Q and V alias the PT chunk (dead before k_trans); k3 col partials reuse Q's slot
    // (Q dead after k_attn, partials dead after k3b, V untouched: 1.8MB << 2 QELEMS*2B).
    bf16* Qlb = PTb;
    bf16* Qrb = PTb + QELEMS;
    bf16* Vlb = PTb + 2*QELEMS;
    bf16* Vrb = PTb + 3*QELEMS;
    float* pcm = (float*)PTb;
    float* pcs = pcm + (size_t)HH*6*384;

    float* out  = (float*)d_out;
    float* out0 = out;
    float* out1 = out + (size_t)BB*CHW;
    float* out2 = out + 2*(size_t)BB*CHW;
    float* out3 = out2 + (size_t)BB*3*HW;
    float* out4 = out3 + (size_t)BB*3*HW;

    k0_zero<<<1,64,0,stream>>>(dsum);
    for (int b=0;b<BB;b++){
        k_qv<<<dim3(6,HH),256,0,stream>>>(x_l,x_r,nlw,nlb,nrw,nrb,
                                          lp1w,lp1b,rp1w,rp1b,lp2w,lp2b,rp2w,rp2b,
                                          Qlb,Qrb,Vlb,Vrb,b);
        k_attn<<<dim3(3,3,HH),256,0,stream>>>(Qlb,Qrb,Abuf);
        k3a<<<dim3(HH,6),256,0,stream>>>(Abuf,rmax,irsum,pcm,pcs,b);
        k3b<<<HH,384,0,stream>>>(pcm,pcs,cmax,icsum,mask_r2l,b);
        k_mats<<<dim3(HH,6),256,0,stream>>>(Abuf,LTb,rmax,irsum,cmax,icsum,
                                            mask_r2l,mask_l2r,b);
        k5m<<<dim3(6,HH),256,0,stream>>>(Abuf,Vrb,x_l,beta, out0,b,0);   // V consumed here,
        k5m<<<dim3(6,HH),256,0,stream>>>(LTb, Vlb,x_r,gamma,out1,b,1);   // BEFORE k_trans
        k_trans<<<dim3(6,6,HH),256,0,stream>>>(Abuf,PTb);
        k6_mfma<<<1728,256,0,stream>>>(Abuf,LTb,PTb,mask_r2l,mask_l2r,dsum,b);
        k78_photo_smooth<<<576,256,0,stream>>>(Abuf,LTb,mask_r2l,mask_l2r,LRl,LRr,out2,out3,dsum,b);
    }
    k9_final<<<1,64,0,stream>>>(dsum,lossi,out4);
}

// Round 10
// 1094.787 us; speedup vs baseline: 1.6999x; 1.0454x over previous
//
#include <hip/hip_runtime.h>
#include <hip/hip_bf16.h>

#define BB 4
#define CC 64
#define HH 96
#define WW 384
#define HW (HH*WW)          // 36864
#define CHW (CC*HW)         // 2359296
#define BH (BB*HH)          // 384
#define EPSV 1e-6f
#define QSCALE 0.125f       // C^-0.5, folded into Q_l

typedef __hip_bfloat16 bf16;
typedef short s8vec __attribute__((ext_vector_type(8)));   // 8 bf16 = one MFMA frag
typedef float f4vec __attribute__((ext_vector_type(4)));   // MFMA accum

__device__ __forceinline__ float b2f(bf16 v){ return __bfloat162float(v); }
__device__ __forceinline__ bf16 f2b(float v){ return __float2bfloat16(v); }
__device__ __forceinline__ unsigned short f2bu(float f){
    bf16 h = __float2bfloat16(f);
    return __builtin_bit_cast(unsigned short, h);
}
__device__ __forceinline__ float bfu2f(unsigned short u){
    unsigned v = ((unsigned)u)<<16;
    return __builtin_bit_cast(float, v);
}

// ---------------- workspace layout (per-batch chunk) ----------------
#define ACHUNK ((size_t)HH*WW*WW)    // 14,155,776 elems
#define SST ((size_t)BH*WW)          // 147456
#define QELEMS ((size_t)HW*64)       // 2,359,296

// LDS chunk swizzle for k6 (unchanged from passing R6)
#define SWZ(row) ((((row) + ((row)>>3)) & 7))

// ---------------- K0: zero loss accumulators ----------------
__global__ void k0_zero(double* dsum){
    if (threadIdx.x < 4) dsum[threadIdx.x] = 0.0;
}

// ---------------- K_qv -- unchanged ----------------
__global__ __launch_bounds__(256) void k_qv(
    const float* __restrict__ xl, const float* __restrict__ xr,
    const float* __restrict__ nlw, const float* __restrict__ nlb,
    const float* __restrict__ nrw, const float* __restrict__ nrb,
    const float* __restrict__ P1l, const float* __restrict__ b1l,
    const float* __restrict__ P1r, const float* __restrict__ b1r,
    const float* __restrict__ P2l, const float* __restrict__ b2l,
    const float* __restrict__ P2r, const float* __restrict__ b2r,
    bf16* __restrict__ Ql, bf16* __restrict__ Qr,
    bf16* __restrict__ Vl, bf16* __restrict__ Vr, int b)
{
    __shared__ float xs[64*64];                  // [c][w]
    __shared__ float p1s[64*65], p2s[64*65];     // [o][c]
    __shared__ float nws[64], nbs[64], b1s[64], b2s[64];
    __shared__ float mus[64], ris[64];
    int t = threadIdx.x;
    int wt = blockIdx.x, l = blockIdx.y;
    int w0 = wt*64;

    for (int side=0; side<2; side++){
        const float* x  = side ? xr  : xl;
        const float* nw = side ? nrw : nlw;
        const float* nb = side ? nrb : nlb;
        const float* P1 = side ? P1r : P1l;
        const float* B1 = side ? b1r : b1l;
        const float* P2 = side ? P2r : P2l;
        const float* B2 = side ? b2r : b2l;
        bf16* Q = side ? Qr : Ql;
        bf16* V = side ? Vr : Vl;
        float qsc = side ? 1.f : QSCALE;

        if (t < 64){ nws[t]=nw[t]; nbs[t]=nb[t]; b1s[t]=B1[t]; b2s[t]=B2[t]; }
        for (int k=0;k<16;k++){
            int i=t+256*k; int o=i>>6, c=i&63;
            p1s[o*65+c]=P1[i]; p2s[o*65+c]=P2[i];
        }
        const float* xb = x + (size_t)b*CHW + (size_t)l*WW + w0;
        for (int k=0;k<16;k++){
            int c=(t>>6)+4*k, w=t&63;
            xs[c*64+w] = xb[(size_t)c*HW + w];
        }
        __syncthreads();
        if (t < 64){
            float s=0.f, ss=0.f;
            for (int c=0;c<64;c++){ float v=xs[c*64+t]; s+=v; ss+=v*v; }
            float mu=s*(1.f/64.f), var=ss*(1.f/64.f)-mu*mu;
            mus[t]=mu; ris[t]=rsqrtf(var+EPSV);
        }
        __syncthreads();

        {
            int vq=t&15, ov=t>>4;
            float acc[4][4]={};
            for (int c=0;c<64;c++){
                float xv[4];
                for (int j=0;j<4;j++) xv[j]=xs[c*64+vq*4+j];
                for (int i=0;i<4;i++){
                    float w2=p2s[(ov*4+i)*65+c];
                    for (int j=0;j<4;j++) acc[i][j]+=w2*xv[j];
                }
            }
            for (int i=0;i<4;i++){
                int c=ov*4+i;
                ushort4 pk;
                pk.x=f2bu(acc[i][0]+b2s[c]); pk.y=f2bu(acc[i][1]+b2s[c]);
                pk.z=f2bu(acc[i][2]+b2s[c]); pk.w=f2bu(acc[i][3]+b2s[c]);
                *reinterpret_cast<ushort4*>(&V[(size_t)c*HW + (size_t)l*WW + w0 + vq*4]) = pk;
            }
        }
        {
            int cq=t&15, wq=t>>4;
            float muj[4], rij[4];
            for (int j=0;j<4;j++){ muj[j]=mus[wq*4+j]; rij[j]=ris[wq*4+j]; }
            float acc[4][4]={};
            for (int c=0;c<64;c++){
                float nwc=nws[c], nbc=nbs[c];
                float xn[4];
                for (int j=0;j<4;j++) xn[j]=(xs[c*64+wq*4+j]-muj[j])*rij[j]*nwc+nbc;
                for (int i=0;i<4;i++){
                    float w1=p1s[(cq*4+i)*65+c];
                    for (int j=0;j<4;j++) acc[i][j]+=w1*xn[j];
                }
            }
            for (int j=0;j<4;j++){
                int w=w0+wq*4+j;
                ushort4 pk;
                pk.x=f2bu(qsc*(acc[0][j]+b1s[cq*4+0]));
                pk.y=f2bu(qsc*(acc[1][j]+b1s[cq*4+1]));
                pk.z=f2bu(qsc*(acc[2][j]+b1s[cq*4+2]));
                pk.w=f2bu(qsc*(acc[3][j]+b1s[cq*4+3]));
                *reinterpret_cast<ushort4*>(&Q[((size_t)l*WW + w)*64 + cq*4]) = pk;
            }
        }
        __syncthreads();   // LDS reuse by next side
    }
}

// ---------------- K_attn: A = Q_l^T Q_r via MFMA, LDS-repacked vector C-write ----------------
// MFMA part unchanged; C now goes acc -> LDS (stride 132: b16 writes 2-way-free) ->
// fully coalesced uint4 row stores (was 256 scalar 2B stores/thread).
__global__ __launch_bounds__(256) void k_attn(
    const bf16* __restrict__ Ql, const bf16* __restrict__ Qr,
    bf16* __restrict__ Abuf)
{
    __shared__ bf16 smem[2*128*72];     // As | Bs; reused as Cs[128][132] after MFMA
    bf16* As = smem;
    bf16* Bs = smem + 128*72;
    int t=threadIdx.x;
    int mt=blockIdx.x, nt=blockIdx.y, l=blockIdx.z;
    const bf16* Qa = Ql + ((size_t)l*WW + mt*128)*64;
    const bf16* Qb = Qr + ((size_t)l*WW + nt*128)*64;
    for (int i=0;i<4;i++){
        int lin=t+256*i;
        int r=lin>>3, c8=lin&7;
        *reinterpret_cast<uint4*>(&As[r*72+c8*8]) =
            *reinterpret_cast<const uint4*>(&Qa[(size_t)r*64 + c8*8]);
        *reinterpret_cast<uint4*>(&Bs[r*72+c8*8]) =
            *reinterpret_cast<const uint4*>(&Qb[(size_t)r*64 + c8*8]);
    }
    __syncthreads();
    int wv=t>>6, lane=t&63;
    int m0=(wv>>1)*64, n0=(wv&1)*64;
    int ln=lane&15, cq=lane>>4;
    f4vec acc[4][4];
    #pragma unroll
    for (int m=0;m<4;m++)
        #pragma unroll
        for (int n=0;n<4;n++) acc[m][n]=(f4vec){0.f,0.f,0.f,0.f};
    #pragma unroll
    for (int kk=0;kk<2;kk++){
        s8vec a[4], bb[4];
        #pragma unroll
        for (int m=0;m<4;m++) a[m]=*reinterpret_cast<const s8vec*>(&As[(m0+m*16+ln)*72 + kk*32 + cq*8]);
        #pragma unroll
        for (int n=0;n<4;n++) bb[n]=*reinterpret_cast<const s8vec*>(&Bs[(n0+n*16+ln)*72 + kk*32 + cq*8]);
        #pragma unroll
        for (int m=0;m<4;m++)
            #pragma unroll
            for (int n=0;n<4;n++)
                acc[m][n]=__builtin_amdgcn_mfma_f32_16x16x32_bf16(a[m],bb[n],acc[m][n],0,0,0);
    }
    __syncthreads();   // all As/Bs reads done before overwrite
    // repack: C/D layout col = lane&15, row = (lane>>4)*4 + reg
    bf16* Cs = smem;   // [128][132]
    #pragma unroll
    for (int m=0;m<4;m++)
        #pragma unroll
        for (int r=0;r<4;r++){
            int wl = m0 + m*16 + cq*4 + r;
            #pragma unroll
            for (int n=0;n<4;n++){
                int vl = n0 + n*16 + ln;
                Cs[wl*132 + vl] = f2b(acc[m][n][r]);
            }
        }
    __syncthreads();
    bf16* Ab = Abuf + (size_t)l*WW*WW + (size_t)(mt*128)*WW + nt*128;
    #pragma unroll
    for (int i=0;i<8;i++){
        int lin = t + 256*i;
        int r_ = lin>>4, c8 = lin&15;
        const uint2* p0 = reinterpret_cast<const uint2*>((const char*)Cs + r_*264 + c8*16);
        uint2 q0 = p0[0], q1 = p0[1];
        uint4 pk; pk.x=q0.x; pk.y=q0.y; pk.z=q1.x; pk.w=q1.y;
        *reinterpret_cast<uint4*>(&Ab[(size_t)r_*WW + c8*8]) = pk;
    }
}

// ---------------- K3a: softmax stats, vectorized single pass -- unchanged ----------------
__global__ __launch_bounds__(256) void k3a(
    const bf16* __restrict__ Abuf, float* __restrict__ rmax, float* __restrict__ irsum,
    float* __restrict__ pcm, float* __restrict__ pcs, int b)
{
    __shared__ float cpm[4][384], cps[4][384];
    int t=threadIdx.x, l=blockIdx.x, seg=blockIdx.y;
    int bh=b*HH+l;
    const bf16* Ab = Abuf + (size_t)l*WW*WW;
    int wid=t>>6, lane=t&63, r4=lane>>4, ln=lane&15;
    float cm[24], cs[24];
    #pragma unroll
    for (int c=0;c<24;c++){ cm[c]=-1e30f; cs[c]=0.f; }

    for (int it=0; it<4; it++){
        int w = seg*64 + wid*16 + it*4 + r4;
        const bf16* row = Ab + (size_t)w*WW;
        float x[24];
        #pragma unroll
        for (int i=0;i<3;i++){
            uint4 u = *reinterpret_cast<const uint4*>(row + 8*(ln+16*i));
            const unsigned short* p = reinterpret_cast<const unsigned short*>(&u);
            #pragma unroll
            for (int e=0;e<8;e++) x[i*8+e] = bfu2f(p[e]);
        }
        float m = x[0];
        #pragma unroll
        for (int c=1;c<24;c++) m = fmaxf(m, x[c]);
        #pragma unroll
        for (int o=1;o<16;o<<=1) m = fmaxf(m, __shfl_xor(m, o, 64));
        float s = 0.f;
        #pragma unroll
        for (int c=0;c<24;c++) s += __expf(x[c]-m);
        #pragma unroll
        for (int o=1;o<16;o<<=1) s += __shfl_xor(s, o, 64);
        if (ln==0){ rmax[(size_t)bh*WW+w]=m; irsum[(size_t)bh*WW+w]=1.f/s; }
        #pragma unroll
        for (int c=0;c<24;c++){
            float mn = fmaxf(cm[c], x[c]);
            cs[c] = cs[c]*__expf(cm[c]-mn) + __expf(x[c]-mn);
            cm[c] = mn;
        }
    }
    #pragma unroll
    for (int o=16;o<64;o<<=1){
        #pragma unroll
        for (int c=0;c<24;c++){
            float om = __shfl_xor(cm[c], o, 64);
            float os = __shfl_xor(cs[c], o, 64);
            float mn = fmaxf(cm[c], om);
            cs[c] = cs[c]*__expf(cm[c]-mn) + os*__expf(om-mn);
            cm[c] = mn;
        }
    }
    if (r4==0){
        #pragma unroll
        for (int i=0;i<3;i++)
            #pragma unroll
            for (int e=0;e<8;e++){
                cpm[wid][8*(ln+16*i)+e]=cm[i*8+e];
                cps[wid][8*(ln+16*i)+e]=cs[i*8+e];
            }
    }
    __syncthreads();
    for (int c=t;c<384;c+=256){
        float M=cpm[0][c], S=cps[0][c];
        #pragma unroll
        for (int p2=1;p2<4;p2++){
            float om=cpm[p2][c], os=cps[p2][c];
            float mn=fmaxf(M,om);
            S = S*__expf(M-mn) + os*__expf(om-mn);
            M = mn;
        }
        pcm[((size_t)l*6+seg)*384+c]=M;
        pcs[((size_t)l*6+seg)*384+c]=S;
    }
}

// ---------------- K3b -- unchanged ----------------
__global__ __launch_bounds__(384) void k3b(
    const float* __restrict__ pcm, const float* __restrict__ pcs,
    float* __restrict__ cmax, float* __restrict__ icsum,
    float* __restrict__ mr2l_acc, int b)
{
    int l=blockIdx.x, c=threadIdx.x, bh=b*HH+l;
    float M=-1e30f, S=0.f;
    for (int s=0;s<6;s++){
        float om=pcm[((size_t)l*6+s)*384+c], os=pcs[((size_t)l*6+s)*384+c];
        float mn=fmaxf(M,om);
        S = S*__expf(M-mn) + os*__expf(om-mn);
        M = mn;
    }
    cmax[(size_t)bh*WW+c]=M; icsum[(size_t)bh*WW+c]=1.f/S;
    mr2l_acc[(size_t)bh*WW+c]=0.f;
}

// ---------------- K_mats: VECTORIZED A -> P + LT with fused mask sums ----------------
// grid (HH, 6), block 256. k78-style: 16-lane groups per row; lane ln holds chunks
// 8*(ln+16i), i=0..2. uint4 load A, 16 exps/chunk in-register, uint4 stores P & LT.
// cmax/icsum staged in LDS once per block. rowsum(LT): 16-lane shfl -> ml2r_sum[w].
// colsum(P): per-lane colp[24] -> shfl over r4 -> LDS over waves -> one atomicAdd/col.
__global__ __launch_bounds__(256) void k_mats(
    bf16* __restrict__ AP, bf16* __restrict__ LT,
    const float* __restrict__ rmax, const float* __restrict__ irsum,
    const float* __restrict__ cmax, const float* __restrict__ icsum,
    float* __restrict__ mr2l_acc, float* __restrict__ ml2r_sum, int b)
{
    __shared__ float cms[384], cis[384];
    __shared__ float cssum[4][384];
    int t=threadIdx.x, l=blockIdx.x, seg=blockIdx.y;
    int bh=b*HH+l;
    bf16* Ab  = AP + (size_t)l*WW*WW;
    bf16* LTb = LT + (size_t)l*WW*WW;
    const float* rm=rmax+(size_t)bh*WW; const float* ris=irsum+(size_t)bh*WW;
    if (t < 96){
        *reinterpret_cast<float4*>(&cms[t*4]) =
            *reinterpret_cast<const float4*>(&cmax[(size_t)bh*WW + t*4]);
        *reinterpret_cast<float4*>(&cis[t*4]) =
            *reinterpret_cast<const float4*>(&icsum[(size_t)bh*WW + t*4]);
    }
    __syncthreads();
    int wid=t>>6, lane=t&63, r4=lane>>4, ln=lane&15;
    float cmv[24], civ[24], colp[24];
    #pragma unroll
    for (int i=0;i<3;i++)
        #pragma unroll
        for (int e=0;e<8;e++){
            int v = 8*(ln+16*i)+e;
            cmv[i*8+e]=cms[v]; civ[i*8+e]=cis[v]; colp[i*8+e]=0.f;
        }

    for (int it=0; it<4; it++){
        int w = seg*64 + wid*16 + it*4 + r4;
        float rmw = rm[w], risw = ris[w];
        bf16* prow = Ab  + (size_t)w*WW;
        bf16* lrow = LTb + (size_t)w*WW;
        float rowp = 0.f;
        #pragma unroll
        for (int i=0;i<3;i++){
            int off = 8*(ln+16*i);
            uint4 u = *reinterpret_cast<const uint4*>(prow + off);
            const unsigned short* pu = reinterpret_cast<const unsigned short*>(&u);
            unsigned short po[8], lo[8];
            #pragma unroll
            for (int e=0;e<8;e++){
                float a = bfu2f(pu[e]);
                unsigned short pb = f2bu(__expf(a - rmw)*risw);
                unsigned short lb = f2bu(__expf(a - cmv[i*8+e])*civ[i*8+e]);
                po[e]=pb; lo[e]=lb;
                colp[i*8+e] += bfu2f(pb);
                rowp        += bfu2f(lb);
            }
            uint4 pk, lk;
            pk.x=(unsigned)po[0]|((unsigned)po[1]<<16); pk.y=(unsigned)po[2]|((unsigned)po[3]<<16);
            pk.z=(unsigned)po[4]|((unsigned)po[5]<<16); pk.w=(unsigned)po[6]|((unsigned)po[7]<<16);
            lk.x=(unsigned)lo[0]|((unsigned)lo[1]<<16); lk.y=(unsigned)lo[2]|((unsigned)lo[3]<<16);
            lk.z=(unsigned)lo[4]|((unsigned)lo[5]<<16); lk.w=(unsigned)lo[6]|((unsigned)lo[7]<<16);
            *reinterpret_cast<uint4*>(prow + off) = pk;
            *reinterpret_cast<uint4*>(lrow + off) = lk;
        }
        #pragma unroll
        for (int o=1;o<16;o<<=1) rowp += __shfl_xor(rowp,o,64);
        if (ln==0) ml2r_sum[(size_t)bh*WW+w] = rowp;
    }
    #pragma unroll
    for (int o=16;o<64;o<<=1)
        #pragma unroll
        for (int c=0;c<24;c++) colp[c] += __shfl_xor(colp[c],o,64);
    if (r4==0){
        #pragma unroll
        for (int i=0;i<3;i++)
            #pragma unroll
            for (int e=0;e<8;e++) cssum[wid][8*(ln+16*i)+e] = colp[i*8+e];
    }
    __syncthreads();
    for (int c=t;c<384;c+=256)
        atomicAdd(&mr2l_acc[(size_t)bh*WW+c],
                  cssum[0][c]+cssum[1][c]+cssum[2][c]+cssum[3][c]);
}

// ---------------- K_trans -- unchanged ----------------
__global__ __launch_bounds__(256) void k_trans(
    const bf16* __restrict__ Pm, bf16* __restrict__ PTm)
{
    __shared__ float tile[64][65];
    int t=threadIdx.x;
    int ti=blockIdx.x, tj=blockIdx.y, l=blockIdx.z;
    const bf16* Pb = Pm + (size_t)l*WW*WW;
    bf16* PTb = PTm + (size_t)l*WW*WW;
    #pragma unroll
    for (int i=0;i<2;i++){
        int lin=t+256*i; int r=lin>>3, c8=lin&7;
        uint4 u = *reinterpret_cast<const uint4*>(&Pb[(size_t)(ti*64+r)*WW + tj*64 + c8*8]);
        const unsigned short* p = reinterpret_cast<const unsigned short*>(&u);
        #pragma unroll
        for (int e=0;e<8;e++) tile[r][c8*8+e] = bfu2f(p[e]);
    }
    __syncthreads();
    #pragma unroll
    for (int i=0;i<2;i++){
        int lin=t+256*i; int vr=lin>>3, c8=lin&7;
        unsigned short o[8];
        #pragma unroll
        for (int e=0;e<8;e++) o[e] = f2bu(tile[c8*8+e][vr]);
        uint4 pk;
        pk.x = (unsigned)o[0] | ((unsigned)o[1]<<16);
        pk.y = (unsigned)o[2] | ((unsigned)o[3]<<16);
        pk.z = (unsigned)o[4] | ((unsigned)o[5]<<16);
        pk.w = (unsigned)o[6] | ((unsigned)o[7]<<16);
        *reinterpret_cast<uint4*>(&PTb[(size_t)(tj*64+vr)*WW + ti*64 + c8*8]) = pk;
    }
}

// ---------------- K5m -- unchanged ----------------
__global__ __launch_bounds__(256) void k5m(
    const bf16* __restrict__ Msrc, const bf16* __restrict__ VT,
    const float* __restrict__ xadd, const float* __restrict__ coef,
    float* __restrict__ outp, int b, int side)
{
    __shared__ bf16 As[64*72];   // VT tile [c][v]
    __shared__ bf16 Bs[64*72];   // M tile  [w][v]
    int t=threadIdx.x;
    int wt=blockIdx.x, l=blockIdx.y;
    int w0=wt*64;
    int wv=t>>6, lane=t&63;
    int cb=(wv>>1)*32, wb=(wv&1)*32;
    int ln=lane&15, cq=lane>>4;
    f4vec acc[2][2];
    #pragma unroll
    for (int m=0;m<2;m++)
        #pragma unroll
        for (int n=0;n<2;n++) acc[m][n]=(f4vec){0.f,0.f,0.f,0.f};
    const bf16* Mb = Msrc + (size_t)l*WW*WW;

    for (int vt=0;vt<6;vt++){
        int v0=vt*64;
        __syncthreads();
        for (int i=0;i<2;i++){
            int lin=t+256*i; int c=lin>>3, c8=lin&7;
            *reinterpret_cast<uint4*>(&As[c*72+c8*8]) =
                *reinterpret_cast<const uint4*>(&VT[(size_t)c*HW + (size_t)l*WW + v0 + c8*8]);
        }
        if (side==0){
            for (int i=0;i<2;i++){
                int lin=t+256*i; int r=lin>>3, c8=lin&7;
                *reinterpret_cast<uint4*>(&Bs[r*72+c8*8]) =
                    *reinterpret_cast<const uint4*>(&Mb[(size_t)(w0+r)*WW + v0 + c8*8]);
            }
        } else {
            int wl=t&63, j0=t>>6;
            for (int jj=0;jj<16;jj++){
                int j=j0+4*jj;
                Bs[wl*72+j] = Mb[(size_t)(v0+j)*WW + w0 + wl];
            }
        }
        __syncthreads();
        #pragma unroll
        for (int kk=0;kk<2;kk++){
            s8vec a[2], bb[2];
            #pragma unroll
            for (int m=0;m<2;m++) a[m]=*reinterpret_cast<const s8vec*>(&As[(cb+m*16+ln)*72+kk*32+cq*8]);
            #pragma unroll
            for (int n=0;n<2;n++) bb[n]=*reinterpret_cast<const s8vec*>(&Bs[(wb+n*16+ln)*72+kk*32+cq*8]);
            #pragma unroll
            for (int m=0;m<2;m++)
                #pragma unroll
                for (int n=0;n<2;n++)
                    acc[m][n]=__builtin_amdgcn_mfma_f32_16x16x32_bf16(a[m],bb[n],acc[m][n],0,0,0);
        }
    }
    const float* xb = xadd + (size_t)b*CHW + (size_t)l*WW + w0;
    float*      ob = outp + (size_t)b*CHW + (size_t)l*WW + w0;
    #pragma unroll
    for (int m=0;m<2;m++){
        #pragma unroll
        for (int r=0;r<4;r++){
            int c = cb + m*16 + cq*4 + r;
            float cf = coef[c];
            #pragma unroll
            for (int n=0;n<2;n++){
                int w = wb + n*16 + ln;
                ob[(size_t)c*HW + w] = xb[(size_t)c*HW + w] + cf*acc[m][n][r];
            }
        }
    }
}

// ---------------- K6 -- unchanged from R9 ----------------
__global__ __launch_bounds__(256) void k6_mfma(
    const bf16* __restrict__ Pm, const bf16* __restrict__ LTm, const bf16* __restrict__ PTm,
    const float* __restrict__ mask_r2l, const float* __restrict__ mask_l2r,
    double* __restrict__ dsum, int b)
{
    __shared__ bf16 As[2][128*64];   // [buf][w][k] swizzled
    __shared__ bf16 Bs[2][128*64];   // [buf][u][k] swizzled
    int t=threadIdx.x;
    int wg=blockIdx.x;
    int xcd = wg & 7, j = wg >> 3;
    int lgrp = j/18, tile = j - lgrp*18;
    int l = xcd + 8*lgrp;
    int which = tile/9; int xt = tile - which*9;
    int wt = xt/3, ut = xt - wt*3;
    int w0=wt*128, u0=ut*128, bh=b*HH+l;
    const float* msk = which ? (mask_r2l+(size_t)bh*WW) : (mask_l2r+(size_t)bh*WW);
    const bf16* Ap = Pm  + (size_t)l*WW*WW;
    const bf16* Lt = LTm + (size_t)l*WW*WW;
    const bf16* Bsrc = (which==0 ? LTm : PTm) + (size_t)l*WW*WW;

    int wv=t>>6, lane=t&63;
    int qr=wv>>1, qc=wv&1;
    int ln=lane&15, cq=lane>>4;

    uint4 rb[4], ra[4];
    uint4 r0[2], r1[2];

    auto stage_read = [&](int kt){
        #pragma unroll
        for (int i=0;i<4;i++){
            int lin=t+256*i; int u=lin>>3, c8=lin&7;
            rb[i] = *reinterpret_cast<const uint4*>(&Bsrc[(size_t)(u0+u)*WW + kt*64 + c8*8]);
        }
        if (which==0){
            #pragma unroll
            for (int i=0;i<4;i++){
                int lin=t+256*i; int w=lin>>3, c8=lin&7;
                ra[i] = *reinterpret_cast<const uint4*>(&Ap[(size_t)(w0+w)*WW + kt*64 + c8*8]);
            }
        } else {
            #pragma unroll
            for (int i=0;i<2;i++){
                int p=(t>>4)+16*i, wc=t&15;
                const bf16* base = &Lt[(size_t)(kt*64 + 2*p)*WW + w0 + wc*8];
                r0[i] = *reinterpret_cast<const uint4*>(base);
                r1[i] = *reinterpret_cast<const uint4*>(base + WW);
            }
        }
    };
    auto stage_write = [&](int bufi){
        bf16* bsw = Bs[bufi]; bf16* asw = As[bufi];
        #pragma unroll
        for (int i=0;i<4;i++){
            int lin=t+256*i; int u=lin>>3, c8=lin&7;
            *reinterpret_cast<uint4*>((char*)bsw + u*128 + ((c8 ^ SWZ(u))<<4)) = rb[i];
        }
        if (which==0){
            #pragma unroll
            for (int i=0;i<4;i++){
                int lin=t+256*i; int w=lin>>3, c8=lin&7;
                *reinterpret_cast<uint4*>((char*)asw + w*128 + ((c8 ^ SWZ(w))<<4)) = ra[i];
            }
        } else {
            #pragma unroll
            for (int i=0;i<2;i++){
                int p=(t>>4)+16*i, wc=t&15;
                const unsigned short* q0 = reinterpret_cast<const unsigned short*>(&r0[i]);
                const unsigned short* q1 = reinterpret_cast<const unsigned short*>(&r1[i]);
                int cb2 = p>>2, off = (p&3)*4;
                #pragma unroll
                for (int jj=0;jj<8;jj++){
                    int w = wc*8 + jj;
                    unsigned val = (unsigned)q0[jj] | ((unsigned)q1[jj]<<16);
                    *reinterpret_cast<unsigned*>((char*)asw + w*128 + ((cb2 ^ SWZ(w))<<4) + off) = val;
                }
            }
        }
    };

    f4vec acc[4][4];
    #pragma unroll
    for (int m=0;m<4;m++)
        #pragma unroll
        for (int n=0;n<4;n++) acc[m][n]=(f4vec){0.f,0.f,0.f,0.f};

    stage_read(0);
    stage_write(0);
    __syncthreads();
    int cur=0;
    for (int kt=0; kt<6; kt++){
        if (kt<5) stage_read(kt+1);
        const bf16* as = As[cur]; const bf16* bs = Bs[cur];
        #pragma unroll
        for (int kk=0;kk<2;kk++){
            s8vec a[4], bb[4];
            #pragma unroll
            for (int m=0;m<4;m++){
                int r = qr*64 + m*16 + ln;
                a[m] = *reinterpret_cast<const s8vec*>(
                    (const char*)as + r*128 + (((kk*4+cq) ^ SWZ(r))<<4));
            }
            #pragma unroll
            for (int n=0;n<4;n++){
                int u = qc*64 + n*16 + ln;
                bb[n] = *reinterpret_cast<const s8vec*>(
                    (const char*)bs + u*128 + (((kk*4+cq) ^ SWZ(u))<<4));
            }
            #pragma unroll
            for (int m=0;m<4;m++)
                #pragma unroll
                for (int n=0;n<4;n++)
                    acc[m][n]=__builtin_amdgcn_mfma_f32_16x16x32_bf16(a[m],bb[n],acc[m][n],0,0,0);
        }
        if (kt<5) stage_write(cur^1);
        __syncthreads();
        cur ^= 1;
    }

    float local = 0.f;
    #pragma unroll
    for (int n=0;n<4;n++){
        int ua = u0 + qc*64 + n*16 + ln;
        float mv = (msk[ua] > 0.1f) ? 1.f : 0.f;
        #pragma unroll
        for (int m=0;m<4;m++){
            int wbase = w0 + qr*64 + m*16 + cq*4;
            #pragma unroll
            for (int r=0;r<4;r++)
                local += mv * fabsf(acc[m][n][r] - ((ua==wbase+r)?1.f:0.f));
        }
    }
    for (int o=32;o;o>>=1) local += __shfl_xor(local,o,64);
    float* red = (float*)As;
    if (lane==0) red[wv]=local;
    __syncthreads();
    if (t==0) atomicAdd(&dsum[0], (double)(red[0]+red[1]+red[2]+red[3]));
}

// ---------------- K78 -- unchanged from R9 ----------------
__global__ __launch_bounds__(256) void k78_photo_smooth(
    const bf16* __restrict__ Pm, const bf16* __restrict__ LTm,
    const float* __restrict__ mask_r2l, const float* __restrict__ mask_l2r,
    const float* __restrict__ LRl, const float* __restrict__ LRr,
    float* __restrict__ out2, float* __restrict__ out3, double* __restrict__ dsum, int b)
{
    __shared__ unsigned short lrR[3*WW], lrL[3*WW];   // bf16-packed LR rows
    __shared__ float redP[4], redW[4], redH[4];
    int t=threadIdx.x;
    int wg=blockIdx.x;
    int xcd = wg & 7, j = wg >> 3;          // j 0..71
    int lgrp = j/6, seg = j - lgrp*6;       // lgrp 0..11, seg 0..5
    int l = xcd*12 + lgrp;
    int bh = b*HH + l;

    for (int c=0;c<3;c++){
        size_t base = ((size_t)(b*3+c)*HH + l)*WW;
        if (t < 96){
            float4 vl = *reinterpret_cast<const float4*>(&LRl[base + t*4]);
            float4 vr = *reinterpret_cast<const float4*>(&LRr[base + t*4]);
            ushort4 pl, pr;
            pl.x=f2bu(vl.x); pl.y=f2bu(vl.y); pl.z=f2bu(vl.z); pl.w=f2bu(vl.w);
            pr.x=f2bu(vr.x); pr.y=f2bu(vr.y); pr.z=f2bu(vr.z); pr.w=f2bu(vr.w);
            *reinterpret_cast<ushort4*>(&lrL[c*WW + t*4]) = pl;
            *reinterpret_cast<ushort4*>(&lrR[c*WW + t*4]) = pr;
            if (seg==0){
                *reinterpret_cast<float4*>(&out2[base + t*4]) = vl;
                *reinterpret_cast<float4*>(&out3[base + t*4]) = vr;
            }
        }
    }
    __syncthreads();

    int wid=t>>6, lane=t&63;
    int r4=lane>>4, ln=lane&15;
    const bf16* Pb  = Pm  + (size_t)l*WW*WW;
    const bf16* LTb = LTm + (size_t)l*WW*WW;
    bool dnok = (l < HH-1);
    const bf16* Pdn = Pb  + (dnok ? (size_t)WW*WW : 0);
    const bf16* Ldn = LTb + (dnok ? (size_t)WW*WW : 0);
    float fdn = dnok ? 1.f : 0.f;
    int src_same = (lane & 48) | ((ln+1)&15);
    int src_zero = (lane & 48);

    float phL=0.f, lwv=0.f, lhv=0.f;

    for (int it=0; it<4; it++){
        int w = seg*64 + wid*16 + it*4 + r4;
        int wn = (w<WW-1) ? w+1 : w;
        float fwn = (w<WW-1) ? 1.f : 0.f;
        const bf16* pr  = Pb  + (size_t)w*WW;
        const bf16* lr_ = LTb + (size_t)w*WW;
        const bf16* prn = Pb  + (size_t)wn*WW;
        const bf16* lrn = LTb + (size_t)wn*WW;
        const bf16* prd = Pdn + (size_t)w*WW;
        const bf16* lrd = Ldn + (size_t)w*WW;

        uint4 up[3], ul[3], upn[3], uln[3], upd[3], uld[3];
        #pragma unroll
        for (int i=0;i<3;i++){
            int off = 8*(ln + 16*i);
            up[i]  = *reinterpret_cast<const uint4*>(pr  + off);
            ul[i]  = *reinterpret_cast<const uint4*>(lr_ + off);
            upn[i] = *reinterpret_cast<const uint4*>(prn + off);
            uln[i] = *reinterpret_cast<const uint4*>(lrn + off);
            upd[i] = *reinterpret_cast<const uint4*>(prd + off);
            uld[i] = *reinterpret_cast<const uint4*>(lrd + off);
        }
        float pn0[3], ln0[3];
        #pragma unroll
        for (int i=0;i<3;i++){
            pn0[i] = bfu2f((unsigned short)(upn[i].x & 0xffffu));
            ln0[i] = bfu2f((unsigned short)(uln[i].x & 0xffffu));
        }

        float a0=0.f,a1=0.f,a2=0.f, d0=0.f,d1=0.f,d2=0.f;
        #pragma unroll
        for (int i=0;i<3;i++){
            const unsigned short* pu = reinterpret_cast<const unsigned short*>(&up[i]);
            const unsigned short* lu = reinterpret_cast<const unsigned short*>(&ul[i]);
            const unsigned short* pnu= reinterpret_cast<const unsigned short*>(&upn[i]);
            const unsigned short* lnu= reinterpret_cast<const unsigned short*>(&uln[i]);
            const unsigned short* pdu= reinterpret_cast<const unsigned short*>(&upd[i]);
            const unsigned short* ldu= reinterpret_cast<const unsigned short*>(&uld[i]);
            int v8 = 8*(ln+16*i);
            uint4 R0 = *reinterpret_cast<const uint4*>(&lrR[0*WW + v8]);
            uint4 R1 = *reinterpret_cast<const uint4*>(&lrR[1*WW + v8]);
            uint4 R2 = *reinterpret_cast<const uint4*>(&lrR[2*WW + v8]);
            uint4 L0 = *reinterpret_cast<const uint4*>(&lrL[0*WW + v8]);
            uint4 L1 = *reinterpret_cast<const uint4*>(&lrL[1*WW + v8]);
            uint4 L2 = *reinterpret_cast<const uint4*>(&lrL[2*WW + v8]);
            const unsigned short* r0c = reinterpret_cast<const unsigned short*>(&R0);
            const unsigned short* r1c = reinterpret_cast<const unsigned short*>(&R1);
            const unsigned short* r2c = reinterpret_cast<const unsigned short*>(&R2);
            const unsigned short* l0c = reinterpret_cast<const unsigned short*>(&L0);
            const unsigned short* l1c = reinterpret_cast<const unsigned short*>(&L1);
            const unsigned short* l2c = reinterpret_cast<const unsigned short*>(&L2);

            float pn_same = __shfl(pn0[i], src_same, 64);
            float ln_same = __shfl(ln0[i], src_same, 64);
            float pn_next = __shfl(pn0[i<2 ? i+1 : 0], src_zero, 64);
            float ln_next = __shfl(ln0[i<2 ? i+1 : 0], src_zero, 64);
            float pn_last = (ln==15) ? pn_next : pn_same;
            float ln_last = (ln==15) ? ln_next : ln_same;

            float pc[8], lc[8];
            #pragma unroll
            for (int e=0;e<8;e++){ pc[e]=bfu2f(pu[e]); lc[e]=bfu2f(lu[e]); }
            #pragma unroll
            for (int e=0;e<8;e++){
                a0 += pc[e]*bfu2f(r0c[e]); a1 += pc[e]*bfu2f(r1c[e]); a2 += pc[e]*bfu2f(r2c[e]);
                d0 += lc[e]*bfu2f(l0c[e]); d1 += lc[e]*bfu2f(l1c[e]); d2 += lc[e]*bfu2f(l2c[e]);
            }
            #pragma unroll
            for (int e=0;e<8;e++){
                lhv += fdn*(fabsf(pc[e]-bfu2f(pdu[e])) + fabsf(lc[e]-bfu2f(ldu[e])));
            }
            #pragma unroll
            for (int e=0;e<7;e++){
                lwv += fwn*(fabsf(pc[e]-bfu2f(pnu[e+1])) + fabsf(lc[e]-bfu2f(lnu[e+1])));
            }
            {
                float m = (v8+7 < WW-1) ? fwn : 0.f;
                lwv += m*(fabsf(pc[7]-pn_last) + fabsf(lc[7]-ln_last));
            }
        }
        #pragma unroll
        for (int o=8;o;o>>=1){
            a0+=__shfl_xor(a0,o,64); a1+=__shfl_xor(a1,o,64); a2+=__shfl_xor(a2,o,64);
            d0+=__shfl_xor(d0,o,64); d1+=__shfl_xor(d1,o,64); d2+=__shfl_xor(d2,o,64);
        }
        if (ln==0){
            float mkL = (mask_l2r[(size_t)bh*WW+w] > 0.1f) ? 1.f : 0.f;
            float mkR = (mask_r2l[(size_t)bh*WW+w] > 0.1f) ? 1.f : 0.f;
            size_t lrb = ((size_t)(b*3)*HH + l)*WW + w;
            size_t chs = (size_t)HH*WW;
            float l0v=LRl[lrb], l1v=LRl[lrb+chs], l2v=LRl[lrb+2*chs];
            float r0v=LRr[lrb], r1v=LRr[lrb+chs], r2v=LRr[lrb+2*chs];
            phL += mkL*(fabsf(l0v-a0)+fabsf(l1v-a1)+fabsf(l2v-a2));
            phL += mkR*(fabsf(r0v-d0)+fabsf(r1v-d1)+fabsf(r2v-d2));
        }
    }
    for (int o=32;o;o>>=1){
        phL+=__shfl_xor(phL,o,64); lwv+=__shfl_xor(lwv,o,64); lhv+=__shfl_xor(lhv,o,64);
    }
    if (lane==0){ redP[wid]=phL; redW[wid]=lwv; redH[wid]=lhv; }
    __syncthreads();
    if (t==0){
        atomicAdd(&dsum[1], (double)(redP[0]+redP[1]+redP[2]+redP[3]));
        atomicAdd(&dsum[3], (double)(redW[0]+redW[1]+redW[2]+redW[3]));
        atomicAdd(&dsum[2], (double)(redH[0]+redH[1]+redH[2]+redH[3]));
    }
}

// ---------------- K9: final loss -- unchanged ----------------
__global__ void k9_final(const double* __restrict__ dsum, const float* __restrict__ lossin,
                         float* __restrict__ out4)
{
    if (threadIdx.x==0){
        double cyc  = dsum[0]/(double)((size_t)BB*HH*WW*WW);
        double photo= dsum[1]/(double)((size_t)BB*3*HH*WW);
        double lhv  = dsum[2]/(double)((size_t)BB*(HH-1)*WW*WW);
        double lwv  = dsum[3]/(double)((size_t)BB*HH*(WW-1)*(WW-1));
        double res  = (double)lossin[0] + 0.0025*(photo + 0.1*(lwv+lhv) + cyc);
        out4[0]=(float)res;
    }
}

extern "C" void kernel_launch(void* const* d_in, const int* in_sizes, int n_in,
                              void* d_out, int out_size, void* d_ws, size_t ws_size,
                              hipStream_t stream)
{
    (void)in_sizes; (void)n_in; (void)out_size; (void)ws_size;
    const float* x_l  = (const float*)d_in[0];
    const float* x_r  = (const float*)d_in[1];
    const float* LRl  = (const float*)d_in[2];
    const float* LRr  = (const float*)d_in[3];
    const float* lossi= (const float*)d_in[4];
    const float* nlw  = (const float*)d_in[5];
    const float* nlb  = (const float*)d_in[6];
    const float* nrw  = (const float*)d_in[7];
    const float* nrb  = (const float*)d_in[8];
    const float* lp1w = (const float*)d_in[9];
    const float* lp1b = (const float*)d_in[10];
    const float* rp1w = (const float*)d_in[11];
    const float* rp1b = (const float*)d_in[12];
    const float* lp2w = (const float*)d_in[13];
    const float* lp2b = (const float*)d_in[14];
    const float* rp2w = (const float*)d_in[15];
    const float* rp2b = (const float*)d_in[16];
    const float* beta = (const float*)d_in[17];
    const float* gamma= (const float*)d_in[18];

    bf16* Abuf = (bf16*)d_ws;             // A -> P in-place
    bf16* LTb  = Abuf + ACHUNK;
    bf16* PTb  = Abuf + 2*ACHUNK;
    float* wsf = (float*)((char*)d_ws + 3*ACHUNK*2);
    float* rmax=wsf, *irsum=wsf+SST, *cmax=wsf+2*SST, *icsum=wsf+3*SST;
    float* mask_r2l=wsf+4*SST, *mask_l2r=wsf+5*SST;
    double* dsum=(double*)(wsf+6*SST);
    // Q and V alias the PT chunk (dead before k_trans); k3 col partials reuse Q's slot
    // (Q dead after k_attn, partials dead after k3b, V untouched).
    bf16* Qlb = PTb;
    bf16* Qrb = PTb + QELEMS;
    bf16* Vlb = PTb + 2*QELEMS;
    bf16* Vrb = PTb + 3*QELEMS;
    float* pcm = (float*)PTb;
    float* pcs = pcm + (size_t)HH*6*384;

    float* out  = (float*)d_out;
    float* out0 = out;
    float* out1 = out + (size_t)BB*CHW;
    float* out2 = out + 2*(size_t)BB*CHW;
    float* out3 = out2 + (size_t)BB*3*HW;
    float* out4 = out3 + (size_t)BB*3*HW;

    k0_zero<<<1,64,0,stream>>>(dsum);
    for (int b=0;b<BB;b++){
        k_qv<<<dim3(6,HH),256,0,stream>>>(x_l,x_r,nlw,nlb,nrw,nrb,
                                          lp1w,lp1b,rp1w,rp1b,lp2w,lp2b,rp2w,rp2b,
                                          Qlb,Qrb,Vlb,Vrb,b);
        k_attn<<<dim3(3,3,HH),256,0,stream>>>(Qlb,Qrb,Abuf);
        k3a<<<dim3(HH,6),256,0,stream>>>(Abuf,rmax,irsum,pcm,pcs,b);
        k3b<<<HH,384,0,stream>>>(pcm,pcs,cmax,icsum,mask_r2l,b);
        k_mats<<<dim3(HH,6),256,0,stream>>>(Abuf,LTb,rmax,irsum,cmax,icsum,
                                            mask_r2l,mask_l2r,b);
        k5m<<<dim3(6,HH),256,0,stream>>>(Abuf,Vrb,x_l,beta, out0,b,0);   // V consumed here,
        k5m<<<dim3(6,HH),256,0,stream>>>(LTb, Vlb,x_r,gamma,out1,b,1);   // BEFORE k_trans
        k_trans<<<dim3(6,6,HH),256,0,stream>>>(Abuf,PTb);
        k6_mfma<<<1728,256,0,stream>>>(Abuf,LTb,PTb,mask_r2l,mask_l2r,dsum,b);
        k78_photo_smooth<<<576,256,0,stream>>>(Abuf,LTb,mask_r2l,mask_l2r,LRl,LRr,out2,out3,dsum,b);
    }
    k9_final<<<1,64,0,stream>>>(dsum,lossi,out4);
}